// Round 13
// baseline (3022.515 us; speedup 1.0000x reference)
//
#include <hip/hip_runtime.h>
#include <hip/hip_bf16.h>
#include <cstdint>
#include <cstddef>

#define E_N 600000
#define NND 50000
#define L 128
#define EGRID 4688              // ceil(E_N/128)
#define PBLK 16384              // u16 per 128-row panel-block (8*128*16)

typedef unsigned short u16;
typedef unsigned int u32;
typedef __attribute__((ext_vector_type(8))) short bf16x8;
typedef __attribute__((ext_vector_type(4))) float f32x4;

static __device__ __forceinline__ u16 f2bf(float f) {
  union { float f; u32 u; } c; c.f = f;
  return (u16)((c.u + 0x7fffu + ((c.u >> 16) & 1u)) >> 16);
}
static __device__ __forceinline__ u32 pk2(float a, float b) {
  return (u32)f2bf(a) | ((u32)f2bf(b) << 16);
}
static __device__ __forceinline__ float bf2f(u32 h) {
  union { u32 u; float f; } c; c.u = (h & 0xffffu) << 16; return c.f;
}
static __device__ __forceinline__ void atomAddF(float* p, float v) {
#if defined(__HIP_DEVICE_COMPILE__)
  unsafeAtomicAdd(p, v);
#else
  atomicAdd(p, v);
#endif
}
static __device__ __forceinline__ bf16x8 bnrelu8(bf16x8 raw, float4 sca, float4 scb,
                                                 float4 sha, float4 shb) {
  union { bf16x8 v; u16 h[8]; } in; in.v = raw;
  const float sc[8] = {sca.x, sca.y, sca.z, sca.w, scb.x, scb.y, scb.z, scb.w};
  const float sh[8] = {sha.x, sha.y, sha.z, sha.w, shb.x, shb.y, shb.z, shb.w};
  float f[8];
  #pragma unroll
  for (int i = 0; i < 8; ++i) f[i] = fmaxf(bf2f(in.h[i]) * sc[i] + sh[i], 0.f);
  union { bf16x8 v; u32 w[4]; } r;
  #pragma unroll
  for (int i = 0; i < 4; ++i) r.w[i] = pk2(f[2 * i], f[2 * i + 1]);
  return r.v;
}

#define MFMA(a, bfr, c) __builtin_amdgcn_mfma_f32_16x16x32_bf16((a), (bfr), (c), 0, 0, 0)

// panel-layout address (u16 units): row-block, panel p (=col/16), local row, col%16
static __device__ __forceinline__ size_t paddr(int row, int panel, int incol) {
  return (size_t)(row >> 7) * PBLK + (size_t)panel * 2048 + (size_t)(row & 127) * 16 + incol;
}

// ================= prepass kernels =================
__global__ __launch_bounds__(256) void k_cvt4(const float* __restrict__ in,
                                              u16* __restrict__ out, int n4) {
  const int i = blockIdx.x * 256 + threadIdx.x;
  if (i < n4) {
    const float4 v = *(const float4*)(in + (size_t)i * 4);
    uint2 o; o.x = pk2(v.x, v.y); o.y = pk2(v.z, v.w);
    *(uint2*)(out + (size_t)i * 4) = o;
  }
}

// in_ea (fp32, original order) -> ea16 (bf16, permuted panel layout)
__global__ __launch_bounds__(256) void k_cvtperm(const float* __restrict__ in_ea,
                                                 const int* __restrict__ perm,
                                                 u16* __restrict__ ea16) {
  const int i = blockIdx.x * 256 + threadIdx.x;
  const int row = i >> 4, part = i & 15;      // 16 threads/row, 8 cols each
  if (row < E_N) {
    const float* p = in_ea + (size_t)perm[row] * L + part * 8;
    const float4 f0 = *(const float4*)p, f1 = *(const float4*)(p + 4);
    union { bf16x8 v; u32 w[4]; } r;
    r.w[0] = pk2(f0.x, f0.y); r.w[1] = pk2(f0.z, f0.w);
    r.w[2] = pk2(f1.x, f1.y); r.w[3] = pk2(f1.z, f1.w);
    *(bf16x8*)(ea16 + paddr(row, part >> 1, (part & 1) * 8)) = r.v;
  }
}

__global__ void k_wt(const float* __restrict__ W, u16* __restrict__ Wt, int K) {
  const int idx = blockIdx.x * 256 + threadIdx.x;
  const int total = 4 * K * 128;
  if (idx >= total) return;
  const int s = idx / (K * 128);
  const int rem = idx - s * K * 128;
  const int n = rem / K;
  const int k = rem - n * K;
  Wt[idx] = f2bf(W[(size_t)s * K * 128 + (size_t)k * 128 + n]);
}

__global__ void k_hist(const int* __restrict__ dstI, int* __restrict__ cnt) {
  const int i = blockIdx.x * 256 + threadIdx.x;
  if (i < E_N) atomicAdd(&cnt[dstI[i]], 1);
}

__global__ __launch_bounds__(1024) void k_scan(const int* __restrict__ cnt, int* __restrict__ startA) {
  __shared__ int buf[1024];
  __shared__ int carry;
  const int tid = threadIdx.x;
  if (tid == 0) carry = 0;
  __syncthreads();
  for (int base = 0; base < NND; base += 1024) {
    int v = (base + tid < NND) ? cnt[base + tid] : 0;
    buf[tid] = v;
    __syncthreads();
    for (int off = 1; off < 1024; off <<= 1) {
      int t = (tid >= off) ? buf[tid - off] : 0;
      __syncthreads();
      buf[tid] += t;
      __syncthreads();
    }
    const int incl = buf[tid];
    const int c = carry;
    if (base + tid < NND) startA[base + tid] = c + incl - v;
    __syncthreads();
    if (tid == 1023) carry = c + incl;
    __syncthreads();
  }
  if (tid == 0) startA[NND] = carry;
}

__global__ void k_fill(const int* __restrict__ dstI, const int* __restrict__ startA,
                       int* __restrict__ cur, int* __restrict__ eids) {
  const int i = blockIdx.x * 256 + threadIdx.x;
  if (i < E_N) {
    const int d = dstI[i];
    const int pos = atomicAdd(&cur[d], 1);
    eids[startA[d] + pos] = i;
  }
}

__global__ void k_perm(const int* __restrict__ srcI, const int* __restrict__ dstI,
                       const int* __restrict__ perm,
                       int* __restrict__ srcP, int* __restrict__ dstP) {
  const int i = blockIdx.x * 256 + threadIdx.x;
  if (i < E_N) {
    const int e = perm[i];
    srcP[i] = srcI[e];
    dstP[i] = dstI[e];
  }
}

// ================= aggregation (panel ea16 -> row-major agg16) =================
__global__ __launch_bounds__(256) void k_agg(const u16* __restrict__ ea16,
                                             const int* __restrict__ startA,
                                             u16* __restrict__ agg16) {
  const int node = blockIdx.x * 4 + (threadIdx.x >> 6);
  const int lane = threadIdx.x & 63;
  if (node >= NND) return;
  const int s = startA[node], e = startA[node + 1];
  const size_t poff = (size_t)(lane >> 3) * 2048 + (size_t)((lane & 7) * 2);
  float a0 = 0.f, a1 = 0.f, b0 = 0.f, b1 = 0.f;
  int i = s;
  for (; i + 1 < e; i += 2) {
    const u32 v0 = *(const u32*)(ea16 + (size_t)(i >> 7) * PBLK + (size_t)(i & 127) * 16 + poff);
    const int j = i + 1;
    const u32 v1 = *(const u32*)(ea16 + (size_t)(j >> 7) * PBLK + (size_t)(j & 127) * 16 + poff);
    a0 += bf2f(v0); a1 += bf2f(v0 >> 16);
    b0 += bf2f(v1); b1 += bf2f(v1 >> 16);
  }
  if (i < e) {
    const u32 v = *(const u32*)(ea16 + (size_t)(i >> 7) * PBLK + (size_t)(i & 127) * 16 + poff);
    a0 += bf2f(v); a1 += bf2f(v >> 16);
  }
  *(u32*)(agg16 + (size_t)node * L + lane * 2) = pk2(a0 + b0, a1 + b1);
}

// ================= BN finalize =================
__global__ void k_bnfin(const float* __restrict__ gS, const float* __restrict__ g,
                        const float* __restrict__ be, float invM, float* __restrict__ ss) {
  const int c = threadIdx.x;
  float s1 = 0.f, s2 = 0.f;
  for (int j = 0; j < 64; ++j) { s1 += gS[j * L + c]; s2 += gS[64 * L + j * L + c]; }
  const float mean = s1 * invM;
  const float var = s2 * invM - mean * mean;
  const float sc = g[c] * rsqrtf(var + 1e-5f);
  ss[c] = sc;
  ss[L + c] = be[c] - mean * sc;
}

// ================= edge layer 1: wave-owns-16-rows, A private, W via 2-buffer LDS =================
// Wave wid owns rows row0+wid*16 .. +15 (one per lane l15), computes all 128 cols.
__global__ __launch_bounds__(512, 8) void k_edge_l1(
    const u16* __restrict__ x16, const u16* __restrict__ ea16,
    const int* __restrict__ srcP, const int* __restrict__ dstP,
    const u16* __restrict__ Wt, const float* __restrict__ b,
    u16* __restrict__ h1, float* __restrict__ gS)
{
  __shared__ __align__(16) char Ws2[2 * 16384];
  __shared__ float red[256];
  const int tid = threadIdx.x, bid = blockIdx.x, row0 = bid * 128;
  const int lane = tid & 63, wid = tid >> 6;
  const int l15 = lane & 15, lq = lane >> 4;
  if (tid < 256) red[tid] = 0.f;

  const int myrow = row0 + wid * 16 + l15;
  const int crow = min(myrow, E_N - 1);
  const int dI = dstP[crow], sI = srcP[crow];

  // private A fragments, rolling window
  bf16x8 af[6][2];
  auto loadA = [&](int cc) {
    if (cc < 4) {
      const int node = (cc < 2) ? dI : sI;
      const u16* p = x16 + (size_t)node * L + (cc & 1) * 64 + lq * 8;
      af[cc][0] = *(const bf16x8*)p;
      af[cc][1] = *(const bf16x8*)(p + 32);
    } else {
      const int pc = cc - 4;
      af[cc][0] = *(const bf16x8*)(ea16 + paddr(crow, pc * 4 + (lq >> 1), (lq & 1) * 8));
      af[cc][1] = *(const bf16x8*)(ea16 + paddr(crow, pc * 4 + 2 + (lq >> 1), (lq & 1) * 8));
    }
  };
  loadA(0); loadA(1); loadA(2);

  // W staging: 1024 16B-slots per chunk; linear LDS write, pre-swizzled global source
  const int n0 = tid >> 3,         kq0 = (tid & 7) ^ (n0 & 7);
  const int n1 = (tid + 512) >> 3, kq1 = ((tid + 512) & 7) ^ (n1 & 7);
  uint4 wa, wb;
  auto wload = [&](int cc) {
    wa = *(const uint4*)(Wt + (size_t)n0 * 384 + cc * 64 + kq0 * 8);
    wb = *(const uint4*)(Wt + (size_t)n1 * 384 + cc * 64 + kq1 * 8);
  };
  auto wwrite = [&](int buf) {
    *(uint4*)(Ws2 + buf * 16384 + tid * 16) = wa;
    *(uint4*)(Ws2 + buf * 16384 + tid * 16 + 8192) = wb;
  };

  wload(0);
  wwrite(0);
  __syncthreads();

  f32x4 acc[8];
  #pragma unroll
  for (int cg = 0; cg < 8; ++cg) acc[cg] = (f32x4){0.f, 0.f, 0.f, 0.f};

  #pragma unroll
  for (int cc = 0; cc < 6; ++cc) {
    if (cc + 1 < 6) wload(cc + 1);     // L2-hot, 1-iter cover
    if (cc + 3 < 6) loadA(cc + 3);     // gathers, 3-iter cover
    const char* base = Ws2 + (cc & 1) * 16384;
    #pragma unroll
    for (int cg = 0; cg < 8; ++cg) {
      const int n = cg * 16 + l15;
      const int sw = (n & 7) << 4;
      #pragma unroll
      for (int k2 = 0; k2 < 2; ++k2) {
        const bf16x8 wf = *(const bf16x8*)(base + ((n * 128 + k2 * 64 + lq * 16) ^ sw));
        acc[cg] = MFMA(wf, af[cc][k2], acc[cg]);   // C^T: lane row = edge row
      }
    }
    if (cc + 1 < 6) wwrite((cc + 1) & 1);
    __syncthreads();
  }

  // epilogue: bias, stats (shfl over l15 + LDS atomics), coalesced panel stores
  const bool valid = myrow < E_N;
  u16* hp = h1 + (size_t)bid * PBLK + (size_t)(wid * 16 + l15) * 16 + lq * 4;
  #pragma unroll
  for (int cg = 0; cg < 8; ++cg) {
    float o[4], s1[4], s2[4];
    #pragma unroll
    for (int r = 0; r < 4; ++r) {
      o[r] = acc[cg][r] + b[cg * 16 + lq * 4 + r];
      s1[r] = valid ? o[r] : 0.f;
      s2[r] = valid ? o[r] * o[r] : 0.f;
    }
    if (valid) {
      ushort4 st;
      st.x = f2bf(o[0]); st.y = f2bf(o[1]); st.z = f2bf(o[2]); st.w = f2bf(o[3]);
      *(ushort4*)(hp + cg * 2048) = st;
    }
    #pragma unroll
    for (int off = 1; off < 16; off <<= 1)
      #pragma unroll
      for (int r = 0; r < 4; ++r) {
        s1[r] += __shfl_xor(s1[r], off);
        s2[r] += __shfl_xor(s2[r], off);
      }
    if (l15 == 0) {
      #pragma unroll
      for (int r = 0; r < 4; ++r) {
        atomAddF(&red[cg * 16 + lq * 4 + r], s1[r]);
        atomAddF(&red[128 + cg * 16 + lq * 4 + r], s2[r]);
      }
    }
  }
  __syncthreads();
  const int slot = (bid & 63) * L;
  if (tid < 128) atomAddF(&gS[slot + tid], red[tid]);
  else if (tid < 256) atomAddF(&gS[64 * L + slot + (tid - 128)], red[tid]);
}

// ================= edge layer 2: wave-owns-16-rows, W staged once (32 KB) =================
template <bool WF32>
__global__ __launch_bounds__(512, 8) void k_edge_l2(
    const u16* __restrict__ h1, const float* __restrict__ ss,
    const u16* __restrict__ Wt, const float* __restrict__ b,
    const int* __restrict__ perm,
    float* __restrict__ ea_out, u16* __restrict__ ea16)
{
  __shared__ __align__(16) char Ws2[2 * 16384];
  const int tid = threadIdx.x, bid = blockIdx.x, row0 = bid * 128;
  const int lane = tid & 63, wid = tid >> 6;
  const int l15 = lane & 15, lq = lane >> 4;

  const int myrow = row0 + wid * 16 + l15;
  const int crow = min(myrow, E_N - 1);

  // stage both W chunks (linear write, pre-swizzled source)
  const int n0 = tid >> 3,         kq0 = (tid & 7) ^ (n0 & 7);
  const int n1 = (tid + 512) >> 3, kq1 = ((tid + 512) & 7) ^ (n1 & 7);
  #pragma unroll
  for (int cc = 0; cc < 2; ++cc) {
    const uint4 wa = *(const uint4*)(Wt + (size_t)n0 * 128 + cc * 64 + kq0 * 8);
    const uint4 wb = *(const uint4*)(Wt + (size_t)n1 * 128 + cc * 64 + kq1 * 8);
    *(uint4*)(Ws2 + cc * 16384 + tid * 16) = wa;
    *(uint4*)(Ws2 + cc * 16384 + tid * 16 + 8192) = wb;
  }

  // private A (h1 panel), raw
  bf16x8 ah[2][2];
  #pragma unroll
  for (int cc = 0; cc < 2; ++cc)
    #pragma unroll
    for (int k2 = 0; k2 < 2; ++k2)
      ah[cc][k2] = *(const bf16x8*)(h1 + paddr(crow, cc * 4 + k2 * 2 + (lq >> 1), (lq & 1) * 8));
  __syncthreads();

  f32x4 acc[8];
  #pragma unroll
  for (int cg = 0; cg < 8; ++cg) acc[cg] = (f32x4){0.f, 0.f, 0.f, 0.f};

  #pragma unroll
  for (int cc = 0; cc < 2; ++cc)
    #pragma unroll
    for (int k2 = 0; k2 < 2; ++k2) {
      const int kb = cc * 64 + k2 * 32 + lq * 8;
      const float4 sca = *(const float4*)(ss + kb), scb = *(const float4*)(ss + kb + 4);
      const float4 sha = *(const float4*)(ss + 128 + kb), shb = *(const float4*)(ss + 128 + kb + 4);
      const bf16x8 afr = bnrelu8(ah[cc][k2], sca, scb, sha, shb);
      const char* base = Ws2 + cc * 16384;
      #pragma unroll
      for (int cg = 0; cg < 8; ++cg) {
        const int n = cg * 16 + l15;
        const int sw = (n & 7) << 4;
        const bf16x8 wf = *(const bf16x8*)(base + ((n * 128 + k2 * 64 + lq * 16) ^ sw));
        acc[cg] = MFMA(wf, afr, acc[cg]);
      }
    }

  // epilogue: o = relu(acc+bias) + resid (in-place panel RMW); fp32 scatter at s=3
  const bool valid = myrow < E_N;
  const int prow = (WF32 && valid) ? perm[myrow] : 0;
  u16* ep = ea16 + (size_t)bid * PBLK + (size_t)(wid * 16 + l15) * 16 + lq * 4;
  #pragma unroll
  for (int cg = 0; cg < 8; ++cg) {
    if (valid) {
      float o[4];
      #pragma unroll
      for (int r = 0; r < 4; ++r) o[r] = fmaxf(acc[cg][r] + b[cg * 16 + lq * 4 + r], 0.f);
      const ushort4 rv = *(const ushort4*)(ep + cg * 2048);
      o[0] += bf2f(rv.x); o[1] += bf2f(rv.y); o[2] += bf2f(rv.z); o[3] += bf2f(rv.w);
      ushort4 st;
      st.x = f2bf(o[0]); st.y = f2bf(o[1]); st.z = f2bf(o[2]); st.w = f2bf(o[3]);
      *(ushort4*)(ep + cg * 2048) = st;
      if (WF32) {
        float4 fv; fv.x = o[0]; fv.y = o[1]; fv.z = o[2]; fv.w = o[3];
        *(float4*)(ea_out + (size_t)prow * L + cg * 16 + lq * 4) = fv;
      }
    }
  }
}

// ================= node layer 1 (x16 + agg16 bf16, row-major) =================
__global__ __launch_bounds__(256) void k_node_l1(
    const u16* __restrict__ x16, const u16* __restrict__ agg16,
    const u16* __restrict__ Wt, const float* __restrict__ b,
    u16* __restrict__ h1, float* __restrict__ gS)
{
  __shared__ __align__(16) char Bs[2][16384];
  __shared__ float red[256];
  const int tid = threadIdx.x, bid = blockIdx.x, row0 = bid * 64;
  red[tid] = 0.f;
  const int lane = tid & 63, wid = tid >> 6, wr = wid >> 1, wc = wid & 1;
  const int l15 = lane & 15, lq = lane >> 4;
  const int r0 = row0 + wr * 32 + l15, r1 = r0 + 16;
  const int rr0 = min(r0, NND - 1), rr1 = min(r1, NND - 1);

  const u16* aP[2][2];
  aP[0][0] = x16 + (size_t)rr0 * L;   aP[1][0] = x16 + (size_t)rr1 * L;
  aP[0][1] = agg16 + (size_t)rr0 * L; aP[1][1] = agg16 + (size_t)rr1 * L;

  f32x4 acc[2][4];
  #pragma unroll
  for (int m = 0; m < 2; ++m)
    #pragma unroll
    for (int n = 0; n < 4; ++n) acc[m][n] = (f32x4){0.f, 0.f, 0.f, 0.f};

  auto loadA = [&](int c, bf16x8 (&af)[2][2]) {
    const int seg = c >> 1;
    const int base = (c & 1) * 64 + lq * 8;
    #pragma unroll
    for (int k2 = 0; k2 < 2; ++k2) {
      af[0][k2] = *(const bf16x8*)(aP[0][seg] + base + k2 * 32);
      af[1][k2] = *(const bf16x8*)(aP[1][seg] + base + k2 * 32);
    }
  };
  auto stage = [&](int c, int buf) {
    #pragma unroll
    for (int i = 0; i < 4; ++i) {
      const int slot = tid + i * 256;
      const int n = slot >> 3, kq = slot & 7;
      const uint4 v = *(const uint4*)(Wt + (size_t)n * 256 + c * 64 + kq * 8);
      *(uint4*)(&Bs[buf][0] + ((n * 128 + kq * 16) ^ ((n & 7) << 4))) = v;
    }
  };

  bf16x8 aCur[2][2], aNxt[2][2];
  loadA(0, aCur);
  stage(0, 0);
  __syncthreads();
  #pragma unroll
  for (int c = 0; c < 4; ++c) {
    if (c + 1 < 4) loadA(c + 1, aNxt);
    {
      const char* base = &Bs[c & 1][0];
      #pragma unroll
      for (int k2 = 0; k2 < 2; ++k2)
        #pragma unroll
        for (int n = 0; n < 4; ++n) {
          const int ncol = wc * 64 + n * 16 + l15;
          const bf16x8 bfr = *(const bf16x8*)(base + ((ncol * 128 + k2 * 64 + lq * 16) ^ ((ncol & 7) << 4)));
          acc[0][n] = MFMA(aCur[0][k2], bfr, acc[0][n]);
          acc[1][n] = MFMA(aCur[1][k2], bfr, acc[1][n]);
        }
    }
    if (c + 1 < 4) stage(c + 1, (c + 1) & 1);
    __syncthreads();
    #pragma unroll
    for (int m = 0; m < 2; ++m)
      #pragma unroll
      for (int k2 = 0; k2 < 2; ++k2) aCur[m][k2] = aNxt[m][k2];
  }

  float bb[4], s1[4], s2[4];
  #pragma unroll
  for (int n = 0; n < 4; ++n) { bb[n] = b[wc * 64 + n * 16 + l15]; s1[n] = 0.f; s2[n] = 0.f; }
  #pragma unroll
  for (int m = 0; m < 2; ++m)
    #pragma unroll
    for (int n = 0; n < 4; ++n) {
      const int ncol = wc * 64 + n * 16 + l15;
      #pragma unroll
      for (int r = 0; r < 4; ++r) {
        const int row = row0 + wr * 32 + m * 16 + lq * 4 + r;
        if (row < NND) {
          const float o = acc[m][n][r] + bb[n];
          s1[n] += o; s2[n] += o * o;
          h1[(size_t)row * L + ncol] = f2bf(o);
        }
      }
    }
  #pragma unroll
  for (int n = 0; n < 4; ++n) {
    const int ncol = wc * 64 + n * 16 + l15;
    atomAddF(&red[ncol], s1[n]);
    atomAddF(&red[128 + ncol], s2[n]);
  }
  __syncthreads();
  const int slot = (bid & 63) * L;
  if (tid < 128) atomAddF(&gS[slot + tid], red[tid]);
  else atomAddF(&gS[64 * L + slot + (tid - 128)], red[tid]);
}

// ================= node layer 2 =================
__global__ __launch_bounds__(256) void k_node_l2(
    const u16* __restrict__ h1, const float* __restrict__ ss,
    const u16* __restrict__ Wt, const float* __restrict__ b,
    const float* __restrict__ resid, float* __restrict__ x_out,
    u16* __restrict__ x16)
{
  __shared__ __align__(16) char Bs[2][16384];
  const int tid = threadIdx.x, bid = blockIdx.x, row0 = bid * 64;
  const int lane = tid & 63, wid = tid >> 6, wr = wid >> 1, wc = wid & 1;
  const int l15 = lane & 15, lq = lane >> 4;
  const int r0 = row0 + wr * 32 + l15, r1 = r0 + 16;
  const int rr0 = min(r0, NND - 1), rr1 = min(r1, NND - 1);
  const u16* a0 = h1 + (size_t)rr0 * L + lq * 8;
  const u16* a1 = h1 + (size_t)rr1 * L + lq * 8;

  f32x4 acc[2][4];
  #pragma unroll
  for (int m = 0; m < 2; ++m)
    #pragma unroll
    for (int n = 0; n < 4; ++n) acc[m][n] = (f32x4){0.f, 0.f, 0.f, 0.f};

  auto stage = [&](int c, int buf) {
    #pragma unroll
    for (int i = 0; i < 4; ++i) {
      const int slot = tid + i * 256;
      const int n = slot >> 3, kq = slot & 7;
      const uint4 v = *(const uint4*)(Wt + (size_t)n * 128 + c * 64 + kq * 8);
      *(uint4*)(&Bs[buf][0] + ((n * 128 + kq * 16) ^ ((n & 7) << 4))) = v;
    }
  };
  stage(0, 0);
  stage(1, 1);
  bf16x8 raw[2][2][2];
  #pragma unroll
  for (int c = 0; c < 2; ++c)
    #pragma unroll
    for (int k2 = 0; k2 < 2; ++k2) {
      raw[c][0][k2] = *(const bf16x8*)(a0 + c * 64 + k2 * 32);
      raw[c][1][k2] = *(const bf16x8*)(a1 + c * 64 + k2 * 32);
    }
  __syncthreads();

  #pragma unroll
  for (int c = 0; c < 2; ++c) {
    bf16x8 af[2][2];
    #pragma unroll
    for (int k2 = 0; k2 < 2; ++k2) {
      const int kg = c * 64 + k2 * 32 + lq * 8;
      const float4 sca = *(const float4*)(ss + kg), scb = *(const float4*)(ss + kg + 4);
      const float4 sha = *(const float4*)(ss + 128 + kg), shb = *(const float4*)(ss + 128 + kg + 4);
      af[0][k2] = bnrelu8(raw[c][0][k2], sca, scb, sha, shb);
      af[1][k2] = bnrelu8(raw[c][1][k2], sca, scb, sha, shb);
    }
    const char* base = &Bs[c][0];
    #pragma unroll
    for (int k2 = 0; k2 < 2; ++k2)
      #pragma unroll
      for (int n = 0; n < 4; ++n) {
        const int ncol = wc * 64 + n * 16 + l15;
        const bf16x8 bfr = *(const bf16x8*)(base + ((ncol * 128 + k2 * 64 + lq * 16) ^ ((ncol & 7) << 4)));
        acc[0][n] = MFMA(af[0][k2], bfr, acc[0][n]);
        acc[1][n] = MFMA(af[1][k2], bfr, acc[1][n]);
      }
  }

  float bb[4];
  #pragma unroll
  for (int n = 0; n < 4; ++n) bb[n] = b[wc * 64 + n * 16 + l15];
  #pragma unroll
  for (int m = 0; m < 2; ++m)
    #pragma unroll
    for (int n = 0; n < 4; ++n) {
      const int ncol = wc * 64 + n * 16 + l15;
      #pragma unroll
      for (int r = 0; r < 4; ++r) {
        const int row = row0 + wr * 32 + m * 16 + lq * 4 + r;
        if (row < NND) {
          const float o = fmaxf(acc[m][n][r] + bb[n], 0.f) + resid[(size_t)row * L + ncol];
          x_out[(size_t)row * L + ncol] = o;
          x16[(size_t)row * L + ncol] = f2bf(o);
        }
      }
    }
}

extern "C" void kernel_launch(void* const* d_in, const int* in_sizes, int n_in,
                              void* d_out, int out_size, void* d_ws, size_t ws_size,
                              hipStream_t stream) {
  (void)in_sizes; (void)n_in; (void)out_size; (void)ws_size;
  const float* in_x  = (const float*)d_in[0];
  const float* in_ea = (const float*)d_in[1];
  const int*   ei    = (const int*)d_in[2];
  const float* eW1 = (const float*)d_in[3];
  const float* eb1 = (const float*)d_in[4];
  const float* eg1 = (const float*)d_in[5];
  const float* ebe1= (const float*)d_in[6];
  const float* eW2 = (const float*)d_in[7];
  const float* eb2 = (const float*)d_in[8];
  const float* nW1 = (const float*)d_in[9];
  const float* nb1 = (const float*)d_in[10];
  const float* ng1 = (const float*)d_in[11];
  const float* nbe1= (const float*)d_in[12];
  const float* nW2 = (const float*)d_in[13];
  const float* nb2 = (const float*)d_in[14];

  float* x  = (float*)d_out;                    // [NND][L]
  float* ea = (float*)d_out + (size_t)NND * L;  // [E_N][L]

  char* w = (char*)d_ws;
  u16* h1e   = (u16*)w;   w += (size_t)EGRID * PBLK * sizeof(u16);  // panel layout
  u16* ea16  = (u16*)w;   w += (size_t)EGRID * PBLK * sizeof(u16);  // panel layout
  u16* h1n   = (u16*)w;   w += (size_t)NND * L * sizeof(u16);
  u16* x16   = (u16*)w;   w += (size_t)NND * L * sizeof(u16);
  u16* agg16 = (u16*)w;   w += (size_t)NND * L * sizeof(u16);
  float* gS  = (float*)w; w += (size_t)2 * 64 * L * sizeof(float);
  float* ss  = (float*)w; w += 4096;
  u16* eW1t = (u16*)w;   w += (size_t)4 * 128 * 384 * sizeof(u16);
  u16* eW2t = (u16*)w;   w += (size_t)4 * 128 * 128 * sizeof(u16);
  u16* nW1t = (u16*)w;   w += (size_t)4 * 128 * 256 * sizeof(u16);
  u16* nW2t = (u16*)w;   w += (size_t)4 * 128 * 128 * sizeof(u16);
  int* cnt    = (int*)w; w += (size_t)NND * sizeof(int);
  int* cur    = (int*)w; w += (size_t)NND * sizeof(int);
  int* startA = (int*)w; w += (size_t)(NND + 64) * sizeof(int);
  int* eids   = (int*)w; w += (size_t)E_N * sizeof(int);     // = perm
  int* srcP   = (int*)w; w += (size_t)E_N * sizeof(int);
  int* dstP   = (int*)w; w += (size_t)E_N * sizeof(int);

  const int* srcI = ei;
  const int* dstI = ei + E_N;

  k_cvt4<<<(NND * L / 4 + 255) / 256, 256, 0, stream>>>(in_x, x16, NND * L / 4);
  k_wt<<<(4 * 384 * 128 + 255) / 256, 256, 0, stream>>>(eW1, eW1t, 384);
  k_wt<<<(4 * 128 * 128 + 255) / 256, 256, 0, stream>>>(eW2, eW2t, 128);
  k_wt<<<(4 * 256 * 128 + 255) / 256, 256, 0, stream>>>(nW1, nW1t, 256);
  k_wt<<<(4 * 128 * 128 + 255) / 256, 256, 0, stream>>>(nW2, nW2t, 128);
  hipMemsetAsync(cnt, 0, (size_t)NND * sizeof(int), stream);
  hipMemsetAsync(cur, 0, (size_t)NND * sizeof(int), stream);
  k_hist<<<(E_N + 255) / 256, 256, 0, stream>>>(dstI, cnt);
  k_scan<<<1, 1024, 0, stream>>>(cnt, startA);
  k_fill<<<(E_N + 255) / 256, 256, 0, stream>>>(dstI, startA, cur, eids);
  k_perm<<<(E_N + 255) / 256, 256, 0, stream>>>(srcI, dstI, eids, srcP, dstP);
  k_cvtperm<<<(E_N * 16 + 255) / 256, 256, 0, stream>>>(in_ea, eids, ea16);

  const int ngrid = (NND + 63) / 64;     // 782

  for (int s = 0; s < 4; ++s) {
    hipMemsetAsync(gS, 0, (size_t)2 * 64 * L * sizeof(float), stream);
    k_edge_l1<<<EGRID, 512, 0, stream>>>(x16, ea16, srcP, dstP,
        eW1t + (size_t)s * 128 * 384, eb1 + (size_t)s * L, h1e, gS);
    k_bnfin<<<1, 128, 0, stream>>>(gS, eg1 + (size_t)s * L, ebe1 + (size_t)s * L,
        1.f / (float)E_N, ss);
    if (s < 3)
      k_edge_l2<false><<<EGRID, 512, 0, stream>>>(h1e, ss,
          eW2t + (size_t)s * 128 * 128, eb2 + (size_t)s * L, eids, ea, ea16);
    else
      k_edge_l2<true><<<EGRID, 512, 0, stream>>>(h1e, ss,
          eW2t + (size_t)s * 128 * 128, eb2 + (size_t)s * L, eids, ea, ea16);
    k_agg<<<(NND + 3) / 4, 256, 0, stream>>>(ea16, startA, agg16);
    hipMemsetAsync(gS, 0, (size_t)2 * 64 * L * sizeof(float), stream);
    k_node_l1<<<ngrid, 256, 0, stream>>>(x16, agg16,
        nW1t + (size_t)s * 128 * 256, nb1 + (size_t)s * L, h1n, gS);
    k_bnfin<<<1, 128, 0, stream>>>(gS, ng1 + (size_t)s * L, nbe1 + (size_t)s * L,
        1.f / (float)NND, ss);
    k_node_l2<<<ngrid, 256, 0, stream>>>(h1n, ss,
        nW2t + (size_t)s * 128 * 128, nb2 + (size_t)s * L,
        (s == 0) ? in_x : x, x, x16);
  }
}

// Round 14
// 2035.094 us; speedup vs baseline: 1.4852x; 1.4852x over previous
//
#include <hip/hip_runtime.h>
#include <hip/hip_bf16.h>
#include <cstdint>
#include <cstddef>

#define E_N 600000
#define NND 50000
#define L 128
#define EGRID 4688              // ceil(E_N/128)
#define PBLK 16384              // u16 per 128-row panel-block (8*128*16)

typedef unsigned short u16;
typedef unsigned int u32;
typedef __attribute__((ext_vector_type(8))) short bf16x8;
typedef __attribute__((ext_vector_type(4))) float f32x4;

static __device__ __forceinline__ u16 f2bf(float f) {
  union { float f; u32 u; } c; c.f = f;
  return (u16)((c.u + 0x7fffu + ((c.u >> 16) & 1u)) >> 16);
}
static __device__ __forceinline__ u32 pk2(float a, float b) {
  return (u32)f2bf(a) | ((u32)f2bf(b) << 16);
}
static __device__ __forceinline__ float bf2f(u32 h) {
  union { u32 u; float f; } c; c.u = (h & 0xffffu) << 16; return c.f;
}
static __device__ __forceinline__ void atomAddF(float* p, float v) {
#if defined(__HIP_DEVICE_COMPILE__)
  unsafeAtomicAdd(p, v);
#else
  atomicAdd(p, v);
#endif
}
static __device__ __forceinline__ bf16x8 bnrelu8(bf16x8 raw, float4 sca, float4 scb,
                                                 float4 sha, float4 shb) {
  union { bf16x8 v; u16 h[8]; } in; in.v = raw;
  const float sc[8] = {sca.x, sca.y, sca.z, sca.w, scb.x, scb.y, scb.z, scb.w};
  const float sh[8] = {sha.x, sha.y, sha.z, sha.w, shb.x, shb.y, shb.z, shb.w};
  float f[8];
  #pragma unroll
  for (int i = 0; i < 8; ++i) f[i] = fmaxf(bf2f(in.h[i]) * sc[i] + sh[i], 0.f);
  union { bf16x8 v; u32 w[4]; } r;
  #pragma unroll
  for (int i = 0; i < 4; ++i) r.w[i] = pk2(f[2 * i], f[2 * i + 1]);
  return r.v;
}

#define MFMA(a, bfr, c) __builtin_amdgcn_mfma_f32_16x16x32_bf16((a), (bfr), (c), 0, 0, 0)

// panel-layout address (u16 units): row-block, panel p (=col/16), local row, col%16
static __device__ __forceinline__ size_t paddr(int row, int panel, int incol) {
  return (size_t)(row >> 7) * PBLK + (size_t)panel * 2048 + (size_t)(row & 127) * 16 + incol;
}

// ================= prepass kernels =================
__global__ __launch_bounds__(256) void k_cvt4(const float* __restrict__ in,
                                              u16* __restrict__ out, int n4) {
  const int i = blockIdx.x * 256 + threadIdx.x;
  if (i < n4) {
    const float4 v = *(const float4*)(in + (size_t)i * 4);
    uint2 o; o.x = pk2(v.x, v.y); o.y = pk2(v.z, v.w);
    *(uint2*)(out + (size_t)i * 4) = o;
  }
}

// in_ea (fp32, original order) -> ea16 (bf16, permuted panel layout)
__global__ __launch_bounds__(256) void k_cvtperm(const float* __restrict__ in_ea,
                                                 const int* __restrict__ perm,
                                                 u16* __restrict__ ea16) {
  const int i = blockIdx.x * 256 + threadIdx.x;
  const int row = i >> 4, part = i & 15;      // 16 threads/row, 8 cols each
  if (row < E_N) {
    const float* p = in_ea + (size_t)perm[row] * L + part * 8;
    const float4 f0 = *(const float4*)p, f1 = *(const float4*)(p + 4);
    union { bf16x8 v; u32 w[4]; } r;
    r.w[0] = pk2(f0.x, f0.y); r.w[1] = pk2(f0.z, f0.w);
    r.w[2] = pk2(f1.x, f1.y); r.w[3] = pk2(f1.z, f1.w);
    *(bf16x8*)(ea16 + paddr(row, part >> 1, (part & 1) * 8)) = r.v;
  }
}

__global__ void k_wt(const float* __restrict__ W, u16* __restrict__ Wt, int K) {
  const int idx = blockIdx.x * 256 + threadIdx.x;
  const int total = 4 * K * 128;
  if (idx >= total) return;
  const int s = idx / (K * 128);
  const int rem = idx - s * K * 128;
  const int n = rem / K;
  const int k = rem - n * K;
  Wt[idx] = f2bf(W[(size_t)s * K * 128 + (size_t)k * 128 + n]);
}

__global__ void k_hist(const int* __restrict__ dstI, int* __restrict__ cnt) {
  const int i = blockIdx.x * 256 + threadIdx.x;
  if (i < E_N) atomicAdd(&cnt[dstI[i]], 1);
}

__global__ __launch_bounds__(1024) void k_scan(const int* __restrict__ cnt, int* __restrict__ startA) {
  __shared__ int buf[1024];
  __shared__ int carry;
  const int tid = threadIdx.x;
  if (tid == 0) carry = 0;
  __syncthreads();
  for (int base = 0; base < NND; base += 1024) {
    int v = (base + tid < NND) ? cnt[base + tid] : 0;
    buf[tid] = v;
    __syncthreads();
    for (int off = 1; off < 1024; off <<= 1) {
      int t = (tid >= off) ? buf[tid - off] : 0;
      __syncthreads();
      buf[tid] += t;
      __syncthreads();
    }
    const int incl = buf[tid];
    const int c = carry;
    if (base + tid < NND) startA[base + tid] = c + incl - v;
    __syncthreads();
    if (tid == 1023) carry = c + incl;
    __syncthreads();
  }
  if (tid == 0) startA[NND] = carry;
}

__global__ void k_fill(const int* __restrict__ dstI, const int* __restrict__ startA,
                       int* __restrict__ cur, int* __restrict__ eids) {
  const int i = blockIdx.x * 256 + threadIdx.x;
  if (i < E_N) {
    const int d = dstI[i];
    const int pos = atomicAdd(&cur[d], 1);
    eids[startA[d] + pos] = i;
  }
}

__global__ void k_perm(const int* __restrict__ srcI, const int* __restrict__ dstI,
                       const int* __restrict__ perm,
                       int* __restrict__ srcP, int* __restrict__ dstP) {
  const int i = blockIdx.x * 256 + threadIdx.x;
  if (i < E_N) {
    const int e = perm[i];
    srcP[i] = srcI[e];
    dstP[i] = dstI[e];
  }
}

// ================= aggregation (panel ea16 -> row-major agg16) =================
__global__ __launch_bounds__(256) void k_agg(const u16* __restrict__ ea16,
                                             const int* __restrict__ startA,
                                             u16* __restrict__ agg16) {
  const int node = blockIdx.x * 4 + (threadIdx.x >> 6);
  const int lane = threadIdx.x & 63;
  if (node >= NND) return;
  const int s = startA[node], e = startA[node + 1];
  const size_t poff = (size_t)(lane >> 3) * 2048 + (size_t)((lane & 7) * 2);
  float a0 = 0.f, a1 = 0.f, b0 = 0.f, b1 = 0.f;
  int i = s;
  for (; i + 1 < e; i += 2) {
    const u32 v0 = *(const u32*)(ea16 + (size_t)(i >> 7) * PBLK + (size_t)(i & 127) * 16 + poff);
    const int j = i + 1;
    const u32 v1 = *(const u32*)(ea16 + (size_t)(j >> 7) * PBLK + (size_t)(j & 127) * 16 + poff);
    a0 += bf2f(v0); a1 += bf2f(v0 >> 16);
    b0 += bf2f(v1); b1 += bf2f(v1 >> 16);
  }
  if (i < e) {
    const u32 v = *(const u32*)(ea16 + (size_t)(i >> 7) * PBLK + (size_t)(i & 127) * 16 + poff);
    a0 += bf2f(v); a1 += bf2f(v >> 16);
  }
  *(u32*)(agg16 + (size_t)node * L + lane * 2) = pk2(a0 + b0, a1 + b1);
}

// ================= BN finalize =================
__global__ void k_bnfin(const float* __restrict__ gS, const float* __restrict__ g,
                        const float* __restrict__ be, float invM, float* __restrict__ ss) {
  const int c = threadIdx.x;
  float s1 = 0.f, s2 = 0.f;
  for (int j = 0; j < 64; ++j) { s1 += gS[j * L + c]; s2 += gS[64 * L + j * L + c]; }
  const float mean = s1 * invM;
  const float var = s2 * invM - mean * mean;
  const float sc = g[c] * rsqrtf(var + 1e-5f);
  ss[c] = sc;
  ss[L + c] = be[c] - mean * sc;
}

// ================= edge layer 1: wave-owns-16-rows, A private, W via 2-buffer LDS =================
// Wave wid owns rows row0+wid*16 .. +15 (one per lane l15), computes all 128 cols.
__global__ __launch_bounds__(512, 4) void k_edge_l1(
    const u16* __restrict__ x16, const u16* __restrict__ ea16,
    const int* __restrict__ srcP, const int* __restrict__ dstP,
    const u16* __restrict__ Wt, const float* __restrict__ b,
    u16* __restrict__ h1, float* __restrict__ gS)
{
  __shared__ __align__(16) char Ws2[2 * 16384];
  __shared__ float red[256];
  const int tid = threadIdx.x, bid = blockIdx.x, row0 = bid * 128;
  const int lane = tid & 63, wid = tid >> 6;
  const int l15 = lane & 15, lq = lane >> 4;
  if (tid < 256) red[tid] = 0.f;

  const int myrow = row0 + wid * 16 + l15;
  const int crow = min(myrow, E_N - 1);
  const int dI = dstP[crow], sI = srcP[crow];

  // private A fragments, rolling window
  bf16x8 af[6][2];
  auto loadA = [&](int cc) {
    if (cc < 4) {
      const int node = (cc < 2) ? dI : sI;
      const u16* p = x16 + (size_t)node * L + (cc & 1) * 64 + lq * 8;
      af[cc][0] = *(const bf16x8*)p;
      af[cc][1] = *(const bf16x8*)(p + 32);
    } else {
      const int pc = cc - 4;
      af[cc][0] = *(const bf16x8*)(ea16 + paddr(crow, pc * 4 + (lq >> 1), (lq & 1) * 8));
      af[cc][1] = *(const bf16x8*)(ea16 + paddr(crow, pc * 4 + 2 + (lq >> 1), (lq & 1) * 8));
    }
  };
  loadA(0); loadA(1); loadA(2);

  // W staging: 1024 16B-slots per chunk; linear LDS write, pre-swizzled global source
  const int n0 = tid >> 3,         kq0 = (tid & 7) ^ (n0 & 7);
  const int n1 = (tid + 512) >> 3, kq1 = ((tid + 512) & 7) ^ (n1 & 7);
  uint4 wa, wb;
  auto wload = [&](int cc) {
    wa = *(const uint4*)(Wt + (size_t)n0 * 384 + cc * 64 + kq0 * 8);
    wb = *(const uint4*)(Wt + (size_t)n1 * 384 + cc * 64 + kq1 * 8);
  };
  auto wwrite = [&](int buf) {
    *(uint4*)(Ws2 + buf * 16384 + tid * 16) = wa;
    *(uint4*)(Ws2 + buf * 16384 + tid * 16 + 8192) = wb;
  };

  wload(0);
  wwrite(0);
  __syncthreads();

  f32x4 acc[8];
  #pragma unroll
  for (int cg = 0; cg < 8; ++cg) acc[cg] = (f32x4){0.f, 0.f, 0.f, 0.f};

  #pragma unroll
  for (int cc = 0; cc < 6; ++cc) {
    if (cc + 1 < 6) wload(cc + 1);     // L2-hot, 1-iter cover
    if (cc + 3 < 6) loadA(cc + 3);     // gathers, 3-iter cover
    const char* base = Ws2 + (cc & 1) * 16384;
    #pragma unroll
    for (int cg = 0; cg < 8; ++cg) {
      const int n = cg * 16 + l15;
      const int sw = (n & 7) << 4;
      #pragma unroll
      for (int k2 = 0; k2 < 2; ++k2) {
        const bf16x8 wf = *(const bf16x8*)(base + ((n * 128 + k2 * 64 + lq * 16) ^ sw));
        acc[cg] = MFMA(wf, af[cc][k2], acc[cg]);   // C^T: lane row = edge row
      }
    }
    if (cc + 1 < 6) wwrite((cc + 1) & 1);
    __syncthreads();
  }

  // epilogue: bias, stats (shfl over l15 + LDS atomics), coalesced panel stores
  const bool valid = myrow < E_N;
  u16* hp = h1 + (size_t)bid * PBLK + (size_t)(wid * 16 + l15) * 16 + lq * 4;
  #pragma unroll
  for (int cg = 0; cg < 8; ++cg) {
    float o[4], s1[4], s2[4];
    #pragma unroll
    for (int r = 0; r < 4; ++r) {
      o[r] = acc[cg][r] + b[cg * 16 + lq * 4 + r];
      s1[r] = valid ? o[r] : 0.f;
      s2[r] = valid ? o[r] * o[r] : 0.f;
    }
    if (valid) {
      ushort4 st;
      st.x = f2bf(o[0]); st.y = f2bf(o[1]); st.z = f2bf(o[2]); st.w = f2bf(o[3]);
      *(ushort4*)(hp + cg * 2048) = st;
    }
    #pragma unroll
    for (int off = 1; off < 16; off <<= 1)
      #pragma unroll
      for (int r = 0; r < 4; ++r) {
        s1[r] += __shfl_xor(s1[r], off);
        s2[r] += __shfl_xor(s2[r], off);
      }
    if (l15 == 0) {
      #pragma unroll
      for (int r = 0; r < 4; ++r) {
        atomAddF(&red[cg * 16 + lq * 4 + r], s1[r]);
        atomAddF(&red[128 + cg * 16 + lq * 4 + r], s2[r]);
      }
    }
  }
  __syncthreads();
  const int slot = (bid & 63) * L;
  if (tid < 128) atomAddF(&gS[slot + tid], red[tid]);
  else if (tid < 256) atomAddF(&gS[64 * L + slot + (tid - 128)], red[tid]);
}

// ================= edge layer 2: wave-owns-16-rows, W staged once (32 KB) =================
template <bool WF32>
__global__ __launch_bounds__(512, 4) void k_edge_l2(
    const u16* __restrict__ h1, const float* __restrict__ ss,
    const u16* __restrict__ Wt, const float* __restrict__ b,
    const int* __restrict__ perm,
    float* __restrict__ ea_out, u16* __restrict__ ea16)
{
  __shared__ __align__(16) char Ws2[2 * 16384];
  const int tid = threadIdx.x, bid = blockIdx.x, row0 = bid * 128;
  const int lane = tid & 63, wid = tid >> 6;
  const int l15 = lane & 15, lq = lane >> 4;

  const int myrow = row0 + wid * 16 + l15;
  const int crow = min(myrow, E_N - 1);

  // stage both W chunks (linear write, pre-swizzled source)
  const int n0 = tid >> 3,         kq0 = (tid & 7) ^ (n0 & 7);
  const int n1 = (tid + 512) >> 3, kq1 = ((tid + 512) & 7) ^ (n1 & 7);
  #pragma unroll
  for (int cc = 0; cc < 2; ++cc) {
    const uint4 wa = *(const uint4*)(Wt + (size_t)n0 * 128 + cc * 64 + kq0 * 8);
    const uint4 wb = *(const uint4*)(Wt + (size_t)n1 * 128 + cc * 64 + kq1 * 8);
    *(uint4*)(Ws2 + cc * 16384 + tid * 16) = wa;
    *(uint4*)(Ws2 + cc * 16384 + tid * 16 + 8192) = wb;
  }

  // private A (h1 panel), raw
  bf16x8 ah[2][2];
  #pragma unroll
  for (int cc = 0; cc < 2; ++cc)
    #pragma unroll
    for (int k2 = 0; k2 < 2; ++k2)
      ah[cc][k2] = *(const bf16x8*)(h1 + paddr(crow, cc * 4 + k2 * 2 + (lq >> 1), (lq & 1) * 8));
  __syncthreads();

  f32x4 acc[8];
  #pragma unroll
  for (int cg = 0; cg < 8; ++cg) acc[cg] = (f32x4){0.f, 0.f, 0.f, 0.f};

  #pragma unroll
  for (int cc = 0; cc < 2; ++cc)
    #pragma unroll
    for (int k2 = 0; k2 < 2; ++k2) {
      const int kb = cc * 64 + k2 * 32 + lq * 8;
      const float4 sca = *(const float4*)(ss + kb), scb = *(const float4*)(ss + kb + 4);
      const float4 sha = *(const float4*)(ss + 128 + kb), shb = *(const float4*)(ss + 128 + kb + 4);
      const bf16x8 afr = bnrelu8(ah[cc][k2], sca, scb, sha, shb);
      const char* base = Ws2 + cc * 16384;
      #pragma unroll
      for (int cg = 0; cg < 8; ++cg) {
        const int n = cg * 16 + l15;
        const int sw = (n & 7) << 4;
        const bf16x8 wf = *(const bf16x8*)(base + ((n * 128 + k2 * 64 + lq * 16) ^ sw));
        acc[cg] = MFMA(wf, afr, acc[cg]);
      }
    }

  // epilogue: o = relu(acc+bias) + resid (in-place panel RMW); fp32 scatter at s=3
  const bool valid = myrow < E_N;
  const int prow = (WF32 && valid) ? perm[myrow] : 0;
  u16* ep = ea16 + (size_t)bid * PBLK + (size_t)(wid * 16 + l15) * 16 + lq * 4;
  #pragma unroll
  for (int cg = 0; cg < 8; ++cg) {
    if (valid) {
      float o[4];
      #pragma unroll
      for (int r = 0; r < 4; ++r) o[r] = fmaxf(acc[cg][r] + b[cg * 16 + lq * 4 + r], 0.f);
      const ushort4 rv = *(const ushort4*)(ep + cg * 2048);
      o[0] += bf2f(rv.x); o[1] += bf2f(rv.y); o[2] += bf2f(rv.z); o[3] += bf2f(rv.w);
      ushort4 st;
      st.x = f2bf(o[0]); st.y = f2bf(o[1]); st.z = f2bf(o[2]); st.w = f2bf(o[3]);
      *(ushort4*)(ep + cg * 2048) = st;
      if (WF32) {
        float4 fv; fv.x = o[0]; fv.y = o[1]; fv.z = o[2]; fv.w = o[3];
        *(float4*)(ea_out + (size_t)prow * L + cg * 16 + lq * 4) = fv;
      }
    }
  }
}

// ================= node layer 1 (x16 + agg16 bf16, row-major) =================
__global__ __launch_bounds__(256) void k_node_l1(
    const u16* __restrict__ x16, const u16* __restrict__ agg16,
    const u16* __restrict__ Wt, const float* __restrict__ b,
    u16* __restrict__ h1, float* __restrict__ gS)
{
  __shared__ __align__(16) char Bs[2][16384];
  __shared__ float red[256];
  const int tid = threadIdx.x, bid = blockIdx.x, row0 = bid * 64;
  red[tid] = 0.f;
  const int lane = tid & 63, wid = tid >> 6, wr = wid >> 1, wc = wid & 1;
  const int l15 = lane & 15, lq = lane >> 4;
  const int r0 = row0 + wr * 32 + l15, r1 = r0 + 16;
  const int rr0 = min(r0, NND - 1), rr1 = min(r1, NND - 1);

  const u16* aP[2][2];
  aP[0][0] = x16 + (size_t)rr0 * L;   aP[1][0] = x16 + (size_t)rr1 * L;
  aP[0][1] = agg16 + (size_t)rr0 * L; aP[1][1] = agg16 + (size_t)rr1 * L;

  f32x4 acc[2][4];
  #pragma unroll
  for (int m = 0; m < 2; ++m)
    #pragma unroll
    for (int n = 0; n < 4; ++n) acc[m][n] = (f32x4){0.f, 0.f, 0.f, 0.f};

  auto loadA = [&](int c, bf16x8 (&af)[2][2]) {
    const int seg = c >> 1;
    const int base = (c & 1) * 64 + lq * 8;
    #pragma unroll
    for (int k2 = 0; k2 < 2; ++k2) {
      af[0][k2] = *(const bf16x8*)(aP[0][seg] + base + k2 * 32);
      af[1][k2] = *(const bf16x8*)(aP[1][seg] + base + k2 * 32);
    }
  };
  auto stage = [&](int c, int buf) {
    #pragma unroll
    for (int i = 0; i < 4; ++i) {
      const int slot = tid + i * 256;
      const int n = slot >> 3, kq = slot & 7;
      const uint4 v = *(const uint4*)(Wt + (size_t)n * 256 + c * 64 + kq * 8);
      *(uint4*)(&Bs[buf][0] + ((n * 128 + kq * 16) ^ ((n & 7) << 4))) = v;
    }
  };

  bf16x8 aCur[2][2], aNxt[2][2];
  loadA(0, aCur);
  stage(0, 0);
  __syncthreads();
  #pragma unroll
  for (int c = 0; c < 4; ++c) {
    if (c + 1 < 4) loadA(c + 1, aNxt);
    {
      const char* base = &Bs[c & 1][0];
      #pragma unroll
      for (int k2 = 0; k2 < 2; ++k2)
        #pragma unroll
        for (int n = 0; n < 4; ++n) {
          const int ncol = wc * 64 + n * 16 + l15;
          const bf16x8 bfr = *(const bf16x8*)(base + ((ncol * 128 + k2 * 64 + lq * 16) ^ ((ncol & 7) << 4)));
          acc[0][n] = MFMA(aCur[0][k2], bfr, acc[0][n]);
          acc[1][n] = MFMA(aCur[1][k2], bfr, acc[1][n]);
        }
    }
    if (c + 1 < 4) stage(c + 1, (c + 1) & 1);
    __syncthreads();
    #pragma unroll
    for (int m = 0; m < 2; ++m)
      #pragma unroll
      for (int k2 = 0; k2 < 2; ++k2) aCur[m][k2] = aNxt[m][k2];
  }

  float bb[4], s1[4], s2[4];
  #pragma unroll
  for (int n = 0; n < 4; ++n) { bb[n] = b[wc * 64 + n * 16 + l15]; s1[n] = 0.f; s2[n] = 0.f; }
  #pragma unroll
  for (int m = 0; m < 2; ++m)
    #pragma unroll
    for (int n = 0; n < 4; ++n) {
      const int ncol = wc * 64 + n * 16 + l15;
      #pragma unroll
      for (int r = 0; r < 4; ++r) {
        const int row = row0 + wr * 32 + m * 16 + lq * 4 + r;
        if (row < NND) {
          const float o = acc[m][n][r] + bb[n];
          s1[n] += o; s2[n] += o * o;
          h1[(size_t)row * L + ncol] = f2bf(o);
        }
      }
    }
  #pragma unroll
  for (int n = 0; n < 4; ++n) {
    const int ncol = wc * 64 + n * 16 + l15;
    atomAddF(&red[ncol], s1[n]);
    atomAddF(&red[128 + ncol], s2[n]);
  }
  __syncthreads();
  const int slot = (bid & 63) * L;
  if (tid < 128) atomAddF(&gS[slot + tid], red[tid]);
  else atomAddF(&gS[64 * L + slot + (tid - 128)], red[tid]);
}

// ================= node layer 2 =================
__global__ __launch_bounds__(256) void k_node_l2(
    const u16* __restrict__ h1, const float* __restrict__ ss,
    const u16* __restrict__ Wt, const float* __restrict__ b,
    const float* __restrict__ resid, float* __restrict__ x_out,
    u16* __restrict__ x16)
{
  __shared__ __align__(16) char Bs[2][16384];
  const int tid = threadIdx.x, bid = blockIdx.x, row0 = bid * 64;
  const int lane = tid & 63, wid = tid >> 6, wr = wid >> 1, wc = wid & 1;
  const int l15 = lane & 15, lq = lane >> 4;
  const int r0 = row0 + wr * 32 + l15, r1 = r0 + 16;
  const int rr0 = min(r0, NND - 1), rr1 = min(r1, NND - 1);
  const u16* a0 = h1 + (size_t)rr0 * L + lq * 8;
  const u16* a1 = h1 + (size_t)rr1 * L + lq * 8;

  f32x4 acc[2][4];
  #pragma unroll
  for (int m = 0; m < 2; ++m)
    #pragma unroll
    for (int n = 0; n < 4; ++n) acc[m][n] = (f32x4){0.f, 0.f, 0.f, 0.f};

  auto stage = [&](int c, int buf) {
    #pragma unroll
    for (int i = 0; i < 4; ++i) {
      const int slot = tid + i * 256;
      const int n = slot >> 3, kq = slot & 7;
      const uint4 v = *(const uint4*)(Wt + (size_t)n * 128 + c * 64 + kq * 8);
      *(uint4*)(&Bs[buf][0] + ((n * 128 + kq * 16) ^ ((n & 7) << 4))) = v;
    }
  };
  stage(0, 0);
  stage(1, 1);
  bf16x8 raw[2][2][2];
  #pragma unroll
  for (int c = 0; c < 2; ++c)
    #pragma unroll
    for (int k2 = 0; k2 < 2; ++k2) {
      raw[c][0][k2] = *(const bf16x8*)(a0 + c * 64 + k2 * 32);
      raw[c][1][k2] = *(const bf16x8*)(a1 + c * 64 + k2 * 32);
    }
  __syncthreads();

  #pragma unroll
  for (int c = 0; c < 2; ++c) {
    bf16x8 af[2][2];
    #pragma unroll
    for (int k2 = 0; k2 < 2; ++k2) {
      const int kg = c * 64 + k2 * 32 + lq * 8;
      const float4 sca = *(const float4*)(ss + kg), scb = *(const float4*)(ss + kg + 4);
      const float4 sha = *(const float4*)(ss + 128 + kg), shb = *(const float4*)(ss + 128 + kg + 4);
      af[0][k2] = bnrelu8(raw[c][0][k2], sca, scb, sha, shb);
      af[1][k2] = bnrelu8(raw[c][1][k2], sca, scb, sha, shb);
    }
    const char* base = &Bs[c][0];
    #pragma unroll
    for (int k2 = 0; k2 < 2; ++k2)
      #pragma unroll
      for (int n = 0; n < 4; ++n) {
        const int ncol = wc * 64 + n * 16 + l15;
        const bf16x8 bfr = *(const bf16x8*)(base + ((ncol * 128 + k2 * 64 + lq * 16) ^ ((ncol & 7) << 4)));
        acc[0][n] = MFMA(af[0][k2], bfr, acc[0][n]);
        acc[1][n] = MFMA(af[1][k2], bfr, acc[1][n]);
      }
  }

  float bb[4];
  #pragma unroll
  for (int n = 0; n < 4; ++n) bb[n] = b[wc * 64 + n * 16 + l15];
  #pragma unroll
  for (int m = 0; m < 2; ++m)
    #pragma unroll
    for (int n = 0; n < 4; ++n) {
      const int ncol = wc * 64 + n * 16 + l15;
      #pragma unroll
      for (int r = 0; r < 4; ++r) {
        const int row = row0 + wr * 32 + m * 16 + lq * 4 + r;
        if (row < NND) {
          const float o = fmaxf(acc[m][n][r] + bb[n], 0.f) + resid[(size_t)row * L + ncol];
          x_out[(size_t)row * L + ncol] = o;
          x16[(size_t)row * L + ncol] = f2bf(o);
        }
      }
    }
}

extern "C" void kernel_launch(void* const* d_in, const int* in_sizes, int n_in,
                              void* d_out, int out_size, void* d_ws, size_t ws_size,
                              hipStream_t stream) {
  (void)in_sizes; (void)n_in; (void)out_size; (void)ws_size;
  const float* in_x  = (const float*)d_in[0];
  const float* in_ea = (const float*)d_in[1];
  const int*   ei    = (const int*)d_in[2];
  const float* eW1 = (const float*)d_in[3];
  const float* eb1 = (const float*)d_in[4];
  const float* eg1 = (const float*)d_in[5];
  const float* ebe1= (const float*)d_in[6];
  const float* eW2 = (const float*)d_in[7];
  const float* eb2 = (const float*)d_in[8];
  const float* nW1 = (const float*)d_in[9];
  const float* nb1 = (const float*)d_in[10];
  const float* ng1 = (const float*)d_in[11];
  const float* nbe1= (const float*)d_in[12];
  const float* nW2 = (const float*)d_in[13];
  const float* nb2 = (const float*)d_in[14];

  float* x  = (float*)d_out;                    // [NND][L]
  float* ea = (float*)d_out + (size_t)NND * L;  // [E_N][L]

  char* w = (char*)d_ws;
  u16* h1e   = (u16*)w;   w += (size_t)EGRID * PBLK * sizeof(u16);  // panel layout
  u16* ea16  = (u16*)w;   w += (size_t)EGRID * PBLK * sizeof(u16);  // panel layout
  u16* h1n   = (u16*)w;   w += (size_t)NND * L * sizeof(u16);
  u16* x16   = (u16*)w;   w += (size_t)NND * L * sizeof(u16);
  u16* agg16 = (u16*)w;   w += (size_t)NND * L * sizeof(u16);
  float* gS  = (float*)w; w += (size_t)2 * 64 * L * sizeof(float);
  float* ss  = (float*)w; w += 4096;
  u16* eW1t = (u16*)w;   w += (size_t)4 * 128 * 384 * sizeof(u16);
  u16* eW2t = (u16*)w;   w += (size_t)4 * 128 * 128 * sizeof(u16);
  u16* nW1t = (u16*)w;   w += (size_t)4 * 128 * 256 * sizeof(u16);
  u16* nW2t = (u16*)w;   w += (size_t)4 * 128 * 128 * sizeof(u16);
  int* cnt    = (int*)w; w += (size_t)NND * sizeof(int);
  int* cur    = (int*)w; w += (size_t)NND * sizeof(int);
  int* startA = (int*)w; w += (size_t)(NND + 64) * sizeof(int);
  int* eids   = (int*)w; w += (size_t)E_N * sizeof(int);     // = perm
  int* srcP   = (int*)w; w += (size_t)E_N * sizeof(int);
  int* dstP   = (int*)w; w += (size_t)E_N * sizeof(int);

  const int* srcI = ei;
  const int* dstI = ei + E_N;

  k_cvt4<<<(NND * L / 4 + 255) / 256, 256, 0, stream>>>(in_x, x16, NND * L / 4);
  k_wt<<<(4 * 384 * 128 + 255) / 256, 256, 0, stream>>>(eW1, eW1t, 384);
  k_wt<<<(4 * 128 * 128 + 255) / 256, 256, 0, stream>>>(eW2, eW2t, 128);
  k_wt<<<(4 * 256 * 128 + 255) / 256, 256, 0, stream>>>(nW1, nW1t, 256);
  k_wt<<<(4 * 128 * 128 + 255) / 256, 256, 0, stream>>>(nW2, nW2t, 128);
  hipMemsetAsync(cnt, 0, (size_t)NND * sizeof(int), stream);
  hipMemsetAsync(cur, 0, (size_t)NND * sizeof(int), stream);
  k_hist<<<(E_N + 255) / 256, 256, 0, stream>>>(dstI, cnt);
  k_scan<<<1, 1024, 0, stream>>>(cnt, startA);
  k_fill<<<(E_N + 255) / 256, 256, 0, stream>>>(dstI, startA, cur, eids);
  k_perm<<<(E_N + 255) / 256, 256, 0, stream>>>(srcI, dstI, eids, srcP, dstP);
  k_cvtperm<<<(E_N * 16 + 255) / 256, 256, 0, stream>>>(in_ea, eids, ea16);

  const int ngrid = (NND + 63) / 64;     // 782

  for (int s = 0; s < 4; ++s) {
    hipMemsetAsync(gS, 0, (size_t)2 * 64 * L * sizeof(float), stream);
    k_edge_l1<<<EGRID, 512, 0, stream>>>(x16, ea16, srcP, dstP,
        eW1t + (size_t)s * 128 * 384, eb1 + (size_t)s * L, h1e, gS);
    k_bnfin<<<1, 128, 0, stream>>>(gS, eg1 + (size_t)s * L, ebe1 + (size_t)s * L,
        1.f / (float)E_N, ss);
    if (s < 3)
      k_edge_l2<false><<<EGRID, 512, 0, stream>>>(h1e, ss,
          eW2t + (size_t)s * 128 * 128, eb2 + (size_t)s * L, eids, ea, ea16);
    else
      k_edge_l2<true><<<EGRID, 512, 0, stream>>>(h1e, ss,
          eW2t + (size_t)s * 128 * 128, eb2 + (size_t)s * L, eids, ea, ea16);
    k_agg<<<(NND + 3) / 4, 256, 0, stream>>>(ea16, startA, agg16);
    hipMemsetAsync(gS, 0, (size_t)2 * 64 * L * sizeof(float), stream);
    k_node_l1<<<ngrid, 256, 0, stream>>>(x16, agg16,
        nW1t + (size_t)s * 128 * 256, nb1 + (size_t)s * L, h1n, gS);
    k_bnfin<<<1, 128, 0, stream>>>(gS, ng1 + (size_t)s * L, nbe1 + (size_t)s * L,
        1.f / (float)NND, ss);
    k_node_l2<<<ngrid, 256, 0, stream>>>(h1n, ss,
        nW2t + (size_t)s * 128 * 128, nb2 + (size_t)s * L,
        (s == 0) ? in_x : x, x, x16);
  }
}

// Round 15
// 2004.882 us; speedup vs baseline: 1.5076x; 1.0151x over previous
//
#include <hip/hip_runtime.h>
#include <hip/hip_bf16.h>
#include <cstdint>
#include <cstddef>

#define E_N 600000
#define NND 50000
#define L 128
#define EGRID 4688              // ceil(E_N/128)
#define PBLK 16384              // u16 per 128-row panel-block (8*128*16)

typedef unsigned short u16;
typedef unsigned int u32;
typedef __attribute__((ext_vector_type(8))) short bf16x8;
typedef __attribute__((ext_vector_type(4))) float f32x4;

static __device__ __forceinline__ u16 f2bf(float f) {
  union { float f; u32 u; } c; c.f = f;
  return (u16)((c.u + 0x7fffu + ((c.u >> 16) & 1u)) >> 16);
}
static __device__ __forceinline__ u32 pk2(float a, float b) {
  return (u32)f2bf(a) | ((u32)f2bf(b) << 16);
}
static __device__ __forceinline__ float bf2f(u32 h) {
  union { u32 u; float f; } c; c.u = (h & 0xffffu) << 16; return c.f;
}
static __device__ __forceinline__ void atomAddF(float* p, float v) {
#if defined(__HIP_DEVICE_COMPILE__)
  unsafeAtomicAdd(p, v);
#else
  atomicAdd(p, v);
#endif
}
static __device__ __forceinline__ bf16x8 bnrelu8(bf16x8 raw, float4 sca, float4 scb,
                                                 float4 sha, float4 shb) {
  union { bf16x8 v; u16 h[8]; } in; in.v = raw;
  const float sc[8] = {sca.x, sca.y, sca.z, sca.w, scb.x, scb.y, scb.z, scb.w};
  const float sh[8] = {sha.x, sha.y, sha.z, sha.w, shb.x, shb.y, shb.z, shb.w};
  float f[8];
  #pragma unroll
  for (int i = 0; i < 8; ++i) f[i] = fmaxf(bf2f(in.h[i]) * sc[i] + sh[i], 0.f);
  union { bf16x8 v; u32 w[4]; } r;
  #pragma unroll
  for (int i = 0; i < 4; ++i) r.w[i] = pk2(f[2 * i], f[2 * i + 1]);
  return r.v;
}

#define MFMA(a, bfr, c) __builtin_amdgcn_mfma_f32_16x16x32_bf16((a), (bfr), (c), 0, 0, 0)

// panel-layout address (u16 units): row-block, panel p (=col/16), local row, col%16
static __device__ __forceinline__ size_t paddr(int row, int panel, int incol) {
  return (size_t)(row >> 7) * PBLK + (size_t)panel * 2048 + (size_t)(row & 127) * 16 + incol;
}

// ================= prepass kernels =================
__global__ __launch_bounds__(256) void k_cvt4(const float* __restrict__ in,
                                              u16* __restrict__ out, int n4) {
  const int i = blockIdx.x * 256 + threadIdx.x;
  if (i < n4) {
    const float4 v = *(const float4*)(in + (size_t)i * 4);
    uint2 o; o.x = pk2(v.x, v.y); o.y = pk2(v.z, v.w);
    *(uint2*)(out + (size_t)i * 4) = o;
  }
}

// in_ea (fp32, original order) -> ea16 (bf16, permuted panel layout)
__global__ __launch_bounds__(256) void k_cvtperm(const float* __restrict__ in_ea,
                                                 const int* __restrict__ perm,
                                                 u16* __restrict__ ea16) {
  const int i = blockIdx.x * 256 + threadIdx.x;
  const int row = i >> 4, part = i & 15;      // 16 threads/row, 8 cols each
  if (row < E_N) {
    const float* p = in_ea + (size_t)perm[row] * L + part * 8;
    const float4 f0 = *(const float4*)p, f1 = *(const float4*)(p + 4);
    union { bf16x8 v; u32 w[4]; } r;
    r.w[0] = pk2(f0.x, f0.y); r.w[1] = pk2(f0.z, f0.w);
    r.w[2] = pk2(f1.x, f1.y); r.w[3] = pk2(f1.z, f1.w);
    *(bf16x8*)(ea16 + paddr(row, part >> 1, (part & 1) * 8)) = r.v;
  }
}

__global__ void k_wt(const float* __restrict__ W, u16* __restrict__ Wt, int K) {
  const int idx = blockIdx.x * 256 + threadIdx.x;
  const int total = 4 * K * 128;
  if (idx >= total) return;
  const int s = idx / (K * 128);
  const int rem = idx - s * K * 128;
  const int n = rem / K;
  const int k = rem - n * K;
  Wt[idx] = f2bf(W[(size_t)s * K * 128 + (size_t)k * 128 + n]);
}

__global__ void k_hist(const int* __restrict__ dstI, int* __restrict__ cnt) {
  const int i = blockIdx.x * 256 + threadIdx.x;
  if (i < E_N) atomicAdd(&cnt[dstI[i]], 1);
}

__global__ __launch_bounds__(1024) void k_scan(const int* __restrict__ cnt, int* __restrict__ startA) {
  __shared__ int buf[1024];
  __shared__ int carry;
  const int tid = threadIdx.x;
  if (tid == 0) carry = 0;
  __syncthreads();
  for (int base = 0; base < NND; base += 1024) {
    int v = (base + tid < NND) ? cnt[base + tid] : 0;
    buf[tid] = v;
    __syncthreads();
    for (int off = 1; off < 1024; off <<= 1) {
      int t = (tid >= off) ? buf[tid - off] : 0;
      __syncthreads();
      buf[tid] += t;
      __syncthreads();
    }
    const int incl = buf[tid];
    const int c = carry;
    if (base + tid < NND) startA[base + tid] = c + incl - v;
    __syncthreads();
    if (tid == 1023) carry = c + incl;
    __syncthreads();
  }
  if (tid == 0) startA[NND] = carry;
}

__global__ void k_fill(const int* __restrict__ dstI, const int* __restrict__ startA,
                       int* __restrict__ cur, int* __restrict__ eids) {
  const int i = blockIdx.x * 256 + threadIdx.x;
  if (i < E_N) {
    const int d = dstI[i];
    const int pos = atomicAdd(&cur[d], 1);
    eids[startA[d] + pos] = i;
  }
}

__global__ void k_perm(const int* __restrict__ srcI, const int* __restrict__ dstI,
                       const int* __restrict__ perm,
                       int* __restrict__ srcP, int* __restrict__ dstP) {
  const int i = blockIdx.x * 256 + threadIdx.x;
  if (i < E_N) {
    const int e = perm[i];
    srcP[i] = srcI[e];
    dstP[i] = dstI[e];
  }
}

// ================= aggregation (panel ea16 -> row-major agg16) =================
__global__ __launch_bounds__(256) void k_agg(const u16* __restrict__ ea16,
                                             const int* __restrict__ startA,
                                             u16* __restrict__ agg16) {
  const int node = blockIdx.x * 4 + (threadIdx.x >> 6);
  const int lane = threadIdx.x & 63;
  if (node >= NND) return;
  const int s = startA[node], e = startA[node + 1];
  const size_t poff = (size_t)(lane >> 3) * 2048 + (size_t)((lane & 7) * 2);
  float a0 = 0.f, a1 = 0.f, b0 = 0.f, b1 = 0.f;
  int i = s;
  for (; i + 1 < e; i += 2) {
    const u32 v0 = *(const u32*)(ea16 + (size_t)(i >> 7) * PBLK + (size_t)(i & 127) * 16 + poff);
    const int j = i + 1;
    const u32 v1 = *(const u32*)(ea16 + (size_t)(j >> 7) * PBLK + (size_t)(j & 127) * 16 + poff);
    a0 += bf2f(v0); a1 += bf2f(v0 >> 16);
    b0 += bf2f(v1); b1 += bf2f(v1 >> 16);
  }
  if (i < e) {
    const u32 v = *(const u32*)(ea16 + (size_t)(i >> 7) * PBLK + (size_t)(i & 127) * 16 + poff);
    a0 += bf2f(v); a1 += bf2f(v >> 16);
  }
  *(u32*)(agg16 + (size_t)node * L + lane * 2) = pk2(a0 + b0, a1 + b1);
}

// ================= BN finalize =================
__global__ void k_bnfin(const float* __restrict__ gS, const float* __restrict__ g,
                        const float* __restrict__ be, float invM, float* __restrict__ ss) {
  const int c = threadIdx.x;
  float s1 = 0.f, s2 = 0.f;
  for (int j = 0; j < 64; ++j) { s1 += gS[j * L + c]; s2 += gS[64 * L + j * L + c]; }
  const float mean = s1 * invM;
  const float var = s2 * invM - mean * mean;
  const float sc = g[c] * rsqrtf(var + 1e-5f);
  ss[c] = sc;
  ss[L + c] = be[c] - mean * sc;
}

// ================= edge layer 1: 2D wave tile (32 rows x 64 cols), A private, W via 2-buffer LDS =================
// wave (wr,wc): rows wr*32 + m*16 + l15 (m=0,1), cols wc*64 + n*16 + lq*4 + r (n=0..3)
__global__ __launch_bounds__(512, 4) void k_edge_l1(
    const u16* __restrict__ x16, const u16* __restrict__ ea16,
    const int* __restrict__ srcP, const int* __restrict__ dstP,
    const u16* __restrict__ Wt, const float* __restrict__ b,
    u16* __restrict__ h1, float* __restrict__ gS)
{
  __shared__ __align__(16) char Ws2[2 * 16384];
  __shared__ float red[256];
  const int tid = threadIdx.x, bid = blockIdx.x, row0 = bid * 128;
  const int lane = tid & 63, wid = tid >> 6;
  const int wr = wid >> 1, wc = wid & 1;
  const int l15 = lane & 15, lq = lane >> 4;
  if (tid < 256) red[tid] = 0.f;

  int crw[2], dI[2], sI[2];
  #pragma unroll
  for (int m = 0; m < 2; ++m) {
    crw[m] = min(row0 + wr * 32 + m * 16 + l15, E_N - 1);
    dI[m] = dstP[crw[m]];
    sI[m] = srcP[crw[m]];
  }

  // private A fragments, 3-deep rolling window: af3[cc%3][m][k2]
  bf16x8 af3[3][2][2];
  auto loadA = [&](int cc, bf16x8 (&dst)[2][2]) {
    #pragma unroll
    for (int m = 0; m < 2; ++m) {
      if (cc < 4) {
        const int node = (cc < 2) ? dI[m] : sI[m];
        const u16* p = x16 + (size_t)node * L + (cc & 1) * 64 + lq * 8;
        dst[m][0] = *(const bf16x8*)p;
        dst[m][1] = *(const bf16x8*)(p + 32);
      } else {
        const int pc = cc - 4;
        dst[m][0] = *(const bf16x8*)(ea16 + paddr(crw[m], pc * 4 + (lq >> 1), (lq & 1) * 8));
        dst[m][1] = *(const bf16x8*)(ea16 + paddr(crw[m], pc * 4 + 2 + (lq >> 1), (lq & 1) * 8));
      }
    }
  };
  loadA(0, af3[0]); loadA(1, af3[1]); loadA(2, af3[2]);

  // W staging: linear LDS write, pre-swizzled global source
  const int n0 = tid >> 3,         kq0 = (tid & 7) ^ (n0 & 7);
  const int n1 = (tid + 512) >> 3, kq1 = ((tid + 512) & 7) ^ (n1 & 7);
  uint4 wa, wb;
  auto wload = [&](int cc) {
    wa = *(const uint4*)(Wt + (size_t)n0 * 384 + cc * 64 + kq0 * 8);
    wb = *(const uint4*)(Wt + (size_t)n1 * 384 + cc * 64 + kq1 * 8);
  };
  auto wwrite = [&](int buf) {
    *(uint4*)(Ws2 + buf * 16384 + tid * 16) = wa;
    *(uint4*)(Ws2 + buf * 16384 + tid * 16 + 8192) = wb;
  };

  wload(0);
  wwrite(0);
  __syncthreads();

  f32x4 acc[2][4];
  #pragma unroll
  for (int m = 0; m < 2; ++m)
    #pragma unroll
    for (int n = 0; n < 4; ++n) acc[m][n] = (f32x4){0.f, 0.f, 0.f, 0.f};

  #pragma unroll
  for (int cc = 0; cc < 6; ++cc) {
    if (cc + 1 < 6) wload(cc + 1);
    const char* base = Ws2 + (cc & 1) * 16384;
    const bf16x8 (&af)[2][2] = af3[cc % 3];
    #pragma unroll
    for (int k2 = 0; k2 < 2; ++k2)
      #pragma unroll
      for (int n = 0; n < 4; ++n) {
        const int ncol = wc * 64 + n * 16 + l15;
        const int sw = (ncol & 7) << 4;
        const bf16x8 wf = *(const bf16x8*)(base + ((ncol * 128 + k2 * 64 + lq * 16) ^ sw));
        acc[0][n] = MFMA(wf, af[0][k2], acc[0][n]);
        acc[1][n] = MFMA(wf, af[1][k2], acc[1][n]);
      }
    if (cc + 3 < 6) loadA(cc + 3, af3[cc % 3]);
    if (cc + 1 < 6) wwrite((cc + 1) & 1);
    __syncthreads();
  }

  // epilogue: bias, stats, ushort4 panel stores (C^T: row=wr*32+m*16+l15, col=wc*64+n*16+lq*4+r)
  #pragma unroll
  for (int m = 0; m < 2; ++m) {
    const int rl = wr * 32 + m * 16 + l15;
    const bool valid = row0 + rl < E_N;
    #pragma unroll
    for (int n = 0; n < 4; ++n) {
      const int colb = wc * 64 + n * 16 + lq * 4;
      const float4 bb = *(const float4*)(b + colb);
      float o[4], s1[4], s2[4];
      o[0] = acc[m][n][0] + bb.x; o[1] = acc[m][n][1] + bb.y;
      o[2] = acc[m][n][2] + bb.z; o[3] = acc[m][n][3] + bb.w;
      #pragma unroll
      for (int r = 0; r < 4; ++r) {
        s1[r] = valid ? o[r] : 0.f;
        s2[r] = valid ? o[r] * o[r] : 0.f;
      }
      if (valid) {
        ushort4 st;
        st.x = f2bf(o[0]); st.y = f2bf(o[1]); st.z = f2bf(o[2]); st.w = f2bf(o[3]);
        *(ushort4*)(h1 + (size_t)bid * PBLK + (size_t)(wc * 4 + n) * 2048 + rl * 16 + lq * 4) = st;
      }
      #pragma unroll
      for (int off = 1; off < 16; off <<= 1)
        #pragma unroll
        for (int r = 0; r < 4; ++r) {
          s1[r] += __shfl_xor(s1[r], off);
          s2[r] += __shfl_xor(s2[r], off);
        }
      if (l15 == 0) {
        #pragma unroll
        for (int r = 0; r < 4; ++r) {
          atomAddF(&red[colb + r], s1[r]);
          atomAddF(&red[128 + colb + r], s2[r]);
        }
      }
    }
  }
  __syncthreads();
  const int slot = (bid & 63) * L;
  if (tid < 128) atomAddF(&gS[slot + tid], red[tid]);
  else if (tid < 256) atomAddF(&gS[64 * L + slot + (tid - 128)], red[tid]);
}

// ================= edge layer 2: 2D wave tile, W staged once (32 KB) =================
template <bool WF32>
__global__ __launch_bounds__(512, 4) void k_edge_l2(
    const u16* __restrict__ h1, const float* __restrict__ ss,
    const u16* __restrict__ Wt, const float* __restrict__ b,
    const int* __restrict__ perm,
    float* __restrict__ ea_out, u16* __restrict__ ea16)
{
  __shared__ __align__(16) char Ws2[2 * 16384];
  const int tid = threadIdx.x, bid = blockIdx.x, row0 = bid * 128;
  const int lane = tid & 63, wid = tid >> 6;
  const int wr = wid >> 1, wc = wid & 1;
  const int l15 = lane & 15, lq = lane >> 4;

  int crw[2];
  #pragma unroll
  for (int m = 0; m < 2; ++m)
    crw[m] = min(row0 + wr * 32 + m * 16 + l15, E_N - 1);

  // stage both W chunks (linear write, pre-swizzled source)
  const int n0 = tid >> 3,         kq0 = (tid & 7) ^ (n0 & 7);
  const int n1 = (tid + 512) >> 3, kq1 = ((tid + 512) & 7) ^ (n1 & 7);
  #pragma unroll
  for (int cc = 0; cc < 2; ++cc) {
    const uint4 wa = *(const uint4*)(Wt + (size_t)n0 * 128 + cc * 64 + kq0 * 8);
    const uint4 wb = *(const uint4*)(Wt + (size_t)n1 * 128 + cc * 64 + kq1 * 8);
    *(uint4*)(Ws2 + cc * 16384 + tid * 16) = wa;
    *(uint4*)(Ws2 + cc * 16384 + tid * 16 + 8192) = wb;
  }

  // private A (h1 panel), raw
  bf16x8 ah[2][2][2];  // [cc][m][k2]
  #pragma unroll
  for (int cc = 0; cc < 2; ++cc)
    #pragma unroll
    for (int m = 0; m < 2; ++m)
      #pragma unroll
      for (int k2 = 0; k2 < 2; ++k2)
        ah[cc][m][k2] = *(const bf16x8*)(h1 + paddr(crw[m], cc * 4 + k2 * 2 + (lq >> 1), (lq & 1) * 8));
  __syncthreads();

  f32x4 acc[2][4];
  #pragma unroll
  for (int m = 0; m < 2; ++m)
    #pragma unroll
    for (int n = 0; n < 4; ++n) acc[m][n] = (f32x4){0.f, 0.f, 0.f, 0.f};

  #pragma unroll
  for (int cc = 0; cc < 2; ++cc)
    #pragma unroll
    for (int k2 = 0; k2 < 2; ++k2) {
      const int kb = cc * 64 + k2 * 32 + lq * 8;
      const float4 sca = *(const float4*)(ss + kb), scb = *(const float4*)(ss + kb + 4);
      const float4 sha = *(const float4*)(ss + 128 + kb), shb = *(const float4*)(ss + 128 + kb + 4);
      const bf16x8 a0 = bnrelu8(ah[cc][0][k2], sca, scb, sha, shb);
      const bf16x8 a1 = bnrelu8(ah[cc][1][k2], sca, scb, sha, shb);
      const char* base = Ws2 + cc * 16384;
      #pragma unroll
      for (int n = 0; n < 4; ++n) {
        const int ncol = wc * 64 + n * 16 + l15;
        const int sw = (ncol & 7) << 4;
        const bf16x8 wf = *(const bf16x8*)(base + ((ncol * 128 + k2 * 64 + lq * 16) ^ sw));
        acc[0][n] = MFMA(wf, a0, acc[0][n]);
        acc[1][n] = MFMA(wf, a1, acc[1][n]);
      }
    }

  // epilogue: o = relu(acc+bias) + resid (in-place panel RMW); fp32 scatter at s=3
  #pragma unroll
  for (int m = 0; m < 2; ++m) {
    const int rl = wr * 32 + m * 16 + l15;
    const int row = row0 + rl;
    if (row < E_N) {
      const int prow = WF32 ? perm[row] : 0;
      #pragma unroll
      for (int n = 0; n < 4; ++n) {
        const int colb = wc * 64 + n * 16 + lq * 4;
        const float4 bb = *(const float4*)(b + colb);
        float o[4];
        o[0] = fmaxf(acc[m][n][0] + bb.x, 0.f);
        o[1] = fmaxf(acc[m][n][1] + bb.y, 0.f);
        o[2] = fmaxf(acc[m][n][2] + bb.z, 0.f);
        o[3] = fmaxf(acc[m][n][3] + bb.w, 0.f);
        u16* ep = ea16 + (size_t)bid * PBLK + (size_t)(wc * 4 + n) * 2048 + rl * 16 + lq * 4;
        const ushort4 rv = *(const ushort4*)ep;
        o[0] += bf2f(rv.x); o[1] += bf2f(rv.y); o[2] += bf2f(rv.z); o[3] += bf2f(rv.w);
        ushort4 st;
        st.x = f2bf(o[0]); st.y = f2bf(o[1]); st.z = f2bf(o[2]); st.w = f2bf(o[3]);
        *(ushort4*)ep = st;
        if (WF32) {
          float4 fv; fv.x = o[0]; fv.y = o[1]; fv.z = o[2]; fv.w = o[3];
          *(float4*)(ea_out + (size_t)prow * L + colb) = fv;
        }
      }
    }
  }
}

// ================= node layer 1 (x16 + agg16 bf16, row-major) =================
__global__ __launch_bounds__(256) void k_node_l1(
    const u16* __restrict__ x16, const u16* __restrict__ agg16,
    const u16* __restrict__ Wt, const float* __restrict__ b,
    u16* __restrict__ h1, float* __restrict__ gS)
{
  __shared__ __align__(16) char Bs[2][16384];
  __shared__ float red[256];
  const int tid = threadIdx.x, bid = blockIdx.x, row0 = bid * 64;
  red[tid] = 0.f;
  const int lane = tid & 63, wid = tid >> 6, wr = wid >> 1, wc = wid & 1;
  const int l15 = lane & 15, lq = lane >> 4;
  const int r0 = row0 + wr * 32 + l15, r1 = r0 + 16;
  const int rr0 = min(r0, NND - 1), rr1 = min(r1, NND - 1);

  const u16* aP[2][2];
  aP[0][0] = x16 + (size_t)rr0 * L;   aP[1][0] = x16 + (size_t)rr1 * L;
  aP[0][1] = agg16 + (size_t)rr0 * L; aP[1][1] = agg16 + (size_t)rr1 * L;

  f32x4 acc[2][4];
  #pragma unroll
  for (int m = 0; m < 2; ++m)
    #pragma unroll
    for (int n = 0; n < 4; ++n) acc[m][n] = (f32x4){0.f, 0.f, 0.f, 0.f};

  auto loadA = [&](int c, bf16x8 (&af)[2][2]) {
    const int seg = c >> 1;
    const int base = (c & 1) * 64 + lq * 8;
    #pragma unroll
    for (int k2 = 0; k2 < 2; ++k2) {
      af[0][k2] = *(const bf16x8*)(aP[0][seg] + base + k2 * 32);
      af[1][k2] = *(const bf16x8*)(aP[1][seg] + base + k2 * 32);
    }
  };
  auto stage = [&](int c, int buf) {
    #pragma unroll
    for (int i = 0; i < 4; ++i) {
      const int slot = tid + i * 256;
      const int n = slot >> 3, kq = slot & 7;
      const uint4 v = *(const uint4*)(Wt + (size_t)n * 256 + c * 64 + kq * 8);
      *(uint4*)(&Bs[buf][0] + ((n * 128 + kq * 16) ^ ((n & 7) << 4))) = v;
    }
  };

  bf16x8 aCur[2][2], aNxt[2][2];
  loadA(0, aCur);
  stage(0, 0);
  __syncthreads();
  #pragma unroll
  for (int c = 0; c < 4; ++c) {
    if (c + 1 < 4) loadA(c + 1, aNxt);
    {
      const char* base = &Bs[c & 1][0];
      #pragma unroll
      for (int k2 = 0; k2 < 2; ++k2)
        #pragma unroll
        for (int n = 0; n < 4; ++n) {
          const int ncol = wc * 64 + n * 16 + l15;
          const bf16x8 bfr = *(const bf16x8*)(base + ((ncol * 128 + k2 * 64 + lq * 16) ^ ((ncol & 7) << 4)));
          acc[0][n] = MFMA(aCur[0][k2], bfr, acc[0][n]);
          acc[1][n] = MFMA(aCur[1][k2], bfr, acc[1][n]);
        }
    }
    if (c + 1 < 4) stage(c + 1, (c + 1) & 1);
    __syncthreads();
    #pragma unroll
    for (int m = 0; m < 2; ++m)
      #pragma unroll
      for (int k2 = 0; k2 < 2; ++k2) aCur[m][k2] = aNxt[m][k2];
  }

  float bb[4], s1[4], s2[4];
  #pragma unroll
  for (int n = 0; n < 4; ++n) { bb[n] = b[wc * 64 + n * 16 + l15]; s1[n] = 0.f; s2[n] = 0.f; }
  #pragma unroll
  for (int m = 0; m < 2; ++m)
    #pragma unroll
    for (int n = 0; n < 4; ++n) {
      const int ncol = wc * 64 + n * 16 + l15;
      #pragma unroll
      for (int r = 0; r < 4; ++r) {
        const int row = row0 + wr * 32 + m * 16 + lq * 4 + r;
        if (row < NND) {
          const float o = acc[m][n][r] + bb[n];
          s1[n] += o; s2[n] += o * o;
          h1[(size_t)row * L + ncol] = f2bf(o);
        }
      }
    }
  #pragma unroll
  for (int n = 0; n < 4; ++n) {
    const int ncol = wc * 64 + n * 16 + l15;
    atomAddF(&red[ncol], s1[n]);
    atomAddF(&red[128 + ncol], s2[n]);
  }
  __syncthreads();
  const int slot = (bid & 63) * L;
  if (tid < 128) atomAddF(&gS[slot + tid], red[tid]);
  else atomAddF(&gS[64 * L + slot + (tid - 128)], red[tid]);
}

// ================= node layer 2 =================
__global__ __launch_bounds__(256) void k_node_l2(
    const u16* __restrict__ h1, const float* __restrict__ ss,
    const u16* __restrict__ Wt, const float* __restrict__ b,
    const float* __restrict__ resid, float* __restrict__ x_out,
    u16* __restrict__ x16)
{
  __shared__ __align__(16) char Bs[2][16384];
  const int tid = threadIdx.x, bid = blockIdx.x, row0 = bid * 64;
  const int lane = tid & 63, wid = tid >> 6, wr = wid >> 1, wc = wid & 1;
  const int l15 = lane & 15, lq = lane >> 4;
  const int r0 = row0 + wr * 32 + l15, r1 = r0 + 16;
  const int rr0 = min(r0, NND - 1), rr1 = min(r1, NND - 1);
  const u16* a0 = h1 + (size_t)rr0 * L + lq * 8;
  const u16* a1 = h1 + (size_t)rr1 * L + lq * 8;

  f32x4 acc[2][4];
  #pragma unroll
  for (int m = 0; m < 2; ++m)
    #pragma unroll
    for (int n = 0; n < 4; ++n) acc[m][n] = (f32x4){0.f, 0.f, 0.f, 0.f};

  auto stage = [&](int c, int buf) {
    #pragma unroll
    for (int i = 0; i < 4; ++i) {
      const int slot = tid + i * 256;
      const int n = slot >> 3, kq = slot & 7;
      const uint4 v = *(const uint4*)(Wt + (size_t)n * 128 + c * 64 + kq * 8);
      *(uint4*)(&Bs[buf][0] + ((n * 128 + kq * 16) ^ ((n & 7) << 4))) = v;
    }
  };
  stage(0, 0);
  stage(1, 1);
  bf16x8 raw[2][2][2];
  #pragma unroll
  for (int c = 0; c < 2; ++c)
    #pragma unroll
    for (int k2 = 0; k2 < 2; ++k2) {
      raw[c][0][k2] = *(const bf16x8*)(a0 + c * 64 + k2 * 32);
      raw[c][1][k2] = *(const bf16x8*)(a1 + c * 64 + k2 * 32);
    }
  __syncthreads();

  #pragma unroll
  for (int c = 0; c < 2; ++c) {
    bf16x8 af[2][2];
    #pragma unroll
    for (int k2 = 0; k2 < 2; ++k2) {
      const int kg = c * 64 + k2 * 32 + lq * 8;
      const float4 sca = *(const float4*)(ss + kg), scb = *(const float4*)(ss + kg + 4);
      const float4 sha = *(const float4*)(ss + 128 + kg), shb = *(const float4*)(ss + 128 + kg + 4);
      af[0][k2] = bnrelu8(raw[c][0][k2], sca, scb, sha, shb);
      af[1][k2] = bnrelu8(raw[c][1][k2], sca, scb, sha, shb);
    }
    const char* base = &Bs[c][0];
    #pragma unroll
    for (int k2 = 0; k2 < 2; ++k2)
      #pragma unroll
      for (int n = 0; n < 4; ++n) {
        const int ncol = wc * 64 + n * 16 + l15;
        const bf16x8 bfr = *(const bf16x8*)(base + ((ncol * 128 + k2 * 64 + lq * 16) ^ ((ncol & 7) << 4)));
        acc[0][n] = MFMA(af[0][k2], bfr, acc[0][n]);
        acc[1][n] = MFMA(af[1][k2], bfr, acc[1][n]);
      }
  }

  float bb[4];
  #pragma unroll
  for (int n = 0; n < 4; ++n) bb[n] = b[wc * 64 + n * 16 + l15];
  #pragma unroll
  for (int m = 0; m < 2; ++m)
    #pragma unroll
    for (int n = 0; n < 4; ++n) {
      const int ncol = wc * 64 + n * 16 + l15;
      #pragma unroll
      for (int r = 0; r < 4; ++r) {
        const int row = row0 + wr * 32 + m * 16 + lq * 4 + r;
        if (row < NND) {
          const float o = fmaxf(acc[m][n][r] + bb[n], 0.f) + resid[(size_t)row * L + ncol];
          x_out[(size_t)row * L + ncol] = o;
          x16[(size_t)row * L + ncol] = f2bf(o);
        }
      }
    }
}

extern "C" void kernel_launch(void* const* d_in, const int* in_sizes, int n_in,
                              void* d_out, int out_size, void* d_ws, size_t ws_size,
                              hipStream_t stream) {
  (void)in_sizes; (void)n_in; (void)out_size; (void)ws_size;
  const float* in_x  = (const float*)d_in[0];
  const float* in_ea = (const float*)d_in[1];
  const int*   ei    = (const int*)d_in[2];
  const float* eW1 = (const float*)d_in[3];
  const float* eb1 = (const float*)d_in[4];
  const float* eg1 = (const float*)d_in[5];
  const float* ebe1= (const float*)d_in[6];
  const float* eW2 = (const float*)d_in[7];
  const float* eb2 = (const float*)d_in[8];
  const float* nW1 = (const float*)d_in[9];
  const float* nb1 = (const float*)d_in[10];
  const float* ng1 = (const float*)d_in[11];
  const float* nbe1= (const float*)d_in[12];
  const float* nW2 = (const float*)d_in[13];
  const float* nb2 = (const float*)d_in[14];

  float* x  = (float*)d_out;                    // [NND][L]
  float* ea = (float*)d_out + (size_t)NND * L;  // [E_N][L]

  char* w = (char*)d_ws;
  u16* h1e   = (u16*)w;   w += (size_t)EGRID * PBLK * sizeof(u16);  // panel layout
  u16* ea16  = (u16*)w;   w += (size_t)EGRID * PBLK * sizeof(u16);  // panel layout
  u16* h1n   = (u16*)w;   w += (size_t)NND * L * sizeof(u16);
  u16* x16   = (u16*)w;   w += (size_t)NND * L * sizeof(u16);
  u16* agg16 = (u16*)w;   w += (size_t)NND * L * sizeof(u16);
  float* gS  = (float*)w; w += (size_t)2 * 64 * L * sizeof(float);
  float* ss  = (float*)w; w += 4096;
  u16* eW1t = (u16*)w;   w += (size_t)4 * 128 * 384 * sizeof(u16);
  u16* eW2t = (u16*)w;   w += (size_t)4 * 128 * 128 * sizeof(u16);
  u16* nW1t = (u16*)w;   w += (size_t)4 * 128 * 256 * sizeof(u16);
  u16* nW2t = (u16*)w;   w += (size_t)4 * 128 * 128 * sizeof(u16);
  int* cnt    = (int*)w; w += (size_t)NND * sizeof(int);
  int* cur    = (int*)w; w += (size_t)NND * sizeof(int);
  int* startA = (int*)w; w += (size_t)(NND + 64) * sizeof(int);
  int* eids   = (int*)w; w += (size_t)E_N * sizeof(int);     // = perm
  int* srcP   = (int*)w; w += (size_t)E_N * sizeof(int);
  int* dstP   = (int*)w; w += (size_t)E_N * sizeof(int);

  const int* srcI = ei;
  const int* dstI = ei + E_N;

  k_cvt4<<<(NND * L / 4 + 255) / 256, 256, 0, stream>>>(in_x, x16, NND * L / 4);
  k_wt<<<(4 * 384 * 128 + 255) / 256, 256, 0, stream>>>(eW1, eW1t, 384);
  k_wt<<<(4 * 128 * 128 + 255) / 256, 256, 0, stream>>>(eW2, eW2t, 128);
  k_wt<<<(4 * 256 * 128 + 255) / 256, 256, 0, stream>>>(nW1, nW1t, 256);
  k_wt<<<(4 * 128 * 128 + 255) / 256, 256, 0, stream>>>(nW2, nW2t, 128);
  hipMemsetAsync(cnt, 0, (size_t)NND * sizeof(int), stream);
  hipMemsetAsync(cur, 0, (size_t)NND * sizeof(int), stream);
  k_hist<<<(E_N + 255) / 256, 256, 0, stream>>>(dstI, cnt);
  k_scan<<<1, 1024, 0, stream>>>(cnt, startA);
  k_fill<<<(E_N + 255) / 256, 256, 0, stream>>>(dstI, startA, cur, eids);
  k_perm<<<(E_N + 255) / 256, 256, 0, stream>>>(srcI, dstI, eids, srcP, dstP);
  k_cvtperm<<<(E_N * 16 + 255) / 256, 256, 0, stream>>>(in_ea, eids, ea16);

  const int ngrid = (NND + 63) / 64;     // 782

  for (int s = 0; s < 4; ++s) {
    hipMemsetAsync(gS, 0, (size_t)2 * 64 * L * sizeof(float), stream);
    k_edge_l1<<<EGRID, 512, 0, stream>>>(x16, ea16, srcP, dstP,
        eW1t + (size_t)s * 128 * 384, eb1 + (size_t)s * L, h1e, gS);
    k_bnfin<<<1, 128, 0, stream>>>(gS, eg1 + (size_t)s * L, ebe1 + (size_t)s * L,
        1.f / (float)E_N, ss);
    if (s < 3)
      k_edge_l2<false><<<EGRID, 512, 0, stream>>>(h1e, ss,
          eW2t + (size_t)s * 128 * 128, eb2 + (size_t)s * L, eids, ea, ea16);
    else
      k_edge_l2<true><<<EGRID, 512, 0, stream>>>(h1e, ss,
          eW2t + (size_t)s * 128 * 128, eb2 + (size_t)s * L, eids, ea, ea16);
    k_agg<<<(NND + 3) / 4, 256, 0, stream>>>(ea16, startA, agg16);
    hipMemsetAsync(gS, 0, (size_t)2 * 64 * L * sizeof(float), stream);
    k_node_l1<<<ngrid, 256, 0, stream>>>(x16, agg16,
        nW1t + (size_t)s * 128 * 256, nb1 + (size_t)s * L, h1n, gS);
    k_bnfin<<<1, 128, 0, stream>>>(gS, ng1 + (size_t)s * L, nbe1 + (size_t)s * L,
        1.f / (float)NND, ss);
    k_node_l2<<<ngrid, 256, 0, stream>>>(h1n, ss,
        nW2t + (size_t)s * 128 * 128, nb2 + (size_t)s * L,
        (s == 0) ? in_x : x, x, x16);
  }
}

// Round 16
// 1943.570 us; speedup vs baseline: 1.5551x; 1.0315x over previous
//
#include <hip/hip_runtime.h>
#include <hip/hip_bf16.h>
#include <cstdint>
#include <cstddef>

#define E_N 600000
#define NND 50000
#define L 128
#define EGRID 4688              // ceil(E_N/128) = 8 * 586
#define XCHUNK 586
#define PBLK 16384              // u16 per 128-row panel-block (8*128*16)
#define NSLOT 256

typedef unsigned short u16;
typedef unsigned int u32;
typedef __attribute__((ext_vector_type(8))) short bf16x8;
typedef __attribute__((ext_vector_type(4))) float f32x4;

static __device__ __forceinline__ u16 f2bf(float f) {
  union { float f; u32 u; } c; c.f = f;
  return (u16)((c.u + 0x7fffu + ((c.u >> 16) & 1u)) >> 16);
}
static __device__ __forceinline__ u32 pk2(float a, float b) {
  return (u32)f2bf(a) | ((u32)f2bf(b) << 16);
}
static __device__ __forceinline__ float bf2f(u32 h) {
  union { u32 u; float f; } c; c.u = (h & 0xffffu) << 16; return c.f;
}
static __device__ __forceinline__ void atomAddF(float* p, float v) {
#if defined(__HIP_DEVICE_COMPILE__)
  unsafeAtomicAdd(p, v);
#else
  atomicAdd(p, v);
#endif
}
static __device__ __forceinline__ bf16x8 bnrelu8(bf16x8 raw, float4 sca, float4 scb,
                                                 float4 sha, float4 shb) {
  union { bf16x8 v; u16 h[8]; } in; in.v = raw;
  const float sc[8] = {sca.x, sca.y, sca.z, sca.w, scb.x, scb.y, scb.z, scb.w};
  const float sh[8] = {sha.x, sha.y, sha.z, sha.w, shb.x, shb.y, shb.z, shb.w};
  float f[8];
  #pragma unroll
  for (int i = 0; i < 8; ++i) f[i] = fmaxf(bf2f(in.h[i]) * sc[i] + sh[i], 0.f);
  union { bf16x8 v; u32 w[4]; } r;
  #pragma unroll
  for (int i = 0; i < 4; ++i) r.w[i] = pk2(f[2 * i], f[2 * i + 1]);
  return r.v;
}

#define MFMA(a, bfr, c) __builtin_amdgcn_mfma_f32_16x16x32_bf16((a), (bfr), (c), 0, 0, 0)

// panel-layout address (u16 units): row-block, panel p (=col/16), local row, col%16
static __device__ __forceinline__ size_t paddr(int row, int panel, int incol) {
  return (size_t)(row >> 7) * PBLK + (size_t)panel * 2048 + (size_t)(row & 127) * 16 + incol;
}

// ================= prepass kernels =================
__global__ __launch_bounds__(256) void k_cvt4(const float* __restrict__ in,
                                              u16* __restrict__ out, int n4) {
  const int i = blockIdx.x * 256 + threadIdx.x;
  if (i < n4) {
    const float4 v = *(const float4*)(in + (size_t)i * 4);
    uint2 o; o.x = pk2(v.x, v.y); o.y = pk2(v.z, v.w);
    *(uint2*)(out + (size_t)i * 4) = o;
  }
}

// in_ea (fp32, original order) -> ea16 (bf16, permuted panel layout)
__global__ __launch_bounds__(256) void k_cvtperm(const float* __restrict__ in_ea,
                                                 const int* __restrict__ perm,
                                                 u16* __restrict__ ea16) {
  const int i = blockIdx.x * 256 + threadIdx.x;
  const int row = i >> 4, part = i & 15;      // 16 threads/row, 8 cols each
  if (row < E_N) {
    const float* p = in_ea + (size_t)perm[row] * L + part * 8;
    const float4 f0 = *(const float4*)p, f1 = *(const float4*)(p + 4);
    union { bf16x8 v; u32 w[4]; } r;
    r.w[0] = pk2(f0.x, f0.y); r.w[1] = pk2(f0.z, f0.w);
    r.w[2] = pk2(f1.x, f1.y); r.w[3] = pk2(f1.z, f1.w);
    *(bf16x8*)(ea16 + paddr(row, part >> 1, (part & 1) * 8)) = r.v;
  }
}

__global__ void k_wt(const float* __restrict__ W, u16* __restrict__ Wt, int K) {
  const int idx = blockIdx.x * 256 + threadIdx.x;
  const int total = 4 * K * 128;
  if (idx >= total) return;
  const int s = idx / (K * 128);
  const int rem = idx - s * K * 128;
  const int n = rem / K;
  const int k = rem - n * K;
  Wt[idx] = f2bf(W[(size_t)s * K * 128 + (size_t)k * 128 + n]);
}

__global__ void k_hist(const int* __restrict__ dstI, int* __restrict__ cnt) {
  const int i = blockIdx.x * 256 + threadIdx.x;
  if (i < E_N) atomicAdd(&cnt[dstI[i]], 1);
}

__global__ __launch_bounds__(1024) void k_scan(const int* __restrict__ cnt, int* __restrict__ startA) {
  __shared__ int buf[1024];
  __shared__ int carry;
  const int tid = threadIdx.x;
  if (tid == 0) carry = 0;
  __syncthreads();
  for (int base = 0; base < NND; base += 1024) {
    int v = (base + tid < NND) ? cnt[base + tid] : 0;
    buf[tid] = v;
    __syncthreads();
    for (int off = 1; off < 1024; off <<= 1) {
      int t = (tid >= off) ? buf[tid - off] : 0;
      __syncthreads();
      buf[tid] += t;
      __syncthreads();
    }
    const int incl = buf[tid];
    const int c = carry;
    if (base + tid < NND) startA[base + tid] = c + incl - v;
    __syncthreads();
    if (tid == 1023) carry = c + incl;
    __syncthreads();
  }
  if (tid == 0) startA[NND] = carry;
}

__global__ void k_fill(const int* __restrict__ dstI, const int* __restrict__ startA,
                       int* __restrict__ cur, int* __restrict__ eids) {
  const int i = blockIdx.x * 256 + threadIdx.x;
  if (i < E_N) {
    const int d = dstI[i];
    const int pos = atomicAdd(&cur[d], 1);
    eids[startA[d] + pos] = i;
  }
}

__global__ void k_perm(const int* __restrict__ srcI, const int* __restrict__ dstI,
                       const int* __restrict__ perm,
                       int* __restrict__ srcP, int* __restrict__ dstP) {
  const int i = blockIdx.x * 256 + threadIdx.x;
  if (i < E_N) {
    const int e = perm[i];
    srcP[i] = srcI[e];
    dstP[i] = dstI[e];
  }
}

// ================= aggregation (panel ea16 -> row-major agg16) =================
__global__ __launch_bounds__(256) void k_agg(const u16* __restrict__ ea16,
                                             const int* __restrict__ startA,
                                             u16* __restrict__ agg16) {
  const int node = blockIdx.x * 4 + (threadIdx.x >> 6);
  const int lane = threadIdx.x & 63;
  if (node >= NND) return;
  const int s = startA[node], e = startA[node + 1];
  const size_t poff = (size_t)(lane >> 3) * 2048 + (size_t)((lane & 7) * 2);
  float a0 = 0.f, a1 = 0.f, b0 = 0.f, b1 = 0.f;
  int i = s;
  for (; i + 1 < e; i += 2) {
    const u32 v0 = *(const u32*)(ea16 + (size_t)(i >> 7) * PBLK + (size_t)(i & 127) * 16 + poff);
    const int j = i + 1;
    const u32 v1 = *(const u32*)(ea16 + (size_t)(j >> 7) * PBLK + (size_t)(j & 127) * 16 + poff);
    a0 += bf2f(v0); a1 += bf2f(v0 >> 16);
    b0 += bf2f(v1); b1 += bf2f(v1 >> 16);
  }
  if (i < e) {
    const u32 v = *(const u32*)(ea16 + (size_t)(i >> 7) * PBLK + (size_t)(i & 127) * 16 + poff);
    a0 += bf2f(v); a1 += bf2f(v >> 16);
  }
  *(u32*)(agg16 + (size_t)node * L + lane * 2) = pk2(a0 + b0, a1 + b1);
}

// ================= BN finalize =================
__global__ void k_bnfin(const float* __restrict__ gS, const float* __restrict__ g,
                        const float* __restrict__ be, float invM, float* __restrict__ ss) {
  const int c = threadIdx.x;
  float s1 = 0.f, s2 = 0.f;
  for (int j = 0; j < NSLOT; ++j) { s1 += gS[j * L + c]; s2 += gS[NSLOT * L + j * L + c]; }
  const float mean = s1 * invM;
  const float var = s2 * invM - mean * mean;
  const float sc = g[c] * rsqrtf(var + 1e-5f);
  ss[c] = sc;
  ss[L + c] = be[c] - mean * sc;
}

// ================= edge layer 1: 2D wave tile (32 rows x 64 cols), A private, W via 2-buffer LDS =================
// wave (wr,wc): rows wr*32 + m*16 + l15 (m=0,1), cols wc*64 + n*16 + lq*4 + r (n=0..3)
__global__ __launch_bounds__(512, 4) void k_edge_l1(
    const u16* __restrict__ x16, const u16* __restrict__ ea16,
    const int* __restrict__ srcP, const int* __restrict__ dstP,
    const u16* __restrict__ Wt, const float* __restrict__ b,
    u16* __restrict__ h1, float* __restrict__ gS)
{
  __shared__ __align__(16) char Ws2[2 * 16384];
  __shared__ float red[256];
  const int tid = threadIdx.x;
  const int bid = (blockIdx.x & 7) * XCHUNK + (blockIdx.x >> 3);  // XCD-aware swizzle
  const int row0 = bid * 128;
  const int lane = tid & 63, wid = tid >> 6;
  const int wr = wid >> 1, wc = wid & 1;
  const int l15 = lane & 15, lq = lane >> 4;
  if (tid < 256) red[tid] = 0.f;

  int crw[2], dI[2], sI[2];
  #pragma unroll
  for (int m = 0; m < 2; ++m) {
    crw[m] = min(row0 + wr * 32 + m * 16 + l15, E_N - 1);
    dI[m] = dstP[crw[m]];
    sI[m] = srcP[crw[m]];
  }

  // private A fragments, 3-deep rolling window: af3[cc%3][m][k2]
  bf16x8 af3[3][2][2];
  auto loadA = [&](int cc, bf16x8 (&dst)[2][2]) {
    #pragma unroll
    for (int m = 0; m < 2; ++m) {
      if (cc < 4) {
        const int node = (cc < 2) ? dI[m] : sI[m];
        const u16* p = x16 + (size_t)node * L + (cc & 1) * 64 + lq * 8;
        dst[m][0] = *(const bf16x8*)p;
        dst[m][1] = *(const bf16x8*)(p + 32);
      } else {
        const int pc = cc - 4;
        dst[m][0] = *(const bf16x8*)(ea16 + paddr(crw[m], pc * 4 + (lq >> 1), (lq & 1) * 8));
        dst[m][1] = *(const bf16x8*)(ea16 + paddr(crw[m], pc * 4 + 2 + (lq >> 1), (lq & 1) * 8));
      }
    }
  };
  loadA(0, af3[0]); loadA(1, af3[1]); loadA(2, af3[2]);

  // W staging: linear LDS write, pre-swizzled global source
  const int n0 = tid >> 3,         kq0 = (tid & 7) ^ (n0 & 7);
  const int n1 = (tid + 512) >> 3, kq1 = ((tid + 512) & 7) ^ (n1 & 7);
  uint4 wa, wb;
  auto wload = [&](int cc) {
    wa = *(const uint4*)(Wt + (size_t)n0 * 384 + cc * 64 + kq0 * 8);
    wb = *(const uint4*)(Wt + (size_t)n1 * 384 + cc * 64 + kq1 * 8);
  };
  auto wwrite = [&](int buf) {
    *(uint4*)(Ws2 + buf * 16384 + tid * 16) = wa;
    *(uint4*)(Ws2 + buf * 16384 + tid * 16 + 8192) = wb;
  };

  wload(0);
  wwrite(0);
  __syncthreads();

  f32x4 acc[2][4];
  #pragma unroll
  for (int m = 0; m < 2; ++m)
    #pragma unroll
    for (int n = 0; n < 4; ++n) acc[m][n] = (f32x4){0.f, 0.f, 0.f, 0.f};

  #pragma unroll
  for (int cc = 0; cc < 6; ++cc) {
    if (cc + 1 < 6) wload(cc + 1);
    const char* base = Ws2 + (cc & 1) * 16384;
    const bf16x8 (&af)[2][2] = af3[cc % 3];
    #pragma unroll
    for (int k2 = 0; k2 < 2; ++k2)
      #pragma unroll
      for (int n = 0; n < 4; ++n) {
        const int ncol = wc * 64 + n * 16 + l15;
        const int sw = (ncol & 7) << 4;
        const bf16x8 wf = *(const bf16x8*)(base + ((ncol * 128 + k2 * 64 + lq * 16) ^ sw));
        acc[0][n] = MFMA(wf, af[0][k2], acc[0][n]);
        acc[1][n] = MFMA(wf, af[1][k2], acc[1][n]);
      }
    if (cc + 3 < 6) loadA(cc + 3, af3[cc % 3]);
    if (cc + 1 < 6) wwrite((cc + 1) & 1);
    __syncthreads();
  }

  // epilogue: bias, stats (m-accumulated, one shuffle tree per n), ushort4 panel stores
  #pragma unroll
  for (int n = 0; n < 4; ++n) {
    const int colb = wc * 64 + n * 16 + lq * 4;
    const float4 bb = *(const float4*)(b + colb);
    float s1[4] = {0.f, 0.f, 0.f, 0.f}, s2[4] = {0.f, 0.f, 0.f, 0.f};
    #pragma unroll
    for (int m = 0; m < 2; ++m) {
      const int rl = wr * 32 + m * 16 + l15;
      const bool valid = row0 + rl < E_N;
      float o[4];
      o[0] = acc[m][n][0] + bb.x; o[1] = acc[m][n][1] + bb.y;
      o[2] = acc[m][n][2] + bb.z; o[3] = acc[m][n][3] + bb.w;
      if (valid) {
        #pragma unroll
        for (int r = 0; r < 4; ++r) { s1[r] += o[r]; s2[r] += o[r] * o[r]; }
        ushort4 st;
        st.x = f2bf(o[0]); st.y = f2bf(o[1]); st.z = f2bf(o[2]); st.w = f2bf(o[3]);
        *(ushort4*)(h1 + (size_t)bid * PBLK + (size_t)(wc * 4 + n) * 2048 + rl * 16 + lq * 4) = st;
      }
    }
    #pragma unroll
    for (int off = 1; off < 16; off <<= 1)
      #pragma unroll
      for (int r = 0; r < 4; ++r) {
        s1[r] += __shfl_xor(s1[r], off);
        s2[r] += __shfl_xor(s2[r], off);
      }
    if (l15 == 0) {
      #pragma unroll
      for (int r = 0; r < 4; ++r) {
        atomAddF(&red[colb + r], s1[r]);
        atomAddF(&red[128 + colb + r], s2[r]);
      }
    }
  }
  __syncthreads();
  const int slot = (bid & (NSLOT - 1)) * L;
  if (tid < 128) atomAddF(&gS[slot + tid], red[tid]);
  else if (tid < 256) atomAddF(&gS[NSLOT * L + slot + (tid - 128)], red[tid]);
}

// ================= edge layer 2: 2D wave tile, W staged once (32 KB) =================
template <bool WF32>
__global__ __launch_bounds__(512, 4) void k_edge_l2(
    const u16* __restrict__ h1, const float* __restrict__ ss,
    const u16* __restrict__ Wt, const float* __restrict__ b,
    const int* __restrict__ perm,
    float* __restrict__ ea_out, u16* __restrict__ ea16)
{
  __shared__ __align__(16) char Ws2[2 * 16384];
  const int tid = threadIdx.x;
  const int bid = (blockIdx.x & 7) * XCHUNK + (blockIdx.x >> 3);  // XCD-aware swizzle
  const int row0 = bid * 128;
  const int lane = tid & 63, wid = tid >> 6;
  const int wr = wid >> 1, wc = wid & 1;
  const int l15 = lane & 15, lq = lane >> 4;

  int crw[2];
  #pragma unroll
  for (int m = 0; m < 2; ++m)
    crw[m] = min(row0 + wr * 32 + m * 16 + l15, E_N - 1);

  // stage both W chunks (linear write, pre-swizzled source)
  const int n0 = tid >> 3,         kq0 = (tid & 7) ^ (n0 & 7);
  const int n1 = (tid + 512) >> 3, kq1 = ((tid + 512) & 7) ^ (n1 & 7);
  #pragma unroll
  for (int cc = 0; cc < 2; ++cc) {
    const uint4 wa = *(const uint4*)(Wt + (size_t)n0 * 128 + cc * 64 + kq0 * 8);
    const uint4 wb = *(const uint4*)(Wt + (size_t)n1 * 128 + cc * 64 + kq1 * 8);
    *(uint4*)(Ws2 + cc * 16384 + tid * 16) = wa;
    *(uint4*)(Ws2 + cc * 16384 + tid * 16 + 8192) = wb;
  }

  // private A (h1 panel), raw
  bf16x8 ah[2][2][2];  // [cc][m][k2]
  #pragma unroll
  for (int cc = 0; cc < 2; ++cc)
    #pragma unroll
    for (int m = 0; m < 2; ++m)
      #pragma unroll
      for (int k2 = 0; k2 < 2; ++k2)
        ah[cc][m][k2] = *(const bf16x8*)(h1 + paddr(crw[m], cc * 4 + k2 * 2 + (lq >> 1), (lq & 1) * 8));
  __syncthreads();

  f32x4 acc[2][4];
  #pragma unroll
  for (int m = 0; m < 2; ++m)
    #pragma unroll
    for (int n = 0; n < 4; ++n) acc[m][n] = (f32x4){0.f, 0.f, 0.f, 0.f};

  #pragma unroll
  for (int cc = 0; cc < 2; ++cc)
    #pragma unroll
    for (int k2 = 0; k2 < 2; ++k2) {
      const int kb = cc * 64 + k2 * 32 + lq * 8;
      const float4 sca = *(const float4*)(ss + kb), scb = *(const float4*)(ss + kb + 4);
      const float4 sha = *(const float4*)(ss + 128 + kb), shb = *(const float4*)(ss + 128 + kb + 4);
      const bf16x8 a0 = bnrelu8(ah[cc][0][k2], sca, scb, sha, shb);
      const bf16x8 a1 = bnrelu8(ah[cc][1][k2], sca, scb, sha, shb);
      const char* base = Ws2 + cc * 16384;
      #pragma unroll
      for (int n = 0; n < 4; ++n) {
        const int ncol = wc * 64 + n * 16 + l15;
        const int sw = (ncol & 7) << 4;
        const bf16x8 wf = *(const bf16x8*)(base + ((ncol * 128 + k2 * 64 + lq * 16) ^ sw));
        acc[0][n] = MFMA(wf, a0, acc[0][n]);
        acc[1][n] = MFMA(wf, a1, acc[1][n]);
      }
    }

  // epilogue: o = relu(acc+bias) + resid (in-place panel RMW); fp32 scatter at s=3
  #pragma unroll
  for (int m = 0; m < 2; ++m) {
    const int rl = wr * 32 + m * 16 + l15;
    const int row = row0 + rl;
    if (row < E_N) {
      const int prow = WF32 ? perm[row] : 0;
      #pragma unroll
      for (int n = 0; n < 4; ++n) {
        const int colb = wc * 64 + n * 16 + lq * 4;
        const float4 bb = *(const float4*)(b + colb);
        float o[4];
        o[0] = fmaxf(acc[m][n][0] + bb.x, 0.f);
        o[1] = fmaxf(acc[m][n][1] + bb.y, 0.f);
        o[2] = fmaxf(acc[m][n][2] + bb.z, 0.f);
        o[3] = fmaxf(acc[m][n][3] + bb.w, 0.f);
        u16* ep = ea16 + (size_t)bid * PBLK + (size_t)(wc * 4 + n) * 2048 + rl * 16 + lq * 4;
        const ushort4 rv = *(const ushort4*)ep;
        o[0] += bf2f(rv.x); o[1] += bf2f(rv.y); o[2] += bf2f(rv.z); o[3] += bf2f(rv.w);
        ushort4 st;
        st.x = f2bf(o[0]); st.y = f2bf(o[1]); st.z = f2bf(o[2]); st.w = f2bf(o[3]);
        *(ushort4*)ep = st;
        if (WF32) {
          float4 fv; fv.x = o[0]; fv.y = o[1]; fv.z = o[2]; fv.w = o[3];
          *(float4*)(ea_out + (size_t)prow * L + colb) = fv;
        }
      }
    }
  }
}

// ================= node layer 1 (x16 + agg16 bf16, row-major) =================
__global__ __launch_bounds__(256) void k_node_l1(
    const u16* __restrict__ x16, const u16* __restrict__ agg16,
    const u16* __restrict__ Wt, const float* __restrict__ b,
    u16* __restrict__ h1, float* __restrict__ gS)
{
  __shared__ __align__(16) char Bs[2][16384];
  __shared__ float red[256];
  const int tid = threadIdx.x, bid = blockIdx.x, row0 = bid * 64;
  red[tid] = 0.f;
  const int lane = tid & 63, wid = tid >> 6, wr = wid >> 1, wc = wid & 1;
  const int l15 = lane & 15, lq = lane >> 4;
  const int r0 = row0 + wr * 32 + l15, r1 = r0 + 16;
  const int rr0 = min(r0, NND - 1), rr1 = min(r1, NND - 1);

  const u16* aP[2][2];
  aP[0][0] = x16 + (size_t)rr0 * L;   aP[1][0] = x16 + (size_t)rr1 * L;
  aP[0][1] = agg16 + (size_t)rr0 * L; aP[1][1] = agg16 + (size_t)rr1 * L;

  f32x4 acc[2][4];
  #pragma unroll
  for (int m = 0; m < 2; ++m)
    #pragma unroll
    for (int n = 0; n < 4; ++n) acc[m][n] = (f32x4){0.f, 0.f, 0.f, 0.f};

  auto loadA = [&](int c, bf16x8 (&af)[2][2]) {
    const int seg = c >> 1;
    const int base = (c & 1) * 64 + lq * 8;
    #pragma unroll
    for (int k2 = 0; k2 < 2; ++k2) {
      af[0][k2] = *(const bf16x8*)(aP[0][seg] + base + k2 * 32);
      af[1][k2] = *(const bf16x8*)(aP[1][seg] + base + k2 * 32);
    }
  };
  auto stage = [&](int c, int buf) {
    #pragma unroll
    for (int i = 0; i < 4; ++i) {
      const int slot = tid + i * 256;
      const int n = slot >> 3, kq = slot & 7;
      const uint4 v = *(const uint4*)(Wt + (size_t)n * 256 + c * 64 + kq * 8);
      *(uint4*)(&Bs[buf][0] + ((n * 128 + kq * 16) ^ ((n & 7) << 4))) = v;
    }
  };

  bf16x8 aCur[2][2], aNxt[2][2];
  loadA(0, aCur);
  stage(0, 0);
  __syncthreads();
  #pragma unroll
  for (int c = 0; c < 4; ++c) {
    if (c + 1 < 4) loadA(c + 1, aNxt);
    {
      const char* base = &Bs[c & 1][0];
      #pragma unroll
      for (int k2 = 0; k2 < 2; ++k2)
        #pragma unroll
        for (int n = 0; n < 4; ++n) {
          const int ncol = wc * 64 + n * 16 + l15;
          const bf16x8 bfr = *(const bf16x8*)(base + ((ncol * 128 + k2 * 64 + lq * 16) ^ ((ncol & 7) << 4)));
          acc[0][n] = MFMA(aCur[0][k2], bfr, acc[0][n]);
          acc[1][n] = MFMA(aCur[1][k2], bfr, acc[1][n]);
        }
    }
    if (c + 1 < 4) stage(c + 1, (c + 1) & 1);
    __syncthreads();
    #pragma unroll
    for (int m = 0; m < 2; ++m)
      #pragma unroll
      for (int k2 = 0; k2 < 2; ++k2) aCur[m][k2] = aNxt[m][k2];
  }

  float bb[4], s1[4], s2[4];
  #pragma unroll
  for (int n = 0; n < 4; ++n) { bb[n] = b[wc * 64 + n * 16 + l15]; s1[n] = 0.f; s2[n] = 0.f; }
  #pragma unroll
  for (int m = 0; m < 2; ++m)
    #pragma unroll
    for (int n = 0; n < 4; ++n) {
      const int ncol = wc * 64 + n * 16 + l15;
      #pragma unroll
      for (int r = 0; r < 4; ++r) {
        const int row = row0 + wr * 32 + m * 16 + lq * 4 + r;
        if (row < NND) {
          const float o = acc[m][n][r] + bb[n];
          s1[n] += o; s2[n] += o * o;
          h1[(size_t)row * L + ncol] = f2bf(o);
        }
      }
    }
  #pragma unroll
  for (int n = 0; n < 4; ++n) {
    const int ncol = wc * 64 + n * 16 + l15;
    atomAddF(&red[ncol], s1[n]);
    atomAddF(&red[128 + ncol], s2[n]);
  }
  __syncthreads();
  const int slot = (bid & (NSLOT - 1)) * L;
  if (tid < 128) atomAddF(&gS[slot + tid], red[tid]);
  else atomAddF(&gS[NSLOT * L + slot + (tid - 128)], red[tid]);
}

// ================= node layer 2 =================
__global__ __launch_bounds__(256) void k_node_l2(
    const u16* __restrict__ h1, const float* __restrict__ ss,
    const u16* __restrict__ Wt, const float* __restrict__ b,
    const float* __restrict__ resid, float* __restrict__ x_out,
    u16* __restrict__ x16)
{
  __shared__ __align__(16) char Bs[2][16384];
  const int tid = threadIdx.x, bid = blockIdx.x, row0 = bid * 64;
  const int lane = tid & 63, wid = tid >> 6, wr = wid >> 1, wc = wid & 1;
  const int l15 = lane & 15, lq = lane >> 4;
  const int r0 = row0 + wr * 32 + l15, r1 = r0 + 16;
  const int rr0 = min(r0, NND - 1), rr1 = min(r1, NND - 1);
  const u16* a0 = h1 + (size_t)rr0 * L + lq * 8;
  const u16* a1 = h1 + (size_t)rr1 * L + lq * 8;

  f32x4 acc[2][4];
  #pragma unroll
  for (int m = 0; m < 2; ++m)
    #pragma unroll
    for (int n = 0; n < 4; ++n) acc[m][n] = (f32x4){0.f, 0.f, 0.f, 0.f};

  auto stage = [&](int c, int buf) {
    #pragma unroll
    for (int i = 0; i < 4; ++i) {
      const int slot = tid + i * 256;
      const int n = slot >> 3, kq = slot & 7;
      const uint4 v = *(const uint4*)(Wt + (size_t)n * 128 + c * 64 + kq * 8);
      *(uint4*)(&Bs[buf][0] + ((n * 128 + kq * 16) ^ ((n & 7) << 4))) = v;
    }
  };
  stage(0, 0);
  stage(1, 1);
  bf16x8 raw[2][2][2];
  #pragma unroll
  for (int c = 0; c < 2; ++c)
    #pragma unroll
    for (int k2 = 0; k2 < 2; ++k2) {
      raw[c][0][k2] = *(const bf16x8*)(a0 + c * 64 + k2 * 32);
      raw[c][1][k2] = *(const bf16x8*)(a1 + c * 64 + k2 * 32);
    }
  __syncthreads();

  #pragma unroll
  for (int c = 0; c < 2; ++c) {
    bf16x8 af[2][2];
    #pragma unroll
    for (int k2 = 0; k2 < 2; ++k2) {
      const int kg = c * 64 + k2 * 32 + lq * 8;
      const float4 sca = *(const float4*)(ss + kg), scb = *(const float4*)(ss + kg + 4);
      const float4 sha = *(const float4*)(ss + 128 + kg), shb = *(const float4*)(ss + 128 + kg + 4);
      af[0][k2] = bnrelu8(raw[c][0][k2], sca, scb, sha, shb);
      af[1][k2] = bnrelu8(raw[c][1][k2], sca, scb, sha, shb);
    }
    const char* base = &Bs[c][0];
    #pragma unroll
    for (int k2 = 0; k2 < 2; ++k2)
      #pragma unroll
      for (int n = 0; n < 4; ++n) {
        const int ncol = wc * 64 + n * 16 + l15;
        const bf16x8 bfr = *(const bf16x8*)(base + ((ncol * 128 + k2 * 64 + lq * 16) ^ ((ncol & 7) << 4)));
        acc[0][n] = MFMA(af[0][k2], bfr, acc[0][n]);
        acc[1][n] = MFMA(af[1][k2], bfr, acc[1][n]);
      }
  }

  float bb[4];
  #pragma unroll
  for (int n = 0; n < 4; ++n) bb[n] = b[wc * 64 + n * 16 + l15];
  #pragma unroll
  for (int m = 0; m < 2; ++m)
    #pragma unroll
    for (int n = 0; n < 4; ++n) {
      const int ncol = wc * 64 + n * 16 + l15;
      #pragma unroll
      for (int r = 0; r < 4; ++r) {
        const int row = row0 + wr * 32 + m * 16 + lq * 4 + r;
        if (row < NND) {
          const float o = fmaxf(acc[m][n][r] + bb[n], 0.f) + resid[(size_t)row * L + ncol];
          x_out[(size_t)row * L + ncol] = o;
          x16[(size_t)row * L + ncol] = f2bf(o);
        }
      }
    }
}

extern "C" void kernel_launch(void* const* d_in, const int* in_sizes, int n_in,
                              void* d_out, int out_size, void* d_ws, size_t ws_size,
                              hipStream_t stream) {
  (void)in_sizes; (void)n_in; (void)out_size; (void)ws_size;
  const float* in_x  = (const float*)d_in[0];
  const float* in_ea = (const float*)d_in[1];
  const int*   ei    = (const int*)d_in[2];
  const float* eW1 = (const float*)d_in[3];
  const float* eb1 = (const float*)d_in[4];
  const float* eg1 = (const float*)d_in[5];
  const float* ebe1= (const float*)d_in[6];
  const float* eW2 = (const float*)d_in[7];
  const float* eb2 = (const float*)d_in[8];
  const float* nW1 = (const float*)d_in[9];
  const float* nb1 = (const float*)d_in[10];
  const float* ng1 = (const float*)d_in[11];
  const float* nbe1= (const float*)d_in[12];
  const float* nW2 = (const float*)d_in[13];
  const float* nb2 = (const float*)d_in[14];

  float* x  = (float*)d_out;                    // [NND][L]
  float* ea = (float*)d_out + (size_t)NND * L;  // [E_N][L]

  char* w = (char*)d_ws;
  u16* h1e   = (u16*)w;   w += (size_t)EGRID * PBLK * sizeof(u16);  // panel layout
  u16* ea16  = (u16*)w;   w += (size_t)EGRID * PBLK * sizeof(u16);  // panel layout
  u16* h1n   = (u16*)w;   w += (size_t)NND * L * sizeof(u16);
  u16* x16   = (u16*)w;   w += (size_t)NND * L * sizeof(u16);
  u16* agg16 = (u16*)w;   w += (size_t)NND * L * sizeof(u16);
  float* gS  = (float*)w; w += (size_t)2 * NSLOT * L * sizeof(float);
  float* ss  = (float*)w; w += 4096;
  u16* eW1t = (u16*)w;   w += (size_t)4 * 128 * 384 * sizeof(u16);
  u16* eW2t = (u16*)w;   w += (size_t)4 * 128 * 128 * sizeof(u16);
  u16* nW1t = (u16*)w;   w += (size_t)4 * 128 * 256 * sizeof(u16);
  u16* nW2t = (u16*)w;   w += (size_t)4 * 128 * 128 * sizeof(u16);
  int* cnt    = (int*)w; w += (size_t)NND * sizeof(int);
  int* cur    = (int*)w; w += (size_t)NND * sizeof(int);
  int* startA = (int*)w; w += (size_t)(NND + 64) * sizeof(int);
  int* eids   = (int*)w; w += (size_t)E_N * sizeof(int);     // = perm
  int* srcP   = (int*)w; w += (size_t)E_N * sizeof(int);
  int* dstP   = (int*)w; w += (size_t)E_N * sizeof(int);

  const int* srcI = ei;
  const int* dstI = ei + E_N;

  k_cvt4<<<(NND * L / 4 + 255) / 256, 256, 0, stream>>>(in_x, x16, NND * L / 4);
  k_wt<<<(4 * 384 * 128 + 255) / 256, 256, 0, stream>>>(eW1, eW1t, 384);
  k_wt<<<(4 * 128 * 128 + 255) / 256, 256, 0, stream>>>(eW2, eW2t, 128);
  k_wt<<<(4 * 256 * 128 + 255) / 256, 256, 0, stream>>>(nW1, nW1t, 256);
  k_wt<<<(4 * 128 * 128 + 255) / 256, 256, 0, stream>>>(nW2, nW2t, 128);
  hipMemsetAsync(cnt, 0, (size_t)NND * sizeof(int), stream);
  hipMemsetAsync(cur, 0, (size_t)NND * sizeof(int), stream);
  k_hist<<<(E_N + 255) / 256, 256, 0, stream>>>(dstI, cnt);
  k_scan<<<1, 1024, 0, stream>>>(cnt, startA);
  k_fill<<<(E_N + 255) / 256, 256, 0, stream>>>(dstI, startA, cur, eids);
  k_perm<<<(E_N + 255) / 256, 256, 0, stream>>>(srcI, dstI, eids, srcP, dstP);
  k_cvtperm<<<(E_N * 16 + 255) / 256, 256, 0, stream>>>(in_ea, eids, ea16);

  const int ngrid = (NND + 63) / 64;     // 782

  for (int s = 0; s < 4; ++s) {
    hipMemsetAsync(gS, 0, (size_t)2 * NSLOT * L * sizeof(float), stream);
    k_edge_l1<<<EGRID, 512, 0, stream>>>(x16, ea16, srcP, dstP,
        eW1t + (size_t)s * 128 * 384, eb1 + (size_t)s * L, h1e, gS);
    k_bnfin<<<1, 128, 0, stream>>>(gS, eg1 + (size_t)s * L, ebe1 + (size_t)s * L,
        1.f / (float)E_N, ss);
    if (s < 3)
      k_edge_l2<false><<<EGRID, 512, 0, stream>>>(h1e, ss,
          eW2t + (size_t)s * 128 * 128, eb2 + (size_t)s * L, eids, ea, ea16);
    else
      k_edge_l2<true><<<EGRID, 512, 0, stream>>>(h1e, ss,
          eW2t + (size_t)s * 128 * 128, eb2 + (size_t)s * L, eids, ea, ea16);
    k_agg<<<(NND + 3) / 4, 256, 0, stream>>>(ea16, startA, agg16);
    hipMemsetAsync(gS, 0, (size_t)2 * NSLOT * L * sizeof(float), stream);
    k_node_l1<<<ngrid, 256, 0, stream>>>(x16, agg16,
        nW1t + (size_t)s * 128 * 256, nb1 + (size_t)s * L, h1n, gS);
    k_bnfin<<<1, 128, 0, stream>>>(gS, ng1 + (size_t)s * L, nbe1 + (size_t)s * L,
        1.f / (float)NND, ss);
    k_node_l2<<<ngrid, 256, 0, stream>>>(h1n, ss,
        nW2t + (size_t)s * 128 * 128, nb2 + (size_t)s * L,
        (s == 0) ? in_x : x, x, x16);
  }
}

// Round 17
// 1909.854 us; speedup vs baseline: 1.5826x; 1.0177x over previous
//
#include <hip/hip_runtime.h>
#include <hip/hip_bf16.h>
#include <cstdint>
#include <cstddef>

#define E_N 600000
#define NND 50000
#define L 128
#define EGRID 4688              // ceil(E_N/128) = 8 * 586
#define XCHUNK 586
#define PBLK 16384              // u16 per 128-row panel-block (8*128*16)
#define NSLOT 256

typedef unsigned short u16;
typedef unsigned int u32;
typedef __attribute__((ext_vector_type(8))) short bf16x8;
typedef __attribute__((ext_vector_type(4))) float f32x4;

static __device__ __forceinline__ u16 f2bf(float f) {
  union { float f; u32 u; } c; c.f = f;
  return (u16)((c.u + 0x7fffu + ((c.u >> 16) & 1u)) >> 16);
}
static __device__ __forceinline__ u32 pk2(float a, float b) {
  return (u32)f2bf(a) | ((u32)f2bf(b) << 16);
}
static __device__ __forceinline__ float bf2f(u32 h) {
  union { u32 u; float f; } c; c.u = (h & 0xffffu) << 16; return c.f;
}
static __device__ __forceinline__ void atomAddF(float* p, float v) {
#if defined(__HIP_DEVICE_COMPILE__)
  unsafeAtomicAdd(p, v);
#else
  atomicAdd(p, v);
#endif
}
static __device__ __forceinline__ bf16x8 bnrelu8(bf16x8 raw, float4 sca, float4 scb,
                                                 float4 sha, float4 shb) {
  union { bf16x8 v; u16 h[8]; } in; in.v = raw;
  const float sc[8] = {sca.x, sca.y, sca.z, sca.w, scb.x, scb.y, scb.z, scb.w};
  const float sh[8] = {sha.x, sha.y, sha.z, sha.w, shb.x, shb.y, shb.z, shb.w};
  float f[8];
  #pragma unroll
  for (int i = 0; i < 8; ++i) f[i] = fmaxf(bf2f(in.h[i]) * sc[i] + sh[i], 0.f);
  union { bf16x8 v; u32 w[4]; } r;
  #pragma unroll
  for (int i = 0; i < 4; ++i) r.w[i] = pk2(f[2 * i], f[2 * i + 1]);
  return r.v;
}

#define MFMA(a, bfr, c) __builtin_amdgcn_mfma_f32_16x16x32_bf16((a), (bfr), (c), 0, 0, 0)

// panel-layout address (u16 units): row-block, panel p (=col/16), local row, col%16
static __device__ __forceinline__ size_t paddr(int row, int panel, int incol) {
  return (size_t)(row >> 7) * PBLK + (size_t)panel * 2048 + (size_t)(row & 127) * 16 + incol;
}

// ================= prepass kernels =================
__global__ __launch_bounds__(256) void k_cvt4(const float* __restrict__ in,
                                              u16* __restrict__ out, int n4) {
  const int i = blockIdx.x * 256 + threadIdx.x;
  if (i < n4) {
    const float4 v = *(const float4*)(in + (size_t)i * 4);
    uint2 o; o.x = pk2(v.x, v.y); o.y = pk2(v.z, v.w);
    *(uint2*)(out + (size_t)i * 4) = o;
  }
}

// in_ea (fp32, original order) -> ea16 (bf16, permuted panel layout)
__global__ __launch_bounds__(256) void k_cvtperm(const float* __restrict__ in_ea,
                                                 const int* __restrict__ perm,
                                                 u16* __restrict__ ea16) {
  const int i = blockIdx.x * 256 + threadIdx.x;
  const int row = i >> 4, part = i & 15;      // 16 threads/row, 8 cols each
  if (row < E_N) {
    const float* p = in_ea + (size_t)perm[row] * L + part * 8;
    const float4 f0 = *(const float4*)p, f1 = *(const float4*)(p + 4);
    union { bf16x8 v; u32 w[4]; } r;
    r.w[0] = pk2(f0.x, f0.y); r.w[1] = pk2(f0.z, f0.w);
    r.w[2] = pk2(f1.x, f1.y); r.w[3] = pk2(f1.z, f1.w);
    *(bf16x8*)(ea16 + paddr(row, part >> 1, (part & 1) * 8)) = r.v;
  }
}

__global__ void k_wt(const float* __restrict__ W, u16* __restrict__ Wt, int K) {
  const int idx = blockIdx.x * 256 + threadIdx.x;
  const int total = 4 * K * 128;
  if (idx >= total) return;
  const int s = idx / (K * 128);
  const int rem = idx - s * K * 128;
  const int n = rem / K;
  const int k = rem - n * K;
  Wt[idx] = f2bf(W[(size_t)s * K * 128 + (size_t)k * 128 + n]);
}

__global__ void k_hist(const int* __restrict__ dstI, int* __restrict__ cnt) {
  const int i = blockIdx.x * 256 + threadIdx.x;
  if (i < E_N) atomicAdd(&cnt[dstI[i]], 1);
}

__global__ __launch_bounds__(1024) void k_scan(const int* __restrict__ cnt, int* __restrict__ startA) {
  __shared__ int buf[1024];
  __shared__ int carry;
  const int tid = threadIdx.x;
  if (tid == 0) carry = 0;
  __syncthreads();
  for (int base = 0; base < NND; base += 1024) {
    int v = (base + tid < NND) ? cnt[base + tid] : 0;
    buf[tid] = v;
    __syncthreads();
    for (int off = 1; off < 1024; off <<= 1) {
      int t = (tid >= off) ? buf[tid - off] : 0;
      __syncthreads();
      buf[tid] += t;
      __syncthreads();
    }
    const int incl = buf[tid];
    const int c = carry;
    if (base + tid < NND) startA[base + tid] = c + incl - v;
    __syncthreads();
    if (tid == 1023) carry = c + incl;
    __syncthreads();
  }
  if (tid == 0) startA[NND] = carry;
}

__global__ void k_fill(const int* __restrict__ dstI, const int* __restrict__ startA,
                       int* __restrict__ cur, int* __restrict__ eids) {
  const int i = blockIdx.x * 256 + threadIdx.x;
  if (i < E_N) {
    const int d = dstI[i];
    const int pos = atomicAdd(&cur[d], 1);
    eids[startA[d] + pos] = i;
  }
}

__global__ void k_perm(const int* __restrict__ srcI, const int* __restrict__ dstI,
                       const int* __restrict__ perm,
                       int* __restrict__ srcP, int* __restrict__ dstP) {
  const int i = blockIdx.x * 256 + threadIdx.x;
  if (i < E_N) {
    const int e = perm[i];
    srcP[i] = srcI[e];
    dstP[i] = dstI[e];
  }
}

// ================= aggregation (panel ea16 -> row-major agg16) =================
__global__ __launch_bounds__(256) void k_agg(const u16* __restrict__ ea16,
                                             const int* __restrict__ startA,
                                             u16* __restrict__ agg16) {
  const int node = blockIdx.x * 4 + (threadIdx.x >> 6);
  const int lane = threadIdx.x & 63;
  if (node >= NND) return;
  const int s = startA[node], e = startA[node + 1];
  const size_t poff = (size_t)(lane >> 3) * 2048 + (size_t)((lane & 7) * 2);
  float a0 = 0.f, a1 = 0.f, b0 = 0.f, b1 = 0.f;
  int i = s;
  for (; i + 1 < e; i += 2) {
    const u32 v0 = *(const u32*)(ea16 + (size_t)(i >> 7) * PBLK + (size_t)(i & 127) * 16 + poff);
    const int j = i + 1;
    const u32 v1 = *(const u32*)(ea16 + (size_t)(j >> 7) * PBLK + (size_t)(j & 127) * 16 + poff);
    a0 += bf2f(v0); a1 += bf2f(v0 >> 16);
    b0 += bf2f(v1); b1 += bf2f(v1 >> 16);
  }
  if (i < e) {
    const u32 v = *(const u32*)(ea16 + (size_t)(i >> 7) * PBLK + (size_t)(i & 127) * 16 + poff);
    a0 += bf2f(v); a1 += bf2f(v >> 16);
  }
  *(u32*)(agg16 + (size_t)node * L + lane * 2) = pk2(a0 + b0, a1 + b1);
}

// ================= BN finalize =================
__global__ void k_bnfin(const float* __restrict__ gS, const float* __restrict__ g,
                        const float* __restrict__ be, float invM, float* __restrict__ ss) {
  const int c = threadIdx.x;
  float s1 = 0.f, s2 = 0.f;
  for (int j = 0; j < NSLOT; ++j) { s1 += gS[j * L + c]; s2 += gS[NSLOT * L + j * L + c]; }
  const float mean = s1 * invM;
  const float var = s2 * invM - mean * mean;
  const float sc = g[c] * rsqrtf(var + 1e-5f);
  ss[c] = sc;
  ss[L + c] = be[c] - mean * sc;
}

// ================= edge layer 1: 2D wave tile (32 rows x 64 cols), A private, W via 2-buffer LDS =================
// chunk order {ea0, ea1, dst0, dst1, src0, src1} -> W k-windows {4,5,0,1,2,3}
// (ea streams from HBM: issue at t=0 for max latency cover; dst/src are L2-hot, 3-chunk prefetch)
__global__ __launch_bounds__(512, 4) void k_edge_l1(
    const u16* __restrict__ x16, const u16* __restrict__ ea16,
    const int* __restrict__ srcP, const int* __restrict__ dstP,
    const u16* __restrict__ Wt, const float* __restrict__ b,
    u16* __restrict__ h1, float* __restrict__ gS)
{
  __shared__ __align__(16) char Ws2[2 * 16384];
  __shared__ float red[256];
  const int tid = threadIdx.x;
  const int bid = (blockIdx.x & 7) * XCHUNK + (blockIdx.x >> 3);  // XCD-aware swizzle
  const int row0 = bid * 128;
  const int lane = tid & 63, wid = tid >> 6;
  const int wr = wid >> 1, wc = wid & 1;
  const int l15 = lane & 15, lq = lane >> 4;
  if (tid < 256) red[tid] = 0.f;

  int crw[2], dI[2], sI[2];
  #pragma unroll
  for (int m = 0; m < 2; ++m) {
    crw[m] = min(row0 + wr * 32 + m * 16 + l15, E_N - 1);
    dI[m] = dstP[crw[m]];
    sI[m] = srcP[crw[m]];
  }

  const int kcMap[6] = {4, 5, 0, 1, 2, 3};   // W k-window for chunk index ci

  // private A fragments, 3-deep rolling window: af3[ci%3][m][k2]
  bf16x8 af3[3][2][2];
  auto loadA = [&](int ci, bf16x8 (&dst)[2][2]) {
    #pragma unroll
    for (int m = 0; m < 2; ++m) {
      if (ci < 2) {           // edge_attr (HBM stream, panel layout)
        dst[m][0] = *(const bf16x8*)(ea16 + paddr(crw[m], ci * 4 + (lq >> 1), (lq & 1) * 8));
        dst[m][1] = *(const bf16x8*)(ea16 + paddr(crw[m], ci * 4 + 2 + (lq >> 1), (lq & 1) * 8));
      } else {                // x[dst] (ci=2,3) or x[src] (ci=4,5), L2-resident gathers
        const int node = (ci < 4) ? dI[m] : sI[m];
        const u16* p = x16 + (size_t)node * L + (ci & 1) * 64 + lq * 8;
        dst[m][0] = *(const bf16x8*)p;
        dst[m][1] = *(const bf16x8*)(p + 32);
      }
    }
  };
  loadA(0, af3[0]); loadA(1, af3[1]); loadA(2, af3[2]);

  // W staging: linear LDS write, pre-swizzled global source
  const int n0 = tid >> 3,         kq0 = (tid & 7) ^ (n0 & 7);
  const int n1 = (tid + 512) >> 3, kq1 = ((tid + 512) & 7) ^ (n1 & 7);
  uint4 wa, wb;
  auto wload = [&](int kw) {
    wa = *(const uint4*)(Wt + (size_t)n0 * 384 + kw * 64 + kq0 * 8);
    wb = *(const uint4*)(Wt + (size_t)n1 * 384 + kw * 64 + kq1 * 8);
  };
  auto wwrite = [&](int buf) {
    *(uint4*)(Ws2 + buf * 16384 + tid * 16) = wa;
    *(uint4*)(Ws2 + buf * 16384 + tid * 16 + 8192) = wb;
  };

  wload(kcMap[0]);
  wwrite(0);
  __syncthreads();

  f32x4 acc[2][4];
  #pragma unroll
  for (int m = 0; m < 2; ++m)
    #pragma unroll
    for (int n = 0; n < 4; ++n) acc[m][n] = (f32x4){0.f, 0.f, 0.f, 0.f};

  #pragma unroll
  for (int cc = 0; cc < 6; ++cc) {
    if (cc + 1 < 6) wload(kcMap[cc + 1]);
    const char* base = Ws2 + (cc & 1) * 16384;
    const bf16x8 (&af)[2][2] = af3[cc % 3];
    __builtin_amdgcn_s_setprio(1);
    #pragma unroll
    for (int k2 = 0; k2 < 2; ++k2)
      #pragma unroll
      for (int n = 0; n < 4; ++n) {
        const int ncol = wc * 64 + n * 16 + l15;
        const int sw = (ncol & 7) << 4;
        const bf16x8 wf = *(const bf16x8*)(base + ((ncol * 128 + k2 * 64 + lq * 16) ^ sw));
        acc[0][n] = MFMA(wf, af[0][k2], acc[0][n]);
        acc[1][n] = MFMA(wf, af[1][k2], acc[1][n]);
      }
    __builtin_amdgcn_s_setprio(0);
    if (cc + 3 < 6) loadA(cc + 3, af3[cc % 3]);
    if (cc + 1 < 6) wwrite((cc + 1) & 1);
    __syncthreads();
  }

  // epilogue: bias, stats (m-accumulated, one shuffle tree per n), ushort4 panel stores
  #pragma unroll
  for (int n = 0; n < 4; ++n) {
    const int colb = wc * 64 + n * 16 + lq * 4;
    const float4 bb = *(const float4*)(b + colb);
    float s1[4] = {0.f, 0.f, 0.f, 0.f}, s2[4] = {0.f, 0.f, 0.f, 0.f};
    #pragma unroll
    for (int m = 0; m < 2; ++m) {
      const int rl = wr * 32 + m * 16 + l15;
      const bool valid = row0 + rl < E_N;
      float o[4];
      o[0] = acc[m][n][0] + bb.x; o[1] = acc[m][n][1] + bb.y;
      o[2] = acc[m][n][2] + bb.z; o[3] = acc[m][n][3] + bb.w;
      if (valid) {
        #pragma unroll
        for (int r = 0; r < 4; ++r) { s1[r] += o[r]; s2[r] += o[r] * o[r]; }
        ushort4 st;
        st.x = f2bf(o[0]); st.y = f2bf(o[1]); st.z = f2bf(o[2]); st.w = f2bf(o[3]);
        *(ushort4*)(h1 + (size_t)bid * PBLK + (size_t)(wc * 4 + n) * 2048 + rl * 16 + lq * 4) = st;
      }
    }
    #pragma unroll
    for (int off = 1; off < 16; off <<= 1)
      #pragma unroll
      for (int r = 0; r < 4; ++r) {
        s1[r] += __shfl_xor(s1[r], off);
        s2[r] += __shfl_xor(s2[r], off);
      }
    if (l15 == 0) {
      #pragma unroll
      for (int r = 0; r < 4; ++r) {
        atomAddF(&red[colb + r], s1[r]);
        atomAddF(&red[128 + colb + r], s2[r]);
      }
    }
  }
  __syncthreads();
  const int slot = (bid & (NSLOT - 1)) * L;
  if (tid < 128) atomAddF(&gS[slot + tid], red[tid]);
  else if (tid < 256) atomAddF(&gS[NSLOT * L + slot + (tid - 128)], red[tid]);
}

// ================= edge layer 2: 2D wave tile, W staged once (32 KB) =================
template <bool WF32>
__global__ __launch_bounds__(512, 4) void k_edge_l2(
    const u16* __restrict__ h1, const float* __restrict__ ss,
    const u16* __restrict__ Wt, const float* __restrict__ b,
    const int* __restrict__ perm,
    float* __restrict__ ea_out, u16* __restrict__ ea16)
{
  __shared__ __align__(16) char Ws2[2 * 16384];
  const int tid = threadIdx.x;
  const int bid = (blockIdx.x & 7) * XCHUNK + (blockIdx.x >> 3);  // XCD-aware swizzle
  const int row0 = bid * 128;
  const int lane = tid & 63, wid = tid >> 6;
  const int wr = wid >> 1, wc = wid & 1;
  const int l15 = lane & 15, lq = lane >> 4;

  int crw[2];
  #pragma unroll
  for (int m = 0; m < 2; ++m)
    crw[m] = min(row0 + wr * 32 + m * 16 + l15, E_N - 1);

  // stage both W chunks (linear write, pre-swizzled source)
  const int n0 = tid >> 3,         kq0 = (tid & 7) ^ (n0 & 7);
  const int n1 = (tid + 512) >> 3, kq1 = ((tid + 512) & 7) ^ (n1 & 7);
  #pragma unroll
  for (int cc = 0; cc < 2; ++cc) {
    const uint4 wa = *(const uint4*)(Wt + (size_t)n0 * 128 + cc * 64 + kq0 * 8);
    const uint4 wb = *(const uint4*)(Wt + (size_t)n1 * 128 + cc * 64 + kq1 * 8);
    *(uint4*)(Ws2 + cc * 16384 + tid * 16) = wa;
    *(uint4*)(Ws2 + cc * 16384 + tid * 16 + 8192) = wb;
  }

  // private A (h1 panel), raw
  bf16x8 ah[2][2][2];  // [cc][m][k2]
  #pragma unroll
  for (int cc = 0; cc < 2; ++cc)
    #pragma unroll
    for (int m = 0; m < 2; ++m)
      #pragma unroll
      for (int k2 = 0; k2 < 2; ++k2)
        ah[cc][m][k2] = *(const bf16x8*)(h1 + paddr(crw[m], cc * 4 + k2 * 2 + (lq >> 1), (lq & 1) * 8));
  __syncthreads();

  f32x4 acc[2][4];
  #pragma unroll
  for (int m = 0; m < 2; ++m)
    #pragma unroll
    for (int n = 0; n < 4; ++n) acc[m][n] = (f32x4){0.f, 0.f, 0.f, 0.f};

  #pragma unroll
  for (int cc = 0; cc < 2; ++cc)
    #pragma unroll
    for (int k2 = 0; k2 < 2; ++k2) {
      const int kb = cc * 64 + k2 * 32 + lq * 8;
      const float4 sca = *(const float4*)(ss + kb), scb = *(const float4*)(ss + kb + 4);
      const float4 sha = *(const float4*)(ss + 128 + kb), shb = *(const float4*)(ss + 128 + kb + 4);
      const bf16x8 a0 = bnrelu8(ah[cc][0][k2], sca, scb, sha, shb);
      const bf16x8 a1 = bnrelu8(ah[cc][1][k2], sca, scb, sha, shb);
      const char* base = Ws2 + cc * 16384;
      __builtin_amdgcn_s_setprio(1);
      #pragma unroll
      for (int n = 0; n < 4; ++n) {
        const int ncol = wc * 64 + n * 16 + l15;
        const int sw = (ncol & 7) << 4;
        const bf16x8 wf = *(const bf16x8*)(base + ((ncol * 128 + k2 * 64 + lq * 16) ^ sw));
        acc[0][n] = MFMA(wf, a0, acc[0][n]);
        acc[1][n] = MFMA(wf, a1, acc[1][n]);
      }
      __builtin_amdgcn_s_setprio(0);
    }

  // epilogue: o = relu(acc+bias) + resid (in-place panel RMW); fp32 scatter at s=3
  #pragma unroll
  for (int m = 0; m < 2; ++m) {
    const int rl = wr * 32 + m * 16 + l15;
    const int row = row0 + rl;
    if (row < E_N) {
      const int prow = WF32 ? perm[row] : 0;
      #pragma unroll
      for (int n = 0; n < 4; ++n) {
        const int colb = wc * 64 + n * 16 + lq * 4;
        const float4 bb = *(const float4*)(b + colb);
        float o[4];
        o[0] = fmaxf(acc[m][n][0] + bb.x, 0.f);
        o[1] = fmaxf(acc[m][n][1] + bb.y, 0.f);
        o[2] = fmaxf(acc[m][n][2] + bb.z, 0.f);
        o[3] = fmaxf(acc[m][n][3] + bb.w, 0.f);
        u16* ep = ea16 + (size_t)bid * PBLK + (size_t)(wc * 4 + n) * 2048 + rl * 16 + lq * 4;
        const ushort4 rv = *(const ushort4*)ep;
        o[0] += bf2f(rv.x); o[1] += bf2f(rv.y); o[2] += bf2f(rv.z); o[3] += bf2f(rv.w);
        ushort4 st;
        st.x = f2bf(o[0]); st.y = f2bf(o[1]); st.z = f2bf(o[2]); st.w = f2bf(o[3]);
        *(ushort4*)ep = st;
        if (WF32) {
          float4 fv; fv.x = o[0]; fv.y = o[1]; fv.z = o[2]; fv.w = o[3];
          *(float4*)(ea_out + (size_t)prow * L + colb) = fv;
        }
      }
    }
  }
}

// ================= node layer 1 (x16 + agg16 bf16, row-major) =================
__global__ __launch_bounds__(256) void k_node_l1(
    const u16* __restrict__ x16, const u16* __restrict__ agg16,
    const u16* __restrict__ Wt, const float* __restrict__ b,
    u16* __restrict__ h1, float* __restrict__ gS)
{
  __shared__ __align__(16) char Bs[2][16384];
  __shared__ float red[256];
  const int tid = threadIdx.x, bid = blockIdx.x, row0 = bid * 64;
  red[tid] = 0.f;
  const int lane = tid & 63, wid = tid >> 6, wr = wid >> 1, wc = wid & 1;
  const int l15 = lane & 15, lq = lane >> 4;
  const int r0 = row0 + wr * 32 + l15, r1 = r0 + 16;
  const int rr0 = min(r0, NND - 1), rr1 = min(r1, NND - 1);

  const u16* aP[2][2];
  aP[0][0] = x16 + (size_t)rr0 * L;   aP[1][0] = x16 + (size_t)rr1 * L;
  aP[0][1] = agg16 + (size_t)rr0 * L; aP[1][1] = agg16 + (size_t)rr1 * L;

  f32x4 acc[2][4];
  #pragma unroll
  for (int m = 0; m < 2; ++m)
    #pragma unroll
    for (int n = 0; n < 4; ++n) acc[m][n] = (f32x4){0.f, 0.f, 0.f, 0.f};

  auto loadA = [&](int c, bf16x8 (&af)[2][2]) {
    const int seg = c >> 1;
    const int base = (c & 1) * 64 + lq * 8;
    #pragma unroll
    for (int k2 = 0; k2 < 2; ++k2) {
      af[0][k2] = *(const bf16x8*)(aP[0][seg] + base + k2 * 32);
      af[1][k2] = *(const bf16x8*)(aP[1][seg] + base + k2 * 32);
    }
  };
  auto stage = [&](int c, int buf) {
    #pragma unroll
    for (int i = 0; i < 4; ++i) {
      const int slot = tid + i * 256;
      const int n = slot >> 3, kq = slot & 7;
      const uint4 v = *(const uint4*)(Wt + (size_t)n * 256 + c * 64 + kq * 8);
      *(uint4*)(&Bs[buf][0] + ((n * 128 + kq * 16) ^ ((n & 7) << 4))) = v;
    }
  };

  bf16x8 aCur[2][2], aNxt[2][2];
  loadA(0, aCur);
  stage(0, 0);
  __syncthreads();
  #pragma unroll
  for (int c = 0; c < 4; ++c) {
    if (c + 1 < 4) loadA(c + 1, aNxt);
    {
      const char* base = &Bs[c & 1][0];
      #pragma unroll
      for (int k2 = 0; k2 < 2; ++k2)
        #pragma unroll
        for (int n = 0; n < 4; ++n) {
          const int ncol = wc * 64 + n * 16 + l15;
          const bf16x8 bfr = *(const bf16x8*)(base + ((ncol * 128 + k2 * 64 + lq * 16) ^ ((ncol & 7) << 4)));
          acc[0][n] = MFMA(aCur[0][k2], bfr, acc[0][n]);
          acc[1][n] = MFMA(aCur[1][k2], bfr, acc[1][n]);
        }
    }
    if (c + 1 < 4) stage(c + 1, (c + 1) & 1);
    __syncthreads();
    #pragma unroll
    for (int m = 0; m < 2; ++m)
      #pragma unroll
      for (int k2 = 0; k2 < 2; ++k2) aCur[m][k2] = aNxt[m][k2];
  }

  float bb[4], s1[4], s2[4];
  #pragma unroll
  for (int n = 0; n < 4; ++n) { bb[n] = b[wc * 64 + n * 16 + l15]; s1[n] = 0.f; s2[n] = 0.f; }
  #pragma unroll
  for (int m = 0; m < 2; ++m)
    #pragma unroll
    for (int n = 0; n < 4; ++n) {
      const int ncol = wc * 64 + n * 16 + l15;
      #pragma unroll
      for (int r = 0; r < 4; ++r) {
        const int row = row0 + wr * 32 + m * 16 + lq * 4 + r;
        if (row < NND) {
          const float o = acc[m][n][r] + bb[n];
          s1[n] += o; s2[n] += o * o;
          h1[(size_t)row * L + ncol] = f2bf(o);
        }
      }
    }
  #pragma unroll
  for (int n = 0; n < 4; ++n) {
    const int ncol = wc * 64 + n * 16 + l15;
    atomAddF(&red[ncol], s1[n]);
    atomAddF(&red[128 + ncol], s2[n]);
  }
  __syncthreads();
  const int slot = (bid & (NSLOT - 1)) * L;
  if (tid < 128) atomAddF(&gS[slot + tid], red[tid]);
  else atomAddF(&gS[NSLOT * L + slot + (tid - 128)], red[tid]);
}

// ================= node layer 2 =================
__global__ __launch_bounds__(256) void k_node_l2(
    const u16* __restrict__ h1, const float* __restrict__ ss,
    const u16* __restrict__ Wt, const float* __restrict__ b,
    const float* __restrict__ resid, float* __restrict__ x_out,
    u16* __restrict__ x16)
{
  __shared__ __align__(16) char Bs[2][16384];
  const int tid = threadIdx.x, bid = blockIdx.x, row0 = bid * 64;
  const int lane = tid & 63, wid = tid >> 6, wr = wid >> 1, wc = wid & 1;
  const int l15 = lane & 15, lq = lane >> 4;
  const int r0 = row0 + wr * 32 + l15, r1 = r0 + 16;
  const int rr0 = min(r0, NND - 1), rr1 = min(r1, NND - 1);
  const u16* a0 = h1 + (size_t)rr0 * L + lq * 8;
  const u16* a1 = h1 + (size_t)rr1 * L + lq * 8;

  f32x4 acc[2][4];
  #pragma unroll
  for (int m = 0; m < 2; ++m)
    #pragma unroll
    for (int n = 0; n < 4; ++n) acc[m][n] = (f32x4){0.f, 0.f, 0.f, 0.f};

  auto stage = [&](int c, int buf) {
    #pragma unroll
    for (int i = 0; i < 4; ++i) {
      const int slot = tid + i * 256;
      const int n = slot >> 3, kq = slot & 7;
      const uint4 v = *(const uint4*)(Wt + (size_t)n * 128 + c * 64 + kq * 8);
      *(uint4*)(&Bs[buf][0] + ((n * 128 + kq * 16) ^ ((n & 7) << 4))) = v;
    }
  };
  stage(0, 0);
  stage(1, 1);
  bf16x8 raw[2][2][2];
  #pragma unroll
  for (int c = 0; c < 2; ++c)
    #pragma unroll
    for (int k2 = 0; k2 < 2; ++k2) {
      raw[c][0][k2] = *(const bf16x8*)(a0 + c * 64 + k2 * 32);
      raw[c][1][k2] = *(const bf16x8*)(a1 + c * 64 + k2 * 32);
    }
  __syncthreads();

  #pragma unroll
  for (int c = 0; c < 2; ++c) {
    bf16x8 af[2][2];
    #pragma unroll
    for (int k2 = 0; k2 < 2; ++k2) {
      const int kg = c * 64 + k2 * 32 + lq * 8;
      const float4 sca = *(const float4*)(ss + kg), scb = *(const float4*)(ss + kg + 4);
      const float4 sha = *(const float4*)(ss + 128 + kg), shb = *(const float4*)(ss + 128 + kg + 4);
      af[0][k2] = bnrelu8(raw[c][0][k2], sca, scb, sha, shb);
      af[1][k2] = bnrelu8(raw[c][1][k2], sca, scb, sha, shb);
    }
    const char* base = &Bs[c][0];
    #pragma unroll
    for (int k2 = 0; k2 < 2; ++k2)
      #pragma unroll
      for (int n = 0; n < 4; ++n) {
        const int ncol = wc * 64 + n * 16 + l15;
        const bf16x8 bfr = *(const bf16x8*)(base + ((ncol * 128 + k2 * 64 + lq * 16) ^ ((ncol & 7) << 4)));
        acc[0][n] = MFMA(af[0][k2], bfr, acc[0][n]);
        acc[1][n] = MFMA(af[1][k2], bfr, acc[1][n]);
      }
  }

  float bb[4];
  #pragma unroll
  for (int n = 0; n < 4; ++n) bb[n] = b[wc * 64 + n * 16 + l15];
  #pragma unroll
  for (int m = 0; m < 2; ++m)
    #pragma unroll
    for (int n = 0; n < 4; ++n) {
      const int ncol = wc * 64 + n * 16 + l15;
      #pragma unroll
      for (int r = 0; r < 4; ++r) {
        const int row = row0 + wr * 32 + m * 16 + lq * 4 + r;
        if (row < NND) {
          const float o = fmaxf(acc[m][n][r] + bb[n], 0.f) + resid[(size_t)row * L + ncol];
          x_out[(size_t)row * L + ncol] = o;
          x16[(size_t)row * L + ncol] = f2bf(o);
        }
      }
    }
}

extern "C" void kernel_launch(void* const* d_in, const int* in_sizes, int n_in,
                              void* d_out, int out_size, void* d_ws, size_t ws_size,
                              hipStream_t stream) {
  (void)in_sizes; (void)n_in; (void)out_size; (void)ws_size;
  const float* in_x  = (const float*)d_in[0];
  const float* in_ea = (const float*)d_in[1];
  const int*   ei    = (const int*)d_in[2];
  const float* eW1 = (const float*)d_in[3];
  const float* eb1 = (const float*)d_in[4];
  const float* eg1 = (const float*)d_in[5];
  const float* ebe1= (const float*)d_in[6];
  const float* eW2 = (const float*)d_in[7];
  const float* eb2 = (const float*)d_in[8];
  const float* nW1 = (const float*)d_in[9];
  const float* nb1 = (const float*)d_in[10];
  const float* ng1 = (const float*)d_in[11];
  const float* nbe1= (const float*)d_in[12];
  const float* nW2 = (const float*)d_in[13];
  const float* nb2 = (const float*)d_in[14];

  float* x  = (float*)d_out;                    // [NND][L]
  float* ea = (float*)d_out + (size_t)NND * L;  // [E_N][L]

  char* w = (char*)d_ws;
  u16* h1e   = (u16*)w;   w += (size_t)EGRID * PBLK * sizeof(u16);  // panel layout
  u16* ea16  = (u16*)w;   w += (size_t)EGRID * PBLK * sizeof(u16);  // panel layout
  u16* h1n   = (u16*)w;   w += (size_t)NND * L * sizeof(u16);
  u16* x16   = (u16*)w;   w += (size_t)NND * L * sizeof(u16);
  u16* agg16 = (u16*)w;   w += (size_t)NND * L * sizeof(u16);
  float* gS  = (float*)w; w += (size_t)2 * NSLOT * L * sizeof(float);
  float* ss  = (float*)w; w += 4096;
  u16* eW1t = (u16*)w;   w += (size_t)4 * 128 * 384 * sizeof(u16);
  u16* eW2t = (u16*)w;   w += (size_t)4 * 128 * 128 * sizeof(u16);
  u16* nW1t = (u16*)w;   w += (size_t)4 * 128 * 256 * sizeof(u16);
  u16* nW2t = (u16*)w;   w += (size_t)4 * 128 * 128 * sizeof(u16);
  int* cnt    = (int*)w; w += (size_t)NND * sizeof(int);
  int* cur    = (int*)w; w += (size_t)NND * sizeof(int);
  int* startA = (int*)w; w += (size_t)(NND + 64) * sizeof(int);
  int* eids   = (int*)w; w += (size_t)E_N * sizeof(int);     // = perm
  int* srcP   = (int*)w; w += (size_t)E_N * sizeof(int);
  int* dstP   = (int*)w; w += (size_t)E_N * sizeof(int);

  const int* srcI = ei;
  const int* dstI = ei + E_N;

  k_cvt4<<<(NND * L / 4 + 255) / 256, 256, 0, stream>>>(in_x, x16, NND * L / 4);
  k_wt<<<(4 * 384 * 128 + 255) / 256, 256, 0, stream>>>(eW1, eW1t, 384);
  k_wt<<<(4 * 128 * 128 + 255) / 256, 256, 0, stream>>>(eW2, eW2t, 128);
  k_wt<<<(4 * 256 * 128 + 255) / 256, 256, 0, stream>>>(nW1, nW1t, 256);
  k_wt<<<(4 * 128 * 128 + 255) / 256, 256, 0, stream>>>(nW2, nW2t, 128);
  hipMemsetAsync(cnt, 0, (size_t)NND * sizeof(int), stream);
  hipMemsetAsync(cur, 0, (size_t)NND * sizeof(int), stream);
  k_hist<<<(E_N + 255) / 256, 256, 0, stream>>>(dstI, cnt);
  k_scan<<<1, 1024, 0, stream>>>(cnt, startA);
  k_fill<<<(E_N + 255) / 256, 256, 0, stream>>>(dstI, startA, cur, eids);
  k_perm<<<(E_N + 255) / 256, 256, 0, stream>>>(srcI, dstI, eids, srcP, dstP);
  k_cvtperm<<<(E_N * 16 + 255) / 256, 256, 0, stream>>>(in_ea, eids, ea16);

  const int ngrid = (NND + 63) / 64;     // 782

  for (int s = 0; s < 4; ++s) {
    hipMemsetAsync(gS, 0, (size_t)2 * NSLOT * L * sizeof(float), stream);
    k_edge_l1<<<EGRID, 512, 0, stream>>>(x16, ea16, srcP, dstP,
        eW1t + (size_t)s * 128 * 384, eb1 + (size_t)s * L, h1e, gS);
    k_bnfin<<<1, 128, 0, stream>>>(gS, eg1 + (size_t)s * L, ebe1 + (size_t)s * L,
        1.f / (float)E_N, ss);
    if (s < 3)
      k_edge_l2<false><<<EGRID, 512, 0, stream>>>(h1e, ss,
          eW2t + (size_t)s * 128 * 128, eb2 + (size_t)s * L, eids, ea, ea16);
    else
      k_edge_l2<true><<<EGRID, 512, 0, stream>>>(h1e, ss,
          eW2t + (size_t)s * 128 * 128, eb2 + (size_t)s * L, eids, ea, ea16);
    k_agg<<<(NND + 3) / 4, 256, 0, stream>>>(ea16, startA, agg16);
    hipMemsetAsync(gS, 0, (size_t)2 * NSLOT * L * sizeof(float), stream);
    k_node_l1<<<ngrid, 256, 0, stream>>>(x16, agg16,
        nW1t + (size_t)s * 128 * 256, nb1 + (size_t)s * L, h1n, gS);
    k_bnfin<<<1, 128, 0, stream>>>(gS, ng1 + (size_t)s * L, nbe1 + (size_t)s * L,
        1.f / (float)NND, ss);
    k_node_l2<<<ngrid, 256, 0, stream>>>(h1n, ss,
        nW2t + (size_t)s * 128 * 128, nb2 + (size_t)s * L,
        (s == 0) ? in_x : x, x, x16);
  }
}

// Round 19
// 1844.032 us; speedup vs baseline: 1.6391x; 1.0357x over previous
//
#include <hip/hip_runtime.h>
#include <hip/hip_bf16.h>
#include <cstdint>
#include <cstddef>

#define E_N 600000
#define NND 50000
#define L 128
#define EGRID 4688              // ceil(E_N/128) = 8 * 586
#define XCHUNK 586
#define PBLK 16384              // u16 per 128-row panel-block (8*128*16)
#define NSLOT 256

typedef unsigned short u16;
typedef unsigned int u32;
typedef __attribute__((ext_vector_type(8))) short bf16x8;
typedef __attribute__((ext_vector_type(4))) float f32x4;

static __device__ __forceinline__ u16 f2bf(float f) {
  union { float f; u32 u; } c; c.f = f;
  return (u16)((c.u + 0x7fffu + ((c.u >> 16) & 1u)) >> 16);
}
static __device__ __forceinline__ u32 pk2(float a, float b) {
  return (u32)f2bf(a) | ((u32)f2bf(b) << 16);
}
static __device__ __forceinline__ float bf2f(u32 h) {
  union { u32 u; float f; } c; c.u = (h & 0xffffu) << 16; return c.f;
}
static __device__ __forceinline__ void atomAddF(float* p, float v) {
#if defined(__HIP_DEVICE_COMPILE__)
  unsafeAtomicAdd(p, v);
#else
  atomicAdd(p, v);
#endif
}
static __device__ __forceinline__ bf16x8 bnrelu8(bf16x8 raw, float4 sca, float4 scb,
                                                 float4 sha, float4 shb) {
  union { bf16x8 v; u16 h[8]; } in; in.v = raw;
  const float sc[8] = {sca.x, sca.y, sca.z, sca.w, scb.x, scb.y, scb.z, scb.w};
  const float sh[8] = {sha.x, sha.y, sha.z, sha.w, shb.x, shb.y, shb.z, shb.w};
  float f[8];
  #pragma unroll
  for (int i = 0; i < 8; ++i) f[i] = fmaxf(bf2f(in.h[i]) * sc[i] + sh[i], 0.f);
  union { bf16x8 v; u32 w[4]; } r;
  #pragma unroll
  for (int i = 0; i < 4; ++i) r.w[i] = pk2(f[2 * i], f[2 * i + 1]);
  return r.v;
}

#define MFMA(a, bfr, c) __builtin_amdgcn_mfma_f32_16x16x32_bf16((a), (bfr), (c), 0, 0, 0)

// panel-layout address (u16 units): row-block, panel p (=col/16), local row, col%16
static __device__ __forceinline__ size_t paddr(int row, int panel, int incol) {
  return (size_t)(row >> 7) * PBLK + (size_t)panel * 2048 + (size_t)(row & 127) * 16 + incol;
}

// ================= prepass kernels =================
__global__ __launch_bounds__(256) void k_cvt4(const float* __restrict__ in,
                                              u16* __restrict__ out, int n4) {
  const int i = blockIdx.x * 256 + threadIdx.x;
  if (i < n4) {
    const float4 v = *(const float4*)(in + (size_t)i * 4);
    uint2 o; o.x = pk2(v.x, v.y); o.y = pk2(v.z, v.w);
    *(uint2*)(out + (size_t)i * 4) = o;
  }
}

// in_ea (fp32, original order) -> ea16 (bf16, permuted panel layout)
__global__ __launch_bounds__(256) void k_cvtperm(const float* __restrict__ in_ea,
                                                 const int* __restrict__ perm,
                                                 u16* __restrict__ ea16) {
  const int i = blockIdx.x * 256 + threadIdx.x;
  const int row = i >> 4, part = i & 15;      // 16 threads/row, 8 cols each
  if (row < E_N) {
    const float* p = in_ea + (size_t)perm[row] * L + part * 8;
    const float4 f0 = *(const float4*)p, f1 = *(const float4*)(p + 4);
    union { bf16x8 v; u32 w[4]; } r;
    r.w[0] = pk2(f0.x, f0.y); r.w[1] = pk2(f0.z, f0.w);
    r.w[2] = pk2(f1.x, f1.y); r.w[3] = pk2(f1.z, f1.w);
    *(bf16x8*)(ea16 + paddr(row, part >> 1, (part & 1) * 8)) = r.v;
  }
}

__global__ void k_wt(const float* __restrict__ W, u16* __restrict__ Wt, int K) {
  const int idx = blockIdx.x * 256 + threadIdx.x;
  const int total = 4 * K * 128;
  if (idx >= total) return;
  const int s = idx / (K * 128);
  const int rem = idx - s * K * 128;
  const int n = rem / K;
  const int k = rem - n * K;
  Wt[idx] = f2bf(W[(size_t)s * K * 128 + (size_t)k * 128 + n]);
}

__global__ void k_hist(const int* __restrict__ dstI, int* __restrict__ cnt) {
  const int i = blockIdx.x * 256 + threadIdx.x;
  if (i < E_N) atomicAdd(&cnt[dstI[i]], 1);
}

__global__ __launch_bounds__(1024) void k_scan(const int* __restrict__ cnt, int* __restrict__ startA) {
  __shared__ int buf[1024];
  __shared__ int carry;
  const int tid = threadIdx.x;
  if (tid == 0) carry = 0;
  __syncthreads();
  for (int base = 0; base < NND; base += 1024) {
    int v = (base + tid < NND) ? cnt[base + tid] : 0;
    buf[tid] = v;
    __syncthreads();
    for (int off = 1; off < 1024; off <<= 1) {
      int t = (tid >= off) ? buf[tid - off] : 0;
      __syncthreads();
      buf[tid] += t;
      __syncthreads();
    }
    const int incl = buf[tid];
    const int c = carry;
    if (base + tid < NND) startA[base + tid] = c + incl - v;
    __syncthreads();
    if (tid == 1023) carry = c + incl;
    __syncthreads();
  }
  if (tid == 0) startA[NND] = carry;
}

__global__ void k_fill(const int* __restrict__ dstI, const int* __restrict__ startA,
                       int* __restrict__ cur, int* __restrict__ eids) {
  const int i = blockIdx.x * 256 + threadIdx.x;
  if (i < E_N) {
    const int d = dstI[i];
    const int pos = atomicAdd(&cur[d], 1);
    eids[startA[d] + pos] = i;
  }
}

__global__ void k_perm(const int* __restrict__ srcI, const int* __restrict__ dstI,
                       const int* __restrict__ perm,
                       int* __restrict__ srcP, int* __restrict__ dstP) {
  const int i = blockIdx.x * 256 + threadIdx.x;
  if (i < E_N) {
    const int e = perm[i];
    srcP[i] = srcI[e];
    dstP[i] = dstI[e];
  }
}

// ================= aggregation (panel ea16 -> row-major agg16) =================
__global__ __launch_bounds__(256) void k_agg(const u16* __restrict__ ea16,
                                             const int* __restrict__ startA,
                                             u16* __restrict__ agg16) {
  const int node = blockIdx.x * 4 + (threadIdx.x >> 6);
  const int lane = threadIdx.x & 63;
  if (node >= NND) return;
  const int s = startA[node], e = startA[node + 1];
  const size_t poff = (size_t)(lane >> 3) * 2048 + (size_t)((lane & 7) * 2);
  float a0 = 0.f, a1 = 0.f, b0 = 0.f, b1 = 0.f;
  int i = s;
  for (; i + 1 < e; i += 2) {
    const u32 v0 = *(const u32*)(ea16 + (size_t)(i >> 7) * PBLK + (size_t)(i & 127) * 16 + poff);
    const int j = i + 1;
    const u32 v1 = *(const u32*)(ea16 + (size_t)(j >> 7) * PBLK + (size_t)(j & 127) * 16 + poff);
    a0 += bf2f(v0); a1 += bf2f(v0 >> 16);
    b0 += bf2f(v1); b1 += bf2f(v1 >> 16);
  }
  if (i < e) {
    const u32 v = *(const u32*)(ea16 + (size_t)(i >> 7) * PBLK + (size_t)(i & 127) * 16 + poff);
    a0 += bf2f(v); a1 += bf2f(v >> 16);
  }
  *(u32*)(agg16 + (size_t)node * L + lane * 2) = pk2(a0 + b0, a1 + b1);
}

// ================= BN finalize (parallel: one block per column) =================
__global__ __launch_bounds__(256) void k_bnfin(const float* __restrict__ gS,
                                               const float* __restrict__ g,
                                               const float* __restrict__ be,
                                               float invM, float* __restrict__ ss) {
  const int c = blockIdx.x;          // column 0..127
  const int t = threadIdx.x;         // slot 0..255
  float s1 = gS[(size_t)t * L + c];
  float s2 = gS[(size_t)(NSLOT + t) * L + c];
  #pragma unroll
  for (int off = 1; off < 64; off <<= 1) {
    s1 += __shfl_xor(s1, off);
    s2 += __shfl_xor(s2, off);
  }
  __shared__ float w1[4], w2[4];
  if ((t & 63) == 0) { w1[t >> 6] = s1; w2[t >> 6] = s2; }
  __syncthreads();
  if (t == 0) {
    const float a = w1[0] + w1[1] + w1[2] + w1[3];
    const float q = w2[0] + w2[1] + w2[2] + w2[3];
    const float mean = a * invM;
    const float var = q * invM - mean * mean;
    const float sc = g[c] * rsqrtf(var + 1e-5f);
    ss[c] = sc;
    ss[L + c] = be[c] - mean * sc;
  }
}

// ================= edge layer 1: 2D wave tile (32 rows x 64 cols), A private, W via 2-buffer LDS =================
// chunk order {ea0, ea1, dst0, dst1, src0, src1} -> W k-windows {4,5,0,1,2,3}
__global__ __launch_bounds__(512, 4) void k_edge_l1(
    const u16* __restrict__ x16, const u16* __restrict__ ea16,
    const int* __restrict__ srcP, const int* __restrict__ dstP,
    const u16* __restrict__ Wt, const float* __restrict__ b,
    u16* __restrict__ h1, float* __restrict__ gS)
{
  __shared__ __align__(16) char Ws2[2 * 16384];
  __shared__ float red[256];
  const int tid = threadIdx.x;
  const int bid = (blockIdx.x & 7) * XCHUNK + (blockIdx.x >> 3);  // XCD-aware swizzle
  const int row0 = bid * 128;
  const int lane = tid & 63, wid = tid >> 6;
  const int wr = wid >> 1, wc = wid & 1;
  const int l15 = lane & 15, lq = lane >> 4;
  if (tid < 256) red[tid] = 0.f;

  int crw[2], dI[2], sI[2];
  #pragma unroll
  for (int m = 0; m < 2; ++m) {
    crw[m] = min(row0 + wr * 32 + m * 16 + l15, E_N - 1);
    dI[m] = dstP[crw[m]];
    sI[m] = srcP[crw[m]];
  }

  const int kcMap[6] = {4, 5, 0, 1, 2, 3};   // W k-window for chunk index ci

  // private A fragments, 3-deep rolling window: af3[ci%3][m][k2]
  bf16x8 af3[3][2][2];
  auto loadA = [&](int ci, bf16x8 (&dst)[2][2]) {
    #pragma unroll
    for (int m = 0; m < 2; ++m) {
      if (ci < 2) {           // edge_attr (HBM stream, panel layout)
        dst[m][0] = *(const bf16x8*)(ea16 + paddr(crw[m], ci * 4 + (lq >> 1), (lq & 1) * 8));
        dst[m][1] = *(const bf16x8*)(ea16 + paddr(crw[m], ci * 4 + 2 + (lq >> 1), (lq & 1) * 8));
      } else {                // x[dst] (ci=2,3) or x[src] (ci=4,5), L2-resident gathers
        const int node = (ci < 4) ? dI[m] : sI[m];
        const u16* p = x16 + (size_t)node * L + (ci & 1) * 64 + lq * 8;
        dst[m][0] = *(const bf16x8*)p;
        dst[m][1] = *(const bf16x8*)(p + 32);
      }
    }
  };
  loadA(0, af3[0]); loadA(1, af3[1]); loadA(2, af3[2]);

  // W staging: linear LDS write, pre-swizzled global source
  const int n0 = tid >> 3,         kq0 = (tid & 7) ^ (n0 & 7);
  const int n1 = (tid + 512) >> 3, kq1 = ((tid + 512) & 7) ^ (n1 & 7);
  uint4 wa, wb;
  auto wload = [&](int kw) {
    wa = *(const uint4*)(Wt + (size_t)n0 * 384 + kw * 64 + kq0 * 8);
    wb = *(const uint4*)(Wt + (size_t)n1 * 384 + kw * 64 + kq1 * 8);
  };
  auto wwrite = [&](int buf) {
    *(uint4*)(Ws2 + buf * 16384 + tid * 16) = wa;
    *(uint4*)(Ws2 + buf * 16384 + tid * 16 + 8192) = wb;
  };

  wload(kcMap[0]);
  wwrite(0);
  __syncthreads();

  f32x4 acc[2][4];
  #pragma unroll
  for (int m = 0; m < 2; ++m)
    #pragma unroll
    for (int n = 0; n < 4; ++n) acc[m][n] = (f32x4){0.f, 0.f, 0.f, 0.f};

  #pragma unroll
  for (int cc = 0; cc < 6; ++cc) {
    if (cc + 1 < 6) wload(kcMap[cc + 1]);
    const char* base = Ws2 + (cc & 1) * 16384;
    const bf16x8 (&af)[2][2] = af3[cc % 3];
    __builtin_amdgcn_s_setprio(1);
    #pragma unroll
    for (int k2 = 0; k2 < 2; ++k2)
      #pragma unroll
      for (int n = 0; n < 4; ++n) {
        const int ncol = wc * 64 + n * 16 + l15;
        const int sw = (ncol & 7) << 4;
        const bf16x8 wf = *(const bf16x8*)(base + ((ncol * 128 + k2 * 64 + lq * 16) ^ sw));
        acc[0][n] = MFMA(wf, af[0][k2], acc[0][n]);
        acc[1][n] = MFMA(wf, af[1][k2], acc[1][n]);
      }
    __builtin_amdgcn_s_setprio(0);
    if (cc + 3 < 6) loadA(cc + 3, af3[cc % 3]);   // after MFMA consumed af3[cc%3]
    if (cc + 1 < 6) wwrite((cc + 1) & 1);
    __syncthreads();
  }

  // epilogue: bias, stats (m-accumulated, one shuffle tree per n), ushort4 panel stores
  #pragma unroll
  for (int n = 0; n < 4; ++n) {
    const int colb = wc * 64 + n * 16 + lq * 4;
    const float4 bb = *(const float4*)(b + colb);
    float s1[4] = {0.f, 0.f, 0.f, 0.f}, s2[4] = {0.f, 0.f, 0.f, 0.f};
    #pragma unroll
    for (int m = 0; m < 2; ++m) {
      const int rl = wr * 32 + m * 16 + l15;
      const bool valid = row0 + rl < E_N;
      float o[4];
      o[0] = acc[m][n][0] + bb.x; o[1] = acc[m][n][1] + bb.y;
      o[2] = acc[m][n][2] + bb.z; o[3] = acc[m][n][3] + bb.w;
      if (valid) {
        #pragma unroll
        for (int r = 0; r < 4; ++r) { s1[r] += o[r]; s2[r] += o[r] * o[r]; }
        ushort4 st;
        st.x = f2bf(o[0]); st.y = f2bf(o[1]); st.z = f2bf(o[2]); st.w = f2bf(o[3]);
        *(ushort4*)(h1 + (size_t)bid * PBLK + (size_t)(wc * 4 + n) * 2048 + rl * 16 + lq * 4) = st;
      }
    }
    #pragma unroll
    for (int off = 1; off < 16; off <<= 1)
      #pragma unroll
      for (int r = 0; r < 4; ++r) {
        s1[r] += __shfl_xor(s1[r], off);
        s2[r] += __shfl_xor(s2[r], off);
      }
    if (l15 == 0) {
      #pragma unroll
      for (int r = 0; r < 4; ++r) {
        atomAddF(&red[colb + r], s1[r]);
        atomAddF(&red[128 + colb + r], s2[r]);
      }
    }
  }
  __syncthreads();
  const int slot = (bid & (NSLOT - 1)) * L;
  if (tid < 128) atomAddF(&gS[slot + tid], red[tid]);
  else if (tid < 256) atomAddF(&gS[NSLOT * L + slot + (tid - 128)], red[tid]);
}

// ================= edge layer 2: 2D wave tile, W staged once (32 KB) =================
template <bool WF32>
__global__ __launch_bounds__(512, 4) void k_edge_l2(
    const u16* __restrict__ h1, const float* __restrict__ ss,
    const u16* __restrict__ Wt, const float* __restrict__ b,
    const int* __restrict__ perm,
    float* __restrict__ ea_out, u16* __restrict__ ea16)
{
  __shared__ __align__(16) char Ws2[2 * 16384];
  const int tid = threadIdx.x;
  const int bid = (blockIdx.x & 7) * XCHUNK + (blockIdx.x >> 3);  // XCD-aware swizzle
  const int row0 = bid * 128;
  const int lane = tid & 63, wid = tid >> 6;
  const int wr = wid >> 1, wc = wid & 1;
  const int l15 = lane & 15, lq = lane >> 4;

  int crw[2];
  #pragma unroll
  for (int m = 0; m < 2; ++m)
    crw[m] = min(row0 + wr * 32 + m * 16 + l15, E_N - 1);

  // stage both W chunks (linear write, pre-swizzled source)
  const int n0 = tid >> 3,         kq0 = (tid & 7) ^ (n0 & 7);
  const int n1 = (tid + 512) >> 3, kq1 = ((tid + 512) & 7) ^ (n1 & 7);
  #pragma unroll
  for (int cc = 0; cc < 2; ++cc) {
    const uint4 wa = *(const uint4*)(Wt + (size_t)n0 * 128 + cc * 64 + kq0 * 8);
    const uint4 wb = *(const uint4*)(Wt + (size_t)n1 * 128 + cc * 64 + kq1 * 8);
    *(uint4*)(Ws2 + cc * 16384 + tid * 16) = wa;
    *(uint4*)(Ws2 + cc * 16384 + tid * 16 + 8192) = wb;
  }

  // private A (h1 panel), raw
  bf16x8 ah[2][2][2];  // [cc][m][k2]
  #pragma unroll
  for (int cc = 0; cc < 2; ++cc)
    #pragma unroll
    for (int m = 0; m < 2; ++m)
      #pragma unroll
      for (int k2 = 0; k2 < 2; ++k2)
        ah[cc][m][k2] = *(const bf16x8*)(h1 + paddr(crw[m], cc * 4 + k2 * 2 + (lq >> 1), (lq & 1) * 8));
  __syncthreads();

  f32x4 acc[2][4];
  #pragma unroll
  for (int m = 0; m < 2; ++m)
    #pragma unroll
    for (int n = 0; n < 4; ++n) acc[m][n] = (f32x4){0.f, 0.f, 0.f, 0.f};

  #pragma unroll
  for (int cc = 0; cc < 2; ++cc)
    #pragma unroll
    for (int k2 = 0; k2 < 2; ++k2) {
      const int kb = cc * 64 + k2 * 32 + lq * 8;
      const float4 sca = *(const float4*)(ss + kb), scb = *(const float4*)(ss + kb + 4);
      const float4 sha = *(const float4*)(ss + 128 + kb), shb = *(const float4*)(ss + 128 + kb + 4);
      const bf16x8 a0 = bnrelu8(ah[cc][0][k2], sca, scb, sha, shb);
      const bf16x8 a1 = bnrelu8(ah[cc][1][k2], sca, scb, sha, shb);
      const char* base = Ws2 + cc * 16384;
      __builtin_amdgcn_s_setprio(1);
      #pragma unroll
      for (int n = 0; n < 4; ++n) {
        const int ncol = wc * 64 + n * 16 + l15;
        const int sw = (ncol & 7) << 4;
        const bf16x8 wf = *(const bf16x8*)(base + ((ncol * 128 + k2 * 64 + lq * 16) ^ sw));
        acc[0][n] = MFMA(wf, a0, acc[0][n]);
        acc[1][n] = MFMA(wf, a1, acc[1][n]);
      }
      __builtin_amdgcn_s_setprio(0);
    }

  // epilogue: o = relu(acc+bias) + resid (in-place panel RMW); fp32 scatter at s=3
  #pragma unroll
  for (int m = 0; m < 2; ++m) {
    const int rl = wr * 32 + m * 16 + l15;
    const int row = row0 + rl;
    if (row < E_N) {
      const int prow = WF32 ? perm[row] : 0;
      #pragma unroll
      for (int n = 0; n < 4; ++n) {
        const int colb = wc * 64 + n * 16 + lq * 4;
        const float4 bb = *(const float4*)(b + colb);
        float o[4];
        o[0] = fmaxf(acc[m][n][0] + bb.x, 0.f);
        o[1] = fmaxf(acc[m][n][1] + bb.y, 0.f);
        o[2] = fmaxf(acc[m][n][2] + bb.z, 0.f);
        o[3] = fmaxf(acc[m][n][3] + bb.w, 0.f);
        u16* ep = ea16 + (size_t)bid * PBLK + (size_t)(wc * 4 + n) * 2048 + rl * 16 + lq * 4;
        const ushort4 rv = *(const ushort4*)ep;
        o[0] += bf2f(rv.x); o[1] += bf2f(rv.y); o[2] += bf2f(rv.z); o[3] += bf2f(rv.w);
        ushort4 st;
        st.x = f2bf(o[0]); st.y = f2bf(o[1]); st.z = f2bf(o[2]); st.w = f2bf(o[3]);
        *(ushort4*)ep = st;
        if (WF32) {
          float4 fv; fv.x = o[0]; fv.y = o[1]; fv.z = o[2]; fv.w = o[3];
          *(float4*)(ea_out + (size_t)prow * L + colb) = fv;
        }
      }
    }
  }
}

// ================= node layer 1 (x16 + agg16 bf16, row-major) =================
__global__ __launch_bounds__(256) void k_node_l1(
    const u16* __restrict__ x16, const u16* __restrict__ agg16,
    const u16* __restrict__ Wt, const float* __restrict__ b,
    u16* __restrict__ h1, float* __restrict__ gS)
{
  __shared__ __align__(16) char Bs[2][16384];
  __shared__ float red[256];
  const int tid = threadIdx.x, bid = blockIdx.x, row0 = bid * 64;
  red[tid] = 0.f;
  const int lane = tid & 63, wid = tid >> 6, wr = wid >> 1, wc = wid & 1;
  const int l15 = lane & 15, lq = lane >> 4;
  const int r0 = row0 + wr * 32 + l15, r1 = r0 + 16;
  const int rr0 = min(r0, NND - 1), rr1 = min(r1, NND - 1);

  const u16* aP[2][2];
  aP[0][0] = x16 + (size_t)rr0 * L;   aP[1][0] = x16 + (size_t)rr1 * L;
  aP[0][1] = agg16 + (size_t)rr0 * L; aP[1][1] = agg16 + (size_t)rr1 * L;

  f32x4 acc[2][4];
  #pragma unroll
  for (int m = 0; m < 2; ++m)
    #pragma unroll
    for (int n = 0; n < 4; ++n) acc[m][n] = (f32x4){0.f, 0.f, 0.f, 0.f};

  auto loadA = [&](int c, bf16x8 (&af)[2][2]) {
    const int seg = c >> 1;
    const int base = (c & 1) * 64 + lq * 8;
    #pragma unroll
    for (int k2 = 0; k2 < 2; ++k2) {
      af[0][k2] = *(const bf16x8*)(aP[0][seg] + base + k2 * 32);
      af[1][k2] = *(const bf16x8*)(aP[1][seg] + base + k2 * 32);
    }
  };
  auto stage = [&](int c, int buf) {
    #pragma unroll
    for (int i = 0; i < 4; ++i) {
      const int slot = tid + i * 256;
      const int n = slot >> 3, kq = slot & 7;
      const uint4 v = *(const uint4*)(Wt + (size_t)n * 256 + c * 64 + kq * 8);
      *(uint4*)(&Bs[buf][0] + ((n * 128 + kq * 16) ^ ((n & 7) << 4))) = v;
    }
  };

  bf16x8 aCur[2][2], aNxt[2][2];
  loadA(0, aCur);
  stage(0, 0);
  __syncthreads();
  #pragma unroll
  for (int c = 0; c < 4; ++c) {
    if (c + 1 < 4) loadA(c + 1, aNxt);
    {
      const char* base = &Bs[c & 1][0];
      #pragma unroll
      for (int k2 = 0; k2 < 2; ++k2)
        #pragma unroll
        for (int n = 0; n < 4; ++n) {
          const int ncol = wc * 64 + n * 16 + l15;
          const bf16x8 bfr = *(const bf16x8*)(base + ((ncol * 128 + k2 * 64 + lq * 16) ^ ((ncol & 7) << 4)));
          acc[0][n] = MFMA(aCur[0][k2], bfr, acc[0][n]);
          acc[1][n] = MFMA(aCur[1][k2], bfr, acc[1][n]);
        }
    }
    if (c + 1 < 4) stage(c + 1, (c + 1) & 1);
    __syncthreads();
    #pragma unroll
    for (int m = 0; m < 2; ++m)
      #pragma unroll
      for (int k2 = 0; k2 < 2; ++k2) aCur[m][k2] = aNxt[m][k2];
  }

  float bb[4], s1[4], s2[4];
  #pragma unroll
  for (int n = 0; n < 4; ++n) { bb[n] = b[wc * 64 + n * 16 + l15]; s1[n] = 0.f; s2[n] = 0.f; }
  #pragma unroll
  for (int m = 0; m < 2; ++m)
    #pragma unroll
    for (int n = 0; n < 4; ++n) {
      const int ncol = wc * 64 + n * 16 + l15;
      #pragma unroll
      for (int r = 0; r < 4; ++r) {
        const int row = row0 + wr * 32 + m * 16 + lq * 4 + r;
        if (row < NND) {
          const float o = acc[m][n][r] + bb[n];
          s1[n] += o; s2[n] += o * o;
          h1[(size_t)row * L + ncol] = f2bf(o);
        }
      }
    }
  #pragma unroll
  for (int n = 0; n < 4; ++n) {
    const int ncol = wc * 64 + n * 16 + l15;
    atomAddF(&red[ncol], s1[n]);
    atomAddF(&red[128 + ncol], s2[n]);
  }
  __syncthreads();
  const int slot = (bid & (NSLOT - 1)) * L;
  if (tid < 128) atomAddF(&gS[slot + tid], red[tid]);
  else atomAddF(&gS[NSLOT * L + slot + (tid - 128)], red[tid]);
}

// ================= node layer 2 =================
__global__ __launch_bounds__(256) void k_node_l2(
    const u16* __restrict__ h1, const float* __restrict__ ss,
    const u16* __restrict__ Wt, const float* __restrict__ b,
    const float* __restrict__ resid, float* __restrict__ x_out,
    u16* __restrict__ x16)
{
  __shared__ __align__(16) char Bs[2][16384];
  const int tid = threadIdx.x, bid = blockIdx.x, row0 = bid * 64;
  const int lane = tid & 63, wid = tid >> 6, wr = wid >> 1, wc = wid & 1;
  const int l15 = lane & 15, lq = lane >> 4;
  const int r0 = row0 + wr * 32 + l15, r1 = r0 + 16;
  const int rr0 = min(r0, NND - 1), rr1 = min(r1, NND - 1);
  const u16* a0 = h1 + (size_t)rr0 * L + lq * 8;
  const u16* a1 = h1 + (size_t)rr1 * L + lq * 8;

  f32x4 acc[2][4];
  #pragma unroll
  for (int m = 0; m < 2; ++m)
    #pragma unroll
    for (int n = 0; n < 4; ++n) acc[m][n] = (f32x4){0.f, 0.f, 0.f, 0.f};

  auto stage = [&](int c, int buf) {
    #pragma unroll
    for (int i = 0; i < 4; ++i) {
      const int slot = tid + i * 256;
      const int n = slot >> 3, kq = slot & 7;
      const uint4 v = *(const uint4*)(Wt + (size_t)n * 128 + c * 64 + kq * 8);
      *(uint4*)(&Bs[buf][0] + ((n * 128 + kq * 16) ^ ((n & 7) << 4))) = v;
    }
  };
  stage(0, 0);
  stage(1, 1);
  bf16x8 raw[2][2][2];
  #pragma unroll
  for (int c = 0; c < 2; ++c)
    #pragma unroll
    for (int k2 = 0; k2 < 2; ++k2) {
      raw[c][0][k2] = *(const bf16x8*)(a0 + c * 64 + k2 * 32);
      raw[c][1][k2] = *(const bf16x8*)(a1 + c * 64 + k2 * 32);
    }
  __syncthreads();

  #pragma unroll
  for (int c = 0; c < 2; ++c) {
    bf16x8 af[2][2];
    #pragma unroll
    for (int k2 = 0; k2 < 2; ++k2) {
      const int kg = c * 64 + k2 * 32 + lq * 8;
      const float4 sca = *(const float4*)(ss + kg), scb = *(const float4*)(ss + kg + 4);
      const float4 sha = *(const float4*)(ss + 128 + kg), shb = *(const float4*)(ss + 128 + kg + 4);
      af[0][k2] = bnrelu8(raw[c][0][k2], sca, scb, sha, shb);
      af[1][k2] = bnrelu8(raw[c][1][k2], sca, scb, sha, shb);
    }
    const char* base = &Bs[c][0];
    #pragma unroll
    for (int k2 = 0; k2 < 2; ++k2)
      #pragma unroll
      for (int n = 0; n < 4; ++n) {
        const int ncol = wc * 64 + n * 16 + l15;
        const bf16x8 bfr = *(const bf16x8*)(base + ((ncol * 128 + k2 * 64 + lq * 16) ^ ((ncol & 7) << 4)));
        acc[0][n] = MFMA(af[0][k2], bfr, acc[0][n]);
        acc[1][n] = MFMA(af[1][k2], bfr, acc[1][n]);
      }
  }

  float bb[4];
  #pragma unroll
  for (int n = 0; n < 4; ++n) bb[n] = b[wc * 64 + n * 16 + l15];
  #pragma unroll
  for (int m = 0; m < 2; ++m)
    #pragma unroll
    for (int n = 0; n < 4; ++n) {
      const int ncol = wc * 64 + n * 16 + l15;
      #pragma unroll
      for (int r = 0; r < 4; ++r) {
        const int row = row0 + wr * 32 + m * 16 + lq * 4 + r;
        if (row < NND) {
          const float o = fmaxf(acc[m][n][r] + bb[n], 0.f) + resid[(size_t)row * L + ncol];
          x_out[(size_t)row * L + ncol] = o;
          x16[(size_t)row * L + ncol] = f2bf(o);
        }
      }
    }
}

extern "C" void kernel_launch(void* const* d_in, const int* in_sizes, int n_in,
                              void* d_out, int out_size, void* d_ws, size_t ws_size,
                              hipStream_t stream) {
  (void)in_sizes; (void)n_in; (void)out_size; (void)ws_size;
  const float* in_x  = (const float*)d_in[0];
  const float* in_ea = (const float*)d_in[1];
  const int*   ei    = (const int*)d_in[2];
  const float* eW1 = (const float*)d_in[3];
  const float* eb1 = (const float*)d_in[4];
  const float* eg1 = (const float*)d_in[5];
  const float* ebe1= (const float*)d_in[6];
  const float* eW2 = (const float*)d_in[7];
  const float* eb2 = (const float*)d_in[8];
  const float* nW1 = (const float*)d_in[9];
  const float* nb1 = (const float*)d_in[10];
  const float* ng1 = (const float*)d_in[11];
  const float* nbe1= (const float*)d_in[12];
  const float* nW2 = (const float*)d_in[13];
  const float* nb2 = (const float*)d_in[14];

  float* x  = (float*)d_out;                    // [NND][L]
  float* ea = (float*)d_out + (size_t)NND * L;  // [E_N][L]

  char* w = (char*)d_ws;
  u16* h1e   = (u16*)w;   w += (size_t)EGRID * PBLK * sizeof(u16);  // panel layout
  u16* ea16  = (u16*)w;   w += (size_t)EGRID * PBLK * sizeof(u16);  // panel layout
  u16* h1n   = (u16*)w;   w += (size_t)NND * L * sizeof(u16);
  u16* x16   = (u16*)w;   w += (size_t)NND * L * sizeof(u16);
  u16* agg16 = (u16*)w;   w += (size_t)NND * L * sizeof(u16);
  float* gS  = (float*)w; w += (size_t)2 * NSLOT * L * sizeof(float);
  float* ss  = (float*)w; w += 4096;
  u16* eW1t = (u16*)w;   w += (size_t)4 * 128 * 384 * sizeof(u16);
  u16* eW2t = (u16*)w;   w += (size_t)4 * 128 * 128 * sizeof(u16);
  u16* nW1t = (u16*)w;   w += (size_t)4 * 128 * 256 * sizeof(u16);
  u16* nW2t = (u16*)w;   w += (size_t)4 * 128 * 128 * sizeof(u16);
  int* cnt    = (int*)w; w += (size_t)NND * sizeof(int);
  int* cur    = (int*)w; w += (size_t)NND * sizeof(int);
  int* startA = (int*)w; w += (size_t)(NND + 64) * sizeof(int);
  int* eids   = (int*)w; w += (size_t)E_N * sizeof(int);     // = perm
  int* srcP   = (int*)w; w += (size_t)E_N * sizeof(int);
  int* dstP   = (int*)w; w += (size_t)E_N * sizeof(int);

  const int* srcI = ei;
  const int* dstI = ei + E_N;

  k_cvt4<<<(NND * L / 4 + 255) / 256, 256, 0, stream>>>(in_x, x16, NND * L / 4);
  k_wt<<<(4 * 384 * 128 + 255) / 256, 256, 0, stream>>>(eW1, eW1t, 384);
  k_wt<<<(4 * 128 * 128 + 255) / 256, 256, 0, stream>>>(eW2, eW2t, 128);
  k_wt<<<(4 * 256 * 128 + 255) / 256, 256, 0, stream>>>(nW1, nW1t, 256);
  k_wt<<<(4 * 128 * 128 + 255) / 256, 256, 0, stream>>>(nW2, nW2t, 128);
  hipMemsetAsync(cnt, 0, (size_t)NND * sizeof(int), stream);
  hipMemsetAsync(cur, 0, (size_t)NND * sizeof(int), stream);
  k_hist<<<(E_N + 255) / 256, 256, 0, stream>>>(dstI, cnt);
  k_scan<<<1, 1024, 0, stream>>>(cnt, startA);
  k_fill<<<(E_N + 255) / 256, 256, 0, stream>>>(dstI, startA, cur, eids);
  k_perm<<<(E_N + 255) / 256, 256, 0, stream>>>(srcI, dstI, eids, srcP, dstP);
  k_cvtperm<<<(E_N * 16 + 255) / 256, 256, 0, stream>>>(in_ea, eids, ea16);

  const int ngrid = (NND + 63) / 64;     // 782

  for (int s = 0; s < 4; ++s) {
    hipMemsetAsync(gS, 0, (size_t)2 * NSLOT * L * sizeof(float), stream);
    k_edge_l1<<<EGRID, 512, 0, stream>>>(x16, ea16, srcP, dstP,
        eW1t + (size_t)s * 128 * 384, eb1 + (size_t)s * L, h1e, gS);
    k_bnfin<<<L, 256, 0, stream>>>(gS, eg1 + (size_t)s * L, ebe1 + (size_t)s * L,
        1.f / (float)E_N, ss);
    if (s < 3)
      k_edge_l2<false><<<EGRID, 512, 0, stream>>>(h1e, ss,
          eW2t + (size_t)s * 128 * 128, eb2 + (size_t)s * L, eids, ea, ea16);
    else
      k_edge_l2<true><<<EGRID, 512, 0, stream>>>(h1e, ss,
          eW2t + (size_t)s * 128 * 128, eb2 + (size_t)s * L, eids, ea, ea16);
    k_agg<<<(NND + 3) / 4, 256, 0, stream>>>(ea16, startA, agg16);
    hipMemsetAsync(gS, 0, (size_t)2 * NSLOT * L * sizeof(float), stream);
    k_node_l1<<<ngrid, 256, 0, stream>>>(x16, agg16,
        nW1t + (size_t)s * 128 * 256, nb1 + (size_t)s * L, h1n, gS);
    k_bnfin<<<L, 256, 0, stream>>>(gS, ng1 + (size_t)s * L, nbe1 + (size_t)s * L,
        1.f / (float)NND, ss);
    k_node_l2<<<ngrid, 256, 0, stream>>>(h1n, ss,
        nW2t + (size_t)s * 128 * 128, nb2 + (size_t)s * L,
        (s == 0) ? in_x : x, x, x16);
  }
}

// Round 20
// 1834.461 us; speedup vs baseline: 1.6476x; 1.0052x over previous
//
#include <hip/hip_runtime.h>
#include <hip/hip_bf16.h>
#include <cstdint>
#include <cstddef>

#define E_N 600000
#define NND 50000
#define L 128
#define EGRID 4688              // ceil(E_N/128) = 8 * 586
#define XCHUNK 586
#define PBLK 16384              // u16 per 128-row panel-block (8*128*16)
#define NSLOT 256

typedef unsigned short u16;
typedef unsigned int u32;
typedef __attribute__((ext_vector_type(8))) short bf16x8;
typedef __attribute__((ext_vector_type(4))) float f32x4;

static __device__ __forceinline__ u16 f2bf(float f) {
  union { float f; u32 u; } c; c.f = f;
  return (u16)((c.u + 0x7fffu + ((c.u >> 16) & 1u)) >> 16);
}
static __device__ __forceinline__ u32 pk2(float a, float b) {
  return (u32)f2bf(a) | ((u32)f2bf(b) << 16);
}
static __device__ __forceinline__ float bf2f(u32 h) {
  union { u32 u; float f; } c; c.u = (h & 0xffffu) << 16; return c.f;
}
static __device__ __forceinline__ void atomAddF(float* p, float v) {
#if defined(__HIP_DEVICE_COMPILE__)
  unsafeAtomicAdd(p, v);
#else
  atomicAdd(p, v);
#endif
}
static __device__ __forceinline__ bf16x8 bnrelu8(bf16x8 raw, float4 sca, float4 scb,
                                                 float4 sha, float4 shb) {
  union { bf16x8 v; u16 h[8]; } in; in.v = raw;
  const float sc[8] = {sca.x, sca.y, sca.z, sca.w, scb.x, scb.y, scb.z, scb.w};
  const float sh[8] = {sha.x, sha.y, sha.z, sha.w, shb.x, shb.y, shb.z, shb.w};
  float f[8];
  #pragma unroll
  for (int i = 0; i < 8; ++i) f[i] = fmaxf(bf2f(in.h[i]) * sc[i] + sh[i], 0.f);
  union { bf16x8 v; u32 w[4]; } r;
  #pragma unroll
  for (int i = 0; i < 4; ++i) r.w[i] = pk2(f[2 * i], f[2 * i + 1]);
  return r.v;
}

#define MFMA(a, bfr, c) __builtin_amdgcn_mfma_f32_16x16x32_bf16((a), (bfr), (c), 0, 0, 0)

// panel-layout address (u16 units): row-block, panel p (=col/16), local row, col%16
static __device__ __forceinline__ size_t paddr(int row, int panel, int incol) {
  return (size_t)(row >> 7) * PBLK + (size_t)panel * 2048 + (size_t)(row & 127) * 16 + incol;
}

// ================= prepass kernels =================
__global__ __launch_bounds__(256) void k_cvt4(const float* __restrict__ in,
                                              u16* __restrict__ out, int n4) {
  const int i = blockIdx.x * 256 + threadIdx.x;
  if (i < n4) {
    const float4 v = *(const float4*)(in + (size_t)i * 4);
    uint2 o; o.x = pk2(v.x, v.y); o.y = pk2(v.z, v.w);
    *(uint2*)(out + (size_t)i * 4) = o;
  }
}

// in_ea (fp32, original order) -> ea16 (bf16, permuted panel layout)
__global__ __launch_bounds__(256) void k_cvtperm(const float* __restrict__ in_ea,
                                                 const int* __restrict__ perm,
                                                 u16* __restrict__ ea16) {
  const int i = blockIdx.x * 256 + threadIdx.x;
  const int row = i >> 4, part = i & 15;      // 16 threads/row, 8 cols each
  if (row < E_N) {
    const float* p = in_ea + (size_t)perm[row] * L + part * 8;
    const float4 f0 = *(const float4*)p, f1 = *(const float4*)(p + 4);
    union { bf16x8 v; u32 w[4]; } r;
    r.w[0] = pk2(f0.x, f0.y); r.w[1] = pk2(f0.z, f0.w);
    r.w[2] = pk2(f1.x, f1.y); r.w[3] = pk2(f1.z, f1.w);
    *(bf16x8*)(ea16 + paddr(row, part >> 1, (part & 1) * 8)) = r.v;
  }
}

__global__ void k_wt(const float* __restrict__ W, u16* __restrict__ Wt, int K) {
  const int idx = blockIdx.x * 256 + threadIdx.x;
  const int total = 4 * K * 128;
  if (idx >= total) return;
  const int s = idx / (K * 128);
  const int rem = idx - s * K * 128;
  const int n = rem / K;
  const int k = rem - n * K;
  Wt[idx] = f2bf(W[(size_t)s * K * 128 + (size_t)k * 128 + n]);
}

__global__ void k_hist(const int* __restrict__ dstI, int* __restrict__ cnt) {
  const int i = blockIdx.x * 256 + threadIdx.x;
  if (i < E_N) atomicAdd(&cnt[dstI[i]], 1);
}

__global__ __launch_bounds__(1024) void k_scan(const int* __restrict__ cnt, int* __restrict__ startA) {
  __shared__ int buf[1024];
  __shared__ int carry;
  const int tid = threadIdx.x;
  if (tid == 0) carry = 0;
  __syncthreads();
  for (int base = 0; base < NND; base += 1024) {
    int v = (base + tid < NND) ? cnt[base + tid] : 0;
    buf[tid] = v;
    __syncthreads();
    for (int off = 1; off < 1024; off <<= 1) {
      int t = (tid >= off) ? buf[tid - off] : 0;
      __syncthreads();
      buf[tid] += t;
      __syncthreads();
    }
    const int incl = buf[tid];
    const int c = carry;
    if (base + tid < NND) startA[base + tid] = c + incl - v;
    __syncthreads();
    if (tid == 1023) carry = c + incl;
    __syncthreads();
  }
  if (tid == 0) startA[NND] = carry;
}

__global__ void k_fill(const int* __restrict__ dstI, const int* __restrict__ startA,
                       int* __restrict__ cur, int* __restrict__ eids) {
  const int i = blockIdx.x * 256 + threadIdx.x;
  if (i < E_N) {
    const int d = dstI[i];
    const int pos = atomicAdd(&cur[d], 1);
    eids[startA[d] + pos] = i;
  }
}

__global__ void k_perm(const int* __restrict__ srcI, const int* __restrict__ dstI,
                       const int* __restrict__ perm,
                       int* __restrict__ srcP, int* __restrict__ dstP) {
  const int i = blockIdx.x * 256 + threadIdx.x;
  if (i < E_N) {
    const int e = perm[i];
    srcP[i] = srcI[e];
    dstP[i] = dstI[e];
  }
}

// ================= aggregation (panel ea16 -> row-major agg16) =================
__global__ __launch_bounds__(256) void k_agg(const u16* __restrict__ ea16,
                                             const int* __restrict__ startA,
                                             u16* __restrict__ agg16) {
  const int node = blockIdx.x * 4 + (threadIdx.x >> 6);
  const int lane = threadIdx.x & 63;
  if (node >= NND) return;
  const int s = startA[node], e = startA[node + 1];
  const size_t poff = (size_t)(lane >> 3) * 2048 + (size_t)((lane & 7) * 2);
  float a0 = 0.f, a1 = 0.f, b0 = 0.f, b1 = 0.f;
  int i = s;
  for (; i + 1 < e; i += 2) {
    const u32 v0 = *(const u32*)(ea16 + (size_t)(i >> 7) * PBLK + (size_t)(i & 127) * 16 + poff);
    const int j = i + 1;
    const u32 v1 = *(const u32*)(ea16 + (size_t)(j >> 7) * PBLK + (size_t)(j & 127) * 16 + poff);
    a0 += bf2f(v0); a1 += bf2f(v0 >> 16);
    b0 += bf2f(v1); b1 += bf2f(v1 >> 16);
  }
  if (i < e) {
    const u32 v = *(const u32*)(ea16 + (size_t)(i >> 7) * PBLK + (size_t)(i & 127) * 16 + poff);
    a0 += bf2f(v); a1 += bf2f(v >> 16);
  }
  *(u32*)(agg16 + (size_t)node * L + lane * 2) = pk2(a0 + b0, a1 + b1);
}

// ================= BN finalize (parallel; zeroes gS in place for next pass) =================
__global__ __launch_bounds__(256) void k_bnfin(float* __restrict__ gS,
                                               const float* __restrict__ g,
                                               const float* __restrict__ be,
                                               float invM, float* __restrict__ ss) {
  const int c = blockIdx.x;          // column 0..127
  const int t = threadIdx.x;         // slot 0..255
  float s1 = gS[(size_t)t * L + c];
  float s2 = gS[(size_t)(NSLOT + t) * L + c];
  gS[(size_t)t * L + c] = 0.f;              // re-zero for next accumulation pass
  gS[(size_t)(NSLOT + t) * L + c] = 0.f;
  #pragma unroll
  for (int off = 1; off < 64; off <<= 1) {
    s1 += __shfl_xor(s1, off);
    s2 += __shfl_xor(s2, off);
  }
  __shared__ float w1[4], w2[4];
  if ((t & 63) == 0) { w1[t >> 6] = s1; w2[t >> 6] = s2; }
  __syncthreads();
  if (t == 0) {
    const float a = w1[0] + w1[1] + w1[2] + w1[3];
    const float q = w2[0] + w2[1] + w2[2] + w2[3];
    const float mean = a * invM;
    const float var = q * invM - mean * mean;
    const float sc = g[c] * rsqrtf(var + 1e-5f);
    ss[c] = sc;
    ss[L + c] = be[c] - mean * sc;
  }
}

// ================= edge layer 1: 2D wave tile (32 rows x 64 cols), A private, W via 2-buffer LDS =================
// chunk order {ea0, ea1, dst0, dst1, src0, src1} -> W k-windows {4,5,0,1,2,3}
__global__ __launch_bounds__(512, 4) void k_edge_l1(
    const u16* __restrict__ x16, const u16* __restrict__ ea16,
    const int* __restrict__ srcP, const int* __restrict__ dstP,
    const u16* __restrict__ Wt, const float* __restrict__ b,
    u16* __restrict__ h1, float* __restrict__ gS)
{
  __shared__ __align__(16) char Ws2[2 * 16384];
  __shared__ float red[256];
  const int tid = threadIdx.x;
  const int bid = (blockIdx.x & 7) * XCHUNK + (blockIdx.x >> 3);  // XCD-aware swizzle
  const int row0 = bid * 128;
  const int lane = tid & 63, wid = tid >> 6;
  const int wr = wid >> 1, wc = wid & 1;
  const int l15 = lane & 15, lq = lane >> 4;
  if (tid < 256) red[tid] = 0.f;

  int crw[2], dI[2], sI[2];
  #pragma unroll
  for (int m = 0; m < 2; ++m) {
    crw[m] = min(row0 + wr * 32 + m * 16 + l15, E_N - 1);
    dI[m] = dstP[crw[m]];
    sI[m] = srcP[crw[m]];
  }

  const int kcMap[6] = {4, 5, 0, 1, 2, 3};   // W k-window for chunk index ci

  // private A fragments, 3-deep rolling window: af3[ci%3][m][k2]
  bf16x8 af3[3][2][2];
  auto loadA = [&](int ci, bf16x8 (&dst)[2][2]) {
    #pragma unroll
    for (int m = 0; m < 2; ++m) {
      if (ci < 2) {           // edge_attr (HBM stream, panel layout)
        dst[m][0] = *(const bf16x8*)(ea16 + paddr(crw[m], ci * 4 + (lq >> 1), (lq & 1) * 8));
        dst[m][1] = *(const bf16x8*)(ea16 + paddr(crw[m], ci * 4 + 2 + (lq >> 1), (lq & 1) * 8));
      } else {                // x[dst] (ci=2,3) or x[src] (ci=4,5), L2-resident gathers
        const int node = (ci < 4) ? dI[m] : sI[m];
        const u16* p = x16 + (size_t)node * L + (ci & 1) * 64 + lq * 8;
        dst[m][0] = *(const bf16x8*)p;
        dst[m][1] = *(const bf16x8*)(p + 32);
      }
    }
  };
  loadA(0, af3[0]); loadA(1, af3[1]); loadA(2, af3[2]);

  // W staging: linear LDS write, pre-swizzled global source
  const int n0 = tid >> 3,         kq0 = (tid & 7) ^ (n0 & 7);
  const int n1 = (tid + 512) >> 3, kq1 = ((tid + 512) & 7) ^ (n1 & 7);
  uint4 wa, wb;
  auto wload = [&](int kw) {
    wa = *(const uint4*)(Wt + (size_t)n0 * 384 + kw * 64 + kq0 * 8);
    wb = *(const uint4*)(Wt + (size_t)n1 * 384 + kw * 64 + kq1 * 8);
  };
  auto wwrite = [&](int buf) {
    *(uint4*)(Ws2 + buf * 16384 + tid * 16) = wa;
    *(uint4*)(Ws2 + buf * 16384 + tid * 16 + 8192) = wb;
  };

  wload(kcMap[0]);
  wwrite(0);
  __syncthreads();

  f32x4 acc[2][4];
  #pragma unroll
  for (int m = 0; m < 2; ++m)
    #pragma unroll
    for (int n = 0; n < 4; ++n) acc[m][n] = (f32x4){0.f, 0.f, 0.f, 0.f};

  #pragma unroll
  for (int cc = 0; cc < 6; ++cc) {
    if (cc + 1 < 6) wload(kcMap[cc + 1]);
    const char* base = Ws2 + (cc & 1) * 16384;
    const bf16x8 (&af)[2][2] = af3[cc % 3];
    __builtin_amdgcn_s_setprio(1);
    #pragma unroll
    for (int k2 = 0; k2 < 2; ++k2)
      #pragma unroll
      for (int n = 0; n < 4; ++n) {
        const int ncol = wc * 64 + n * 16 + l15;
        const int sw = (ncol & 7) << 4;
        const bf16x8 wf = *(const bf16x8*)(base + ((ncol * 128 + k2 * 64 + lq * 16) ^ sw));
        acc[0][n] = MFMA(wf, af[0][k2], acc[0][n]);
        acc[1][n] = MFMA(wf, af[1][k2], acc[1][n]);
      }
    __builtin_amdgcn_s_setprio(0);
    if (cc + 3 < 6) loadA(cc + 3, af3[cc % 3]);   // after MFMA consumed af3[cc%3]
    if (cc + 1 < 6) wwrite((cc + 1) & 1);
    __syncthreads();
  }

  // epilogue: bias, stats (m-accumulated, one shuffle tree per n), ushort4 panel stores
  #pragma unroll
  for (int n = 0; n < 4; ++n) {
    const int colb = wc * 64 + n * 16 + lq * 4;
    const float4 bb = *(const float4*)(b + colb);
    float s1[4] = {0.f, 0.f, 0.f, 0.f}, s2[4] = {0.f, 0.f, 0.f, 0.f};
    #pragma unroll
    for (int m = 0; m < 2; ++m) {
      const int rl = wr * 32 + m * 16 + l15;
      const bool valid = row0 + rl < E_N;
      float o[4];
      o[0] = acc[m][n][0] + bb.x; o[1] = acc[m][n][1] + bb.y;
      o[2] = acc[m][n][2] + bb.z; o[3] = acc[m][n][3] + bb.w;
      if (valid) {
        #pragma unroll
        for (int r = 0; r < 4; ++r) { s1[r] += o[r]; s2[r] += o[r] * o[r]; }
        ushort4 st;
        st.x = f2bf(o[0]); st.y = f2bf(o[1]); st.z = f2bf(o[2]); st.w = f2bf(o[3]);
        *(ushort4*)(h1 + (size_t)bid * PBLK + (size_t)(wc * 4 + n) * 2048 + rl * 16 + lq * 4) = st;
      }
    }
    #pragma unroll
    for (int off = 1; off < 16; off <<= 1)
      #pragma unroll
      for (int r = 0; r < 4; ++r) {
        s1[r] += __shfl_xor(s1[r], off);
        s2[r] += __shfl_xor(s2[r], off);
      }
    if (l15 == 0) {
      #pragma unroll
      for (int r = 0; r < 4; ++r) {
        atomAddF(&red[colb + r], s1[r]);
        atomAddF(&red[128 + colb + r], s2[r]);
      }
    }
  }
  __syncthreads();
  const int slot = (bid & (NSLOT - 1)) * L;
  if (tid < 128) atomAddF(&gS[slot + tid], red[tid]);
  else if (tid < 256) atomAddF(&gS[NSLOT * L + slot + (tid - 128)], red[tid]);
}

// ================= edge layer 2: 2D wave tile, W staged once (32 KB) =================
template <bool WF32>
__global__ __launch_bounds__(512, 4) void k_edge_l2(
    const u16* __restrict__ h1, const float* __restrict__ ss,
    const u16* __restrict__ Wt, const float* __restrict__ b,
    const int* __restrict__ perm,
    float* __restrict__ ea_out, u16* __restrict__ ea16)
{
  __shared__ __align__(16) char Ws2[2 * 16384];
  const int tid = threadIdx.x;
  const int bid = (blockIdx.x & 7) * XCHUNK + (blockIdx.x >> 3);  // XCD-aware swizzle
  const int row0 = bid * 128;
  const int lane = tid & 63, wid = tid >> 6;
  const int wr = wid >> 1, wc = wid & 1;
  const int l15 = lane & 15, lq = lane >> 4;

  int crw[2];
  #pragma unroll
  for (int m = 0; m < 2; ++m)
    crw[m] = min(row0 + wr * 32 + m * 16 + l15, E_N - 1);

  // stage both W chunks (linear write, pre-swizzled source)
  const int n0 = tid >> 3,         kq0 = (tid & 7) ^ (n0 & 7);
  const int n1 = (tid + 512) >> 3, kq1 = ((tid + 512) & 7) ^ (n1 & 7);
  #pragma unroll
  for (int cc = 0; cc < 2; ++cc) {
    const uint4 wa = *(const uint4*)(Wt + (size_t)n0 * 128 + cc * 64 + kq0 * 8);
    const uint4 wb = *(const uint4*)(Wt + (size_t)n1 * 128 + cc * 64 + kq1 * 8);
    *(uint4*)(Ws2 + cc * 16384 + tid * 16) = wa;
    *(uint4*)(Ws2 + cc * 16384 + tid * 16 + 8192) = wb;
  }

  // private A (h1 panel), raw
  bf16x8 ah[2][2][2];  // [cc][m][k2]
  #pragma unroll
  for (int cc = 0; cc < 2; ++cc)
    #pragma unroll
    for (int m = 0; m < 2; ++m)
      #pragma unroll
      for (int k2 = 0; k2 < 2; ++k2)
        ah[cc][m][k2] = *(const bf16x8*)(h1 + paddr(crw[m], cc * 4 + k2 * 2 + (lq >> 1), (lq & 1) * 8));
  __syncthreads();

  f32x4 acc[2][4];
  #pragma unroll
  for (int m = 0; m < 2; ++m)
    #pragma unroll
    for (int n = 0; n < 4; ++n) acc[m][n] = (f32x4){0.f, 0.f, 0.f, 0.f};

  #pragma unroll
  for (int cc = 0; cc < 2; ++cc)
    #pragma unroll
    for (int k2 = 0; k2 < 2; ++k2) {
      const int kb = cc * 64 + k2 * 32 + lq * 8;
      const float4 sca = *(const float4*)(ss + kb), scb = *(const float4*)(ss + kb + 4);
      const float4 sha = *(const float4*)(ss + 128 + kb), shb = *(const float4*)(ss + 128 + kb + 4);
      const bf16x8 a0 = bnrelu8(ah[cc][0][k2], sca, scb, sha, shb);
      const bf16x8 a1 = bnrelu8(ah[cc][1][k2], sca, scb, sha, shb);
      const char* base = Ws2 + cc * 16384;
      __builtin_amdgcn_s_setprio(1);
      #pragma unroll
      for (int n = 0; n < 4; ++n) {
        const int ncol = wc * 64 + n * 16 + l15;
        const int sw = (ncol & 7) << 4;
        const bf16x8 wf = *(const bf16x8*)(base + ((ncol * 128 + k2 * 64 + lq * 16) ^ sw));
        acc[0][n] = MFMA(wf, a0, acc[0][n]);
        acc[1][n] = MFMA(wf, a1, acc[1][n]);
      }
      __builtin_amdgcn_s_setprio(0);
    }

  // epilogue: o = relu(acc+bias) + resid (in-place panel RMW); fp32 scatter at s=3
  #pragma unroll
  for (int m = 0; m < 2; ++m) {
    const int rl = wr * 32 + m * 16 + l15;
    const int row = row0 + rl;
    if (row < E_N) {
      const int prow = WF32 ? perm[row] : 0;
      #pragma unroll
      for (int n = 0; n < 4; ++n) {
        const int colb = wc * 64 + n * 16 + lq * 4;
        const float4 bb = *(const float4*)(b + colb);
        float o[4];
        o[0] = fmaxf(acc[m][n][0] + bb.x, 0.f);
        o[1] = fmaxf(acc[m][n][1] + bb.y, 0.f);
        o[2] = fmaxf(acc[m][n][2] + bb.z, 0.f);
        o[3] = fmaxf(acc[m][n][3] + bb.w, 0.f);
        u16* ep = ea16 + (size_t)bid * PBLK + (size_t)(wc * 4 + n) * 2048 + rl * 16 + lq * 4;
        const ushort4 rv = *(const ushort4*)ep;
        o[0] += bf2f(rv.x); o[1] += bf2f(rv.y); o[2] += bf2f(rv.z); o[3] += bf2f(rv.w);
        ushort4 st;
        st.x = f2bf(o[0]); st.y = f2bf(o[1]); st.z = f2bf(o[2]); st.w = f2bf(o[3]);
        *(ushort4*)ep = st;
        if (WF32) {
          float4 fv; fv.x = o[0]; fv.y = o[1]; fv.z = o[2]; fv.w = o[3];
          *(float4*)(ea_out + (size_t)prow * L + colb) = fv;
        }
      }
    }
  }
}

// ================= node layer 1 (x16 + agg16 bf16, row-major) =================
__global__ __launch_bounds__(256) void k_node_l1(
    const u16* __restrict__ x16, const u16* __restrict__ agg16,
    const u16* __restrict__ Wt, const float* __restrict__ b,
    u16* __restrict__ h1, float* __restrict__ gS)
{
  __shared__ __align__(16) char Bs[2][16384];
  __shared__ float red[256];
  const int tid = threadIdx.x, bid = blockIdx.x, row0 = bid * 64;
  red[tid] = 0.f;
  const int lane = tid & 63, wid = tid >> 6, wr = wid >> 1, wc = wid & 1;
  const int l15 = lane & 15, lq = lane >> 4;
  const int r0 = row0 + wr * 32 + l15, r1 = r0 + 16;
  const int rr0 = min(r0, NND - 1), rr1 = min(r1, NND - 1);

  const u16* aP[2][2];
  aP[0][0] = x16 + (size_t)rr0 * L;   aP[1][0] = x16 + (size_t)rr1 * L;
  aP[0][1] = agg16 + (size_t)rr0 * L; aP[1][1] = agg16 + (size_t)rr1 * L;

  f32x4 acc[2][4];
  #pragma unroll
  for (int m = 0; m < 2; ++m)
    #pragma unroll
    for (int n = 0; n < 4; ++n) acc[m][n] = (f32x4){0.f, 0.f, 0.f, 0.f};

  auto loadA = [&](int c, bf16x8 (&af)[2][2]) {
    const int seg = c >> 1;
    const int base = (c & 1) * 64 + lq * 8;
    #pragma unroll
    for (int k2 = 0; k2 < 2; ++k2) {
      af[0][k2] = *(const bf16x8*)(aP[0][seg] + base + k2 * 32);
      af[1][k2] = *(const bf16x8*)(aP[1][seg] + base + k2 * 32);
    }
  };
  auto stage = [&](int c, int buf) {
    #pragma unroll
    for (int i = 0; i < 4; ++i) {
      const int slot = tid + i * 256;
      const int n = slot >> 3, kq = slot & 7;
      const uint4 v = *(const uint4*)(Wt + (size_t)n * 256 + c * 64 + kq * 8);
      *(uint4*)(&Bs[buf][0] + ((n * 128 + kq * 16) ^ ((n & 7) << 4))) = v;
    }
  };

  bf16x8 aCur[2][2], aNxt[2][2];
  loadA(0, aCur);
  stage(0, 0);
  __syncthreads();
  #pragma unroll
  for (int c = 0; c < 4; ++c) {
    if (c + 1 < 4) loadA(c + 1, aNxt);
    {
      const char* base = &Bs[c & 1][0];
      #pragma unroll
      for (int k2 = 0; k2 < 2; ++k2)
        #pragma unroll
        for (int n = 0; n < 4; ++n) {
          const int ncol = wc * 64 + n * 16 + l15;
          const bf16x8 bfr = *(const bf16x8*)(base + ((ncol * 128 + k2 * 64 + lq * 16) ^ ((ncol & 7) << 4)));
          acc[0][n] = MFMA(aCur[0][k2], bfr, acc[0][n]);
          acc[1][n] = MFMA(aCur[1][k2], bfr, acc[1][n]);
        }
    }
    if (c + 1 < 4) stage(c + 1, (c + 1) & 1);
    __syncthreads();
    #pragma unroll
    for (int m = 0; m < 2; ++m)
      #pragma unroll
      for (int k2 = 0; k2 < 2; ++k2) aCur[m][k2] = aNxt[m][k2];
  }

  float bb[4], s1[4], s2[4];
  #pragma unroll
  for (int n = 0; n < 4; ++n) { bb[n] = b[wc * 64 + n * 16 + l15]; s1[n] = 0.f; s2[n] = 0.f; }
  #pragma unroll
  for (int m = 0; m < 2; ++m)
    #pragma unroll
    for (int n = 0; n < 4; ++n) {
      const int ncol = wc * 64 + n * 16 + l15;
      #pragma unroll
      for (int r = 0; r < 4; ++r) {
        const int row = row0 + wr * 32 + m * 16 + lq * 4 + r;
        if (row < NND) {
          const float o = acc[m][n][r] + bb[n];
          s1[n] += o; s2[n] += o * o;
          h1[(size_t)row * L + ncol] = f2bf(o);
        }
      }
    }
  #pragma unroll
  for (int n = 0; n < 4; ++n) {
    const int ncol = wc * 64 + n * 16 + l15;
    atomAddF(&red[ncol], s1[n]);
    atomAddF(&red[128 + ncol], s2[n]);
  }
  __syncthreads();
  const int slot = (bid & (NSLOT - 1)) * L;
  if (tid < 128) atomAddF(&gS[slot + tid], red[tid]);
  else atomAddF(&gS[NSLOT * L + slot + (tid - 128)], red[tid]);
}

// ================= node layer 2 =================
__global__ __launch_bounds__(256) void k_node_l2(
    const u16* __restrict__ h1, const float* __restrict__ ss,
    const u16* __restrict__ Wt, const float* __restrict__ b,
    const float* __restrict__ resid, float* __restrict__ x_out,
    u16* __restrict__ x16)
{
  __shared__ __align__(16) char Bs[2][16384];
  const int tid = threadIdx.x, bid = blockIdx.x, row0 = bid * 64;
  const int lane = tid & 63, wid = tid >> 6, wr = wid >> 1, wc = wid & 1;
  const int l15 = lane & 15, lq = lane >> 4;
  const int r0 = row0 + wr * 32 + l15, r1 = r0 + 16;
  const int rr0 = min(r0, NND - 1), rr1 = min(r1, NND - 1);
  const u16* a0 = h1 + (size_t)rr0 * L + lq * 8;
  const u16* a1 = h1 + (size_t)rr1 * L + lq * 8;

  f32x4 acc[2][4];
  #pragma unroll
  for (int m = 0; m < 2; ++m)
    #pragma unroll
    for (int n = 0; n < 4; ++n) acc[m][n] = (f32x4){0.f, 0.f, 0.f, 0.f};

  auto stage = [&](int c, int buf) {
    #pragma unroll
    for (int i = 0; i < 4; ++i) {
      const int slot = tid + i * 256;
      const int n = slot >> 3, kq = slot & 7;
      const uint4 v = *(const uint4*)(Wt + (size_t)n * 128 + c * 64 + kq * 8);
      *(uint4*)(&Bs[buf][0] + ((n * 128 + kq * 16) ^ ((n & 7) << 4))) = v;
    }
  };
  stage(0, 0);
  stage(1, 1);
  bf16x8 raw[2][2][2];
  #pragma unroll
  for (int c = 0; c < 2; ++c)
    #pragma unroll
    for (int k2 = 0; k2 < 2; ++k2) {
      raw[c][0][k2] = *(const bf16x8*)(a0 + c * 64 + k2 * 32);
      raw[c][1][k2] = *(const bf16x8*)(a1 + c * 64 + k2 * 32);
    }
  __syncthreads();

  #pragma unroll
  for (int c = 0; c < 2; ++c) {
    bf16x8 af[2][2];
    #pragma unroll
    for (int k2 = 0; k2 < 2; ++k2) {
      const int kg = c * 64 + k2 * 32 + lq * 8;
      const float4 sca = *(const float4*)(ss + kg), scb = *(const float4*)(ss + kg + 4);
      const float4 sha = *(const float4*)(ss + 128 + kg), shb = *(const float4*)(ss + 128 + kg + 4);
      af[0][k2] = bnrelu8(raw[c][0][k2], sca, scb, sha, shb);
      af[1][k2] = bnrelu8(raw[c][1][k2], sca, scb, sha, shb);
    }
    const char* base = &Bs[c][0];
    #pragma unroll
    for (int k2 = 0; k2 < 2; ++k2)
      #pragma unroll
      for (int n = 0; n < 4; ++n) {
        const int ncol = wc * 64 + n * 16 + l15;
        const bf16x8 bfr = *(const bf16x8*)(base + ((ncol * 128 + k2 * 64 + lq * 16) ^ ((ncol & 7) << 4)));
        acc[0][n] = MFMA(af[0][k2], bfr, acc[0][n]);
        acc[1][n] = MFMA(af[1][k2], bfr, acc[1][n]);
      }
  }

  float bb[4];
  #pragma unroll
  for (int n = 0; n < 4; ++n) bb[n] = b[wc * 64 + n * 16 + l15];
  #pragma unroll
  for (int m = 0; m < 2; ++m)
    #pragma unroll
    for (int n = 0; n < 4; ++n) {
      const int ncol = wc * 64 + n * 16 + l15;
      #pragma unroll
      for (int r = 0; r < 4; ++r) {
        const int row = row0 + wr * 32 + m * 16 + lq * 4 + r;
        if (row < NND) {
          const float o = fmaxf(acc[m][n][r] + bb[n], 0.f) + resid[(size_t)row * L + ncol];
          x_out[(size_t)row * L + ncol] = o;
          x16[(size_t)row * L + ncol] = f2bf(o);
        }
      }
    }
}

extern "C" void kernel_launch(void* const* d_in, const int* in_sizes, int n_in,
                              void* d_out, int out_size, void* d_ws, size_t ws_size,
                              hipStream_t stream) {
  (void)in_sizes; (void)n_in; (void)out_size; (void)ws_size;
  const float* in_x  = (const float*)d_in[0];
  const float* in_ea = (const float*)d_in[1];
  const int*   ei    = (const int*)d_in[2];
  const float* eW1 = (const float*)d_in[3];
  const float* eb1 = (const float*)d_in[4];
  const float* eg1 = (const float*)d_in[5];
  const float* ebe1= (const float*)d_in[6];
  const float* eW2 = (const float*)d_in[7];
  const float* eb2 = (const float*)d_in[8];
  const float* nW1 = (const float*)d_in[9];
  const float* nb1 = (const float*)d_in[10];
  const float* ng1 = (const float*)d_in[11];
  const float* nbe1= (const float*)d_in[12];
  const float* nW2 = (const float*)d_in[13];
  const float* nb2 = (const float*)d_in[14];

  float* x  = (float*)d_out;                    // [NND][L]
  float* ea = (float*)d_out + (size_t)NND * L;  // [E_N][L]

  char* w = (char*)d_ws;
  u16* h1e   = (u16*)w;   w += (size_t)EGRID * PBLK * sizeof(u16);  // panel layout
  u16* ea16  = (u16*)w;   w += (size_t)EGRID * PBLK * sizeof(u16);  // panel layout
  u16* h1n   = (u16*)w;   w += (size_t)NND * L * sizeof(u16);
  u16* x16   = (u16*)w;   w += (size_t)NND * L * sizeof(u16);
  u16* agg16 = (u16*)w;   w += (size_t)NND * L * sizeof(u16);
  float* gS  = (float*)w; w += (size_t)2 * NSLOT * L * sizeof(float);
  float* ss  = (float*)w; w += 4096;
  u16* eW1t = (u16*)w;   w += (size_t)4 * 128 * 384 * sizeof(u16);
  u16* eW2t = (u16*)w;   w += (size_t)4 * 128 * 128 * sizeof(u16);
  u16* nW1t = (u16*)w;   w += (size_t)4 * 128 * 256 * sizeof(u16);
  u16* nW2t = (u16*)w;   w += (size_t)4 * 128 * 128 * sizeof(u16);
  int* cnt    = (int*)w; w += (size_t)NND * sizeof(int);
  int* cur    = (int*)w; w += (size_t)NND * sizeof(int);
  int* startA = (int*)w; w += (size_t)(NND + 64) * sizeof(int);
  int* eids   = (int*)w; w += (size_t)E_N * sizeof(int);     // = perm
  int* srcP   = (int*)w; w += (size_t)E_N * sizeof(int);
  int* dstP   = (int*)w; w += (size_t)E_N * sizeof(int);

  const int* srcI = ei;
  const int* dstI = ei + E_N;

  k_cvt4<<<(NND * L / 4 + 255) / 256, 256, 0, stream>>>(in_x, x16, NND * L / 4);
  k_wt<<<(4 * 384 * 128 + 255) / 256, 256, 0, stream>>>(eW1, eW1t, 384);
  k_wt<<<(4 * 128 * 128 + 255) / 256, 256, 0, stream>>>(eW2, eW2t, 128);
  k_wt<<<(4 * 256 * 128 + 255) / 256, 256, 0, stream>>>(nW1, nW1t, 256);
  k_wt<<<(4 * 128 * 128 + 255) / 256, 256, 0, stream>>>(nW2, nW2t, 128);
  hipMemsetAsync(cnt, 0, (size_t)NND * sizeof(int), stream);
  hipMemsetAsync(cur, 0, (size_t)NND * sizeof(int), stream);
  hipMemsetAsync(gS, 0, (size_t)2 * NSLOT * L * sizeof(float), stream);  // seed once; bnfin re-zeroes
  k_hist<<<(E_N + 255) / 256, 256, 0, stream>>>(dstI, cnt);
  k_scan<<<1, 1024, 0, stream>>>(cnt, startA);
  k_fill<<<(E_N + 255) / 256, 256, 0, stream>>>(dstI, startA, cur, eids);
  k_perm<<<(E_N + 255) / 256, 256, 0, stream>>>(srcI, dstI, eids, srcP, dstP);
  k_cvtperm<<<(E_N * 16 + 255) / 256, 256, 0, stream>>>(in_ea, eids, ea16);

  const int ngrid = (NND + 63) / 64;     // 782

  for (int s = 0; s < 4; ++s) {
    k_edge_l1<<<EGRID, 512, 0, stream>>>(x16, ea16, srcP, dstP,
        eW1t + (size_t)s * 128 * 384, eb1 + (size_t)s * L, h1e, gS);
    k_bnfin<<<L, 256, 0, stream>>>(gS, eg1 + (size_t)s * L, ebe1 + (size_t)s * L,
        1.f / (float)E_N, ss);
    if (s < 3)
      k_edge_l2<false><<<EGRID, 512, 0, stream>>>(h1e, ss,
          eW2t + (size_t)s * 128 * 128, eb2 + (size_t)s * L, eids, ea, ea16);
    else
      k_edge_l2<true><<<EGRID, 512, 0, stream>>>(h1e, ss,
          eW2t + (size_t)s * 128 * 128, eb2 + (size_t)s * L, eids, ea, ea16);
    k_agg<<<(NND + 3) / 4, 256, 0, stream>>>(ea16, startA, agg16);
    k_node_l1<<<ngrid, 256, 0, stream>>>(x16, agg16,
        nW1t + (size_t)s * 128 * 256, nb1 + (size_t)s * L, h1n, gS);
    k_bnfin<<<L, 256, 0, stream>>>(gS, ng1 + (size_t)s * L, nbe1 + (size_t)s * L,
        1.f / (float)NND, ss);
    k_node_l2<<<ngrid, 256, 0, stream>>>(h1n, ss,
        nW2t + (size_t)s * 128 * 128, nb2 + (size_t)s * L,
        (s == 0) ? in_x : x, x, x16);
  }
}